// Round 1
// baseline (8278.381 us; speedup 1.0000x reference)
//
#include <hip/hip_runtime.h>
#include <math.h>

// ---- static config ----
#define BB 32
#define TT 12
#define NN 500
#define UU 32
#define CC 32          // NRES == NDIL
#define NSKIPC 256
#define NENDC 512
#define NPREDC 12
#define TX 13          // padded time length / X stride
#define TG 12          // G/D stride
#define BNN (BB*NN)    // 16000
#define XSZ (BNN*TX*CC)    // 6,656,000
#define GSZ (BNN*TG*CC)    // 6,144,000
#define DSZ GSZ
#define BN_EPS 1e-5f

// ---- workspace offsets (floats) ----
#define OFF_V      0u
#define OFF_ADJ    16000u
#define OFF_AT     516000u
#define OFF_PROJ   1016000u
#define OFF_SKIP   1040576u
#define OFF_PSUM   5136576u
#define OFF_PSUMSQ 5648576u
#define OFF_STAT   6160576u
#define OFF_X      6160640u
#define OFF_XN     12816640u
#define OFF_G      19472640u
#define OFF_D      25616640u
#define OFF_Y1     OFF_D      // reused after layers

// ================= adaptive supports =================

__global__ void k_v(const float* __restrict__ factor, const float* __restrict__ map_w,
                    const float* __restrict__ map_b, float* __restrict__ v) {
  int n = blockIdx.x; int d = threadIdx.x; // 32 threads
  __shared__ float fr[UU];
  fr[d] = factor[n*UU + d];
  __syncthreads();
  float acc = map_b[d];
#pragma unroll
  for (int u=0;u<UU;u++) acc += fr[u]*map_w[u*32+d];
  v[n*32+d] = fmaxf(acc, 0.f);
}

__global__ __launch_bounds__(256) void k_pair(const float* __restrict__ v,
    const float* __restrict__ a1w, const float* __restrict__ a1b,
    const float* __restrict__ a2w, const float* __restrict__ a2b,
    const float* __restrict__ a3w, const float* __restrict__ a3b,
    float* __restrict__ adj) {
  int i = blockIdx.x;
  __shared__ float w1[64*64];
  __shared__ float w2[64*32];
  __shared__ float vi[32];
  __shared__ float dsti[64];
  __shared__ float w3s[64];
  for (int idx=threadIdx.x; idx<64*64; idx+=256) w1[idx]=a1w[idx];
  for (int idx=threadIdx.x; idx<64*32; idx+=256) w2[idx]=a2w[idx];
  if (threadIdx.x<64) w3s[threadIdx.x] = a3w[threadIdx.x];
  if (threadIdx.x<32) vi[threadIdx.x] = v[i*32+threadIdx.x];
  __syncthreads();
  if (threadIdx.x<64) {
    int o=threadIdx.x; float a=a1b[o];
#pragma unroll
    for(int u=0;u<32;u++) a += vi[u]*w1[(32+u)*64+o];
    dsti[o]=a;
  }
  __syncthreads();
  float b2_0 = a3b[0], b2_1 = a3b[1];
  for (int j=threadIdx.x; j<NN; j+=256) {
    float vj[32];
#pragma unroll
    for(int u=0;u<32;u++) vj[u]=v[j*32+u];
    float h1[64];
#pragma unroll
    for(int o=0;o<64;o++){
      float a=dsti[o];
#pragma unroll
      for(int u=0;u<32;u++) a += vj[u]*w1[u*64+o];
      h1[o]=fmaxf(a,0.f);
    }
    float h2[32];
#pragma unroll
    for(int o=0;o<32;o++){
      float a=a2b[o];
#pragma unroll
      for(int k=0;k<64;k++) a += h1[k]*w2[k*32+o];
      h2[o]=fmaxf(a,0.f);
    }
    float e0=b2_0, e1=b2_1;
#pragma unroll
    for(int k=0;k<32;k++){ e0+=h2[k]*w3s[k*2]; e1+=h2[k]*w3s[k*2+1]; }
    adj[i*NN + j] = e0;
    adj[250000 + i*NN + j] = e1;
  }
}

__global__ __launch_bounds__(256) void k_softmax(const float* __restrict__ adj,
    float* __restrict__ sup_out, float* __restrict__ AT) {
  int row = blockIdx.x;           // e*500 + i
  int e = row/NN, i = row%NN;
  const float* a = adj + e*250000 + i*NN;
  __shared__ float red[64];
  float m = -1e30f;
  for (int j=threadIdx.x;j<NN;j+=256) m = fmaxf(m, a[j]);
#pragma unroll
  for (int off=32; off; off>>=1) m = fmaxf(m, __shfl_down(m, off));
  int lane = threadIdx.x & 63, wid = threadIdx.x >> 6;
  if (lane==0) red[wid]=m;
  __syncthreads();
  if (threadIdx.x==0){ float mm=red[0]; for(int w=1;w<4;w++) mm=fmaxf(mm,red[w]); red[32]=mm; }
  __syncthreads();
  m = red[32];
  float s=0.f;
  for (int j=threadIdx.x;j<NN;j+=256) s += __expf(a[j]-m);
#pragma unroll
  for (int off=32; off; off>>=1) s += __shfl_down(s, off);
  if (lane==0) red[wid]=s;
  __syncthreads();
  if (threadIdx.x==0){ float ss=0; for(int w=0;w<4;w++) ss+=red[w]; red[33]=ss; }
  __syncthreads();
  float inv = 1.f/red[33];
  for (int j=threadIdx.x;j<NN;j+=256) {
    float val = __expf(a[j]-m)*inv;
    if (j==i) val = 1.f;     // max(softmax, I): softmax<=1 so diag -> 1
    sup_out[e*250000 + i*NN + j] = val;
    AT[e*250000 + j*NN + i] = val;
  }
}

// ================= input projection / enter conv =================

__global__ void k_proj(const float* __restrict__ inputs, const float* __restrict__ factor,
                       float* __restrict__ proj) {
  int bt = blockIdx.x; // b*T + t
  __shared__ float xin[NN*2];
  for (int idx=threadIdx.x; idx<NN*2; idx+=64) xin[idx] = inputs[bt*NN*2 + idx];
  __syncthreads();
  int u = threadIdx.x>>1, f = threadIdx.x&1;
  float acc=0.f;
  for (int n=0;n<NN;n++) acc += xin[n*2+f]*factor[n*UU+u];
  proj[bt*64 + u*2+f] = acc;
}

__global__ __launch_bounds__(256) void k_enter(const float* __restrict__ inputs,
    const float* __restrict__ factor, const float* __restrict__ proj,
    const float* __restrict__ ew, const float* __restrict__ eb, float* __restrict__ X) {
  int idx = blockIdx.x*256+threadIdx.x;
  if (idx >= BB*NN*TX) return;
  int t = idx % TX; int n = (idx/TX)%NN; int b = idx/(TX*NN);
  float x4[4]={0.f,0.f,0.f,0.f};
  if (t>0) {
    int tt=t-1;
    float s0=0.f,s1=0.f;
    const float* pr = proj + (b*TT+tt)*64;
    const float* fr = factor + n*UU;
#pragma unroll
    for(int u=0;u<UU;u++){ s0 += pr[u*2]*fr[u]; s1 += pr[u*2+1]*fr[u]; }
    float i0 = inputs[((b*TT+tt)*NN+n)*2];
    float i1 = inputs[((b*TT+tt)*NN+n)*2+1];
    x4[0]=s0; x4[1]=s1; x4[2]=i0-s0; x4[3]=i1-s1;
  }
  float* xp = X + ((b*NN+n)*TX + t)*CC;
#pragma unroll
  for(int o=0;o<CC;o++){
    xp[o] = eb[o] + ew[o*4]*x4[0] + ew[o*4+1]*x4[1] + ew[o*4+2]*x4[2] + ew[o*4+3]*x4[3];
  }
}

// ================= per-layer kernels =================

__global__ __launch_bounds__(256) void k_gated(const float* __restrict__ X, float* __restrict__ G,
    const float* __restrict__ fw, const float* __restrict__ fb,
    const float* __restrict__ gw, const float* __restrict__ gb,
    int d, int t_in, int t_out) {
  int bn = blockIdx.x;
  __shared__ float xs[TX*CC];
  __shared__ float fwT[2048], gwT[2048];  // [c][k][o]
  for (int idx=threadIdx.x; idx<2048; idx+=256) {
    int o = idx>>6, c=(idx>>1)&31, k=idx&1;
    fwT[(c*2+k)*32+o]=fw[idx];
    gwT[(c*2+k)*32+o]=gw[idx];
  }
  for (int idx=threadIdx.x; idx<t_in*CC; idx+=256) xs[idx]=X[bn*TX*CC + idx];
  __syncthreads();
  for (int oid=threadIdx.x; oid<t_out*CC; oid+=256) {
    int t=oid>>5, o=oid&31;
    float f=fb[o], g=gb[o];
#pragma unroll
    for(int c=0;c<CC;c++){
      float xa=xs[t*32+c], xb=xs[(t+d)*32+c];
      f += fwT[(c*2)*32+o]*xa + fwT[(c*2+1)*32+o]*xb;
      g += gwT[(c*2)*32+o]*xa + gwT[(c*2+1)*32+o]*xb;
    }
    G[bn*TG*CC + oid] = tanhf(f)*(1.f/(1.f+__expf(-g)));
  }
}

__global__ __launch_bounds__(256) void k_skip(const float* __restrict__ G,
    const float* __restrict__ sw, const float* __restrict__ sb,
    float* __restrict__ skip, int t_out, int init) {
  int bn = blockIdx.x;
  __shared__ float gl[32];
  __shared__ float swT[NSKIPC*32];   // [c][o]
  for (int idx=threadIdx.x; idx<NSKIPC*32; idx+=256) {
    int o=idx>>5, c=idx&31;
    swT[c*NSKIPC+o] = sw[idx];
  }
  if (threadIdx.x<32) gl[threadIdx.x] = G[bn*TG*CC + (t_out-1)*32 + threadIdx.x];
  __syncthreads();
  int o = threadIdx.x;
  float acc = sb[o];
#pragma unroll
  for(int c=0;c<32;c++) acc += swT[c*NSKIPC+o]*gl[c];
  float* sp = skip + bn*NSKIPC + o;
  *sp = init ? acc : (*sp + acc);
}

// out[b][w][q] = sum_v AT[e][w][v] * IN_e[b][v][q]
__global__ __launch_bounds__(256) void k_diffuse(const float* __restrict__ AT,
    const float* __restrict__ in0, const float* __restrict__ in1,
    float* __restrict__ out0, float* __restrict__ out1, int qmax) {
  int e = blockIdx.z & 1, b = blockIdx.z >> 1;
  int w0 = blockIdx.x * 64, q0 = blockIdx.y * 64;
  const float* A  = AT + e*250000;
  const float* IN = (e ? in1 : in0) + b*NN*TG*CC;
  float* OUT      = (e ? out1 : out0) + b*NN*TG*CC;
  __shared__ float As[16*64];  // [k][w]
  __shared__ float Bs[16*64];  // [k][q]
  float acc[4][4] = {};
  int tw = threadIdx.x>>4, tq = threadIdx.x&15;
  for (int v0=0; v0<NN; v0+=16) {
    {
      int w = threadIdx.x>>2, k4=(threadIdx.x&3)*4;
      float4 val = {0,0,0,0};
      if (v0+k4+3 < NN) val = *(const float4*)(A + (w0+w)*NN + v0 + k4);
      // (w0+w always < 512; rows 500..511 of last tile guarded at write)
      if (w0+w >= NN) val = make_float4(0,0,0,0);
      As[(k4+0)*64+w]=val.x; As[(k4+1)*64+w]=val.y; As[(k4+2)*64+w]=val.z; As[(k4+3)*64+w]=val.w;
    }
    {
      int k = threadIdx.x>>4, q4=(threadIdx.x&15)*4;
      float4 val={0,0,0,0};
      if (v0+k < NN && q0+q4 < qmax) val = *(const float4*)(IN + (v0+k)*TG*CC + q0+q4);
      ((float4*)Bs)[k*16 + (q4>>2)] = val;
    }
    __syncthreads();
#pragma unroll
    for (int k=0;k<16;k++){
      float4 av = ((float4*)As)[k*16+tw];
      float4 bv = ((float4*)Bs)[k*16+tq];
      acc[0][0]+=av.x*bv.x; acc[0][1]+=av.x*bv.y; acc[0][2]+=av.x*bv.z; acc[0][3]+=av.x*bv.w;
      acc[1][0]+=av.y*bv.x; acc[1][1]+=av.y*bv.y; acc[1][2]+=av.y*bv.z; acc[1][3]+=av.y*bv.w;
      acc[2][0]+=av.z*bv.x; acc[2][1]+=av.z*bv.y; acc[2][2]+=av.z*bv.z; acc[2][3]+=av.z*bv.w;
      acc[3][0]+=av.w*bv.x; acc[3][1]+=av.w*bv.y; acc[3][2]+=av.w*bv.z; acc[3][3]+=av.w*bv.w;
    }
    __syncthreads();
  }
#pragma unroll
  for (int i=0;i<4;i++){
    int w = w0 + tw*4 + i;
    if (w >= NN) continue;
    int q = q0 + tq*4;
    if (q < qmax) *(float4*)(OUT + w*TG*CC + q) = make_float4(acc[i][0],acc[i][1],acc[i][2],acc[i][3]);
  }
}

__global__ __launch_bounds__(256) void k_gc(const float* __restrict__ G,
    const float* __restrict__ D, const float* __restrict__ X, float* __restrict__ Xn,
    const float* __restrict__ gcw, const float* __restrict__ gcb,
    float* __restrict__ psum, float* __restrict__ psumsq, int d, int t_out) {
  int bn = blockIdx.x;
  __shared__ float srcs[5*TG*CC];   // 1920
  __shared__ float gcT[160*32];     // [cc][o]
  __shared__ float red[TG*CC];
  for (int idx=threadIdx.x; idx<5120; idx+=256){
    int o=idx/160, cc=idx%160;
    gcT[cc*32+o] = gcw[idx];
  }
  int nq = t_out*CC;
  for (int idx=threadIdx.x; idx<nq; idx+=256){
    srcs[0*384+idx] = G[bn*TG*CC+idx];
    srcs[1*384+idx] = D[0*DSZ + bn*TG*CC+idx];
    srcs[2*384+idx] = D[1*DSZ + bn*TG*CC+idx];
    srcs[3*384+idx] = D[2*DSZ + bn*TG*CC+idx];
    srcs[4*384+idx] = D[3*DSZ + bn*TG*CC+idx];
  }
  __syncthreads();
  for (int oid=threadIdx.x; oid<nq; oid+=256){
    int t=oid>>5, o=oid&31;
    float acc = gcb[o];
#pragma unroll
    for (int s=0;s<5;s++)
#pragma unroll
      for (int c=0;c<32;c++)
        acc += gcT[(s*32+c)*32+o]*srcs[s*384+t*32+c];
    acc += X[bn*TX*CC + (t+d)*CC + o];
    red[oid] = acc;
    Xn[bn*TX*CC + oid] = acc;
  }
  __syncthreads();
  if (threadIdx.x < 32){
    int o=threadIdx.x; float s=0.f, ss=0.f;
    for (int t=0;t<t_out;t++){ float val=red[t*32+o]; s+=val; ss+=val*val; }
    psum[o*BNN + bn]=s; psumsq[o*BNN + bn]=ss;
  }
}

__global__ __launch_bounds__(256) void k_bnstat(const float* __restrict__ psum,
    const float* __restrict__ psumsq, const float* __restrict__ g,
    const float* __restrict__ bta, float* __restrict__ stat, float cntinv) {
  int o = blockIdx.x;
  float s=0.f, ss=0.f;
  for (int i=threadIdx.x;i<BNN;i+=256){ s+=psum[o*BNN+i]; ss+=psumsq[o*BNN+i]; }
  __shared__ float r1[4], r2[4];
#pragma unroll
  for (int off=32;off;off>>=1){ s+=__shfl_down(s,off); ss+=__shfl_down(ss,off); }
  int lane=threadIdx.x&63, wid=threadIdx.x>>6;
  if (!lane){ r1[wid]=s; r2[wid]=ss; }
  __syncthreads();
  if (!threadIdx.x){
    s=r1[0]+r1[1]+r1[2]+r1[3]; ss=r2[0]+r2[1]+r2[2]+r2[3];
    float m = s*cntinv; float var = ss*cntinv - m*m;
    float rstd = rsqrtf(var + BN_EPS);
    float sc = rstd*g[o];
    stat[o]=sc; stat[32+o]=bta[o]-m*sc;
  }
}

__global__ __launch_bounds__(256) void k_bnapply(float* __restrict__ Xn,
    const float* __restrict__ stat, int t_out) {
  int nq = t_out*CC;
  long total = (long)BNN*nq;
  for (long idx = (long)blockIdx.x*256+threadIdx.x; idx<total; idx += (long)gridDim.x*256){
    long bn = idx/nq; int r = (int)(idx - bn*nq);
    float val = Xn[bn*TX*CC + r];
    Xn[bn*TX*CC + r] = val*stat[r&31] + stat[32+(r&31)];
  }
}

// ================= output head =================

__global__ __launch_bounds__(256) void k_head1(const float* __restrict__ skip,
    const float* __restrict__ o1w, const float* __restrict__ o1b, float* __restrict__ Y1) {
  int m0 = blockIdx.x*64, n0 = blockIdx.y*64;
  __shared__ float As[16*64];  // [k][m]
  __shared__ float Bs[16*64];  // [k][n]
  float acc[4][4]={};
  int tm=threadIdx.x>>4, tn=threadIdx.x&15;
  for (int k0=0;k0<NSKIPC;k0+=16){
    {
      int mm = threadIdx.x>>2, k4=(threadIdx.x&3)*4;
      float4 va = *(const float4*)(skip + (m0+mm)*NSKIPC + k0+k4);
      As[(k4+0)*64+mm]=fmaxf(va.x,0.f); As[(k4+1)*64+mm]=fmaxf(va.y,0.f);
      As[(k4+2)*64+mm]=fmaxf(va.z,0.f); As[(k4+3)*64+mm]=fmaxf(va.w,0.f);
      float4 vb = *(const float4*)(o1w + (n0+mm)*NSKIPC + k0+k4);
      Bs[(k4+0)*64+mm]=vb.x; Bs[(k4+1)*64+mm]=vb.y;
      Bs[(k4+2)*64+mm]=vb.z; Bs[(k4+3)*64+mm]=vb.w;
    }
    __syncthreads();
#pragma unroll
    for (int k=0;k<16;k++){
      float4 av = ((float4*)As)[k*16+tm];
      float4 bv = ((float4*)Bs)[k*16+tn];
      acc[0][0]+=av.x*bv.x; acc[0][1]+=av.x*bv.y; acc[0][2]+=av.x*bv.z; acc[0][3]+=av.x*bv.w;
      acc[1][0]+=av.y*bv.x; acc[1][1]+=av.y*bv.y; acc[1][2]+=av.y*bv.z; acc[1][3]+=av.y*bv.w;
      acc[2][0]+=av.z*bv.x; acc[2][1]+=av.z*bv.y; acc[2][2]+=av.z*bv.z; acc[2][3]+=av.z*bv.w;
      acc[3][0]+=av.w*bv.x; acc[3][1]+=av.w*bv.y; acc[3][2]+=av.w*bv.z; acc[3][3]+=av.w*bv.w;
    }
    __syncthreads();
  }
  float4 bias = *(const float4*)(o1b + n0 + tn*4);
#pragma unroll
  for (int i=0;i<4;i++){
    int m = m0 + tm*4 + i;
    float4 r;
    r.x = fmaxf(acc[i][0]+bias.x, 0.f);
    r.y = fmaxf(acc[i][1]+bias.y, 0.f);
    r.z = fmaxf(acc[i][2]+bias.z, 0.f);
    r.w = fmaxf(acc[i][3]+bias.w, 0.f);
    *(float4*)(Y1 + m*NENDC + n0 + tn*4) = r;
  }
}

__global__ __launch_bounds__(256) void k_head2(const float* __restrict__ Y1,
    const float* __restrict__ o2w, const float* __restrict__ o2b, float* __restrict__ y) {
  int m = blockIdx.x*256+threadIdx.x;
  if (m >= BNN) return;
  float accs[NPREDC];
#pragma unroll
  for (int p=0;p<NPREDC;p++) accs[p]=o2b[p];
  for (int e=0;e<NENDC;e+=4){
    float4 yv = *(const float4*)(Y1 + m*NENDC + e);
#pragma unroll
    for (int p=0;p<NPREDC;p++){
      accs[p] += o2w[p*NENDC+e]*yv.x + o2w[p*NENDC+e+1]*yv.y
               + o2w[p*NENDC+e+2]*yv.z + o2w[p*NENDC+e+3]*yv.w;
    }
  }
  int b=m/NN, n=m%NN;
#pragma unroll
  for (int p=0;p<NPREDC;p++) y[(b*NPREDC+p)*NN+n]=accs[p];
}

// ================= host =================

extern "C" void kernel_launch(void* const* d_in, const int* in_sizes, int n_in,
                              void* d_out, int out_size, void* d_ws, size_t ws_size,
                              hipStream_t stream) {
  const float* inputs  = (const float*)d_in[0];
  const float* factor  = (const float*)d_in[1];
  const float* map_w   = (const float*)d_in[2];
  const float* map_b   = (const float*)d_in[3];
  const float* a1w     = (const float*)d_in[4];
  const float* a1b     = (const float*)d_in[5];
  const float* a2w     = (const float*)d_in[6];
  const float* a2b     = (const float*)d_in[7];
  const float* a3w     = (const float*)d_in[8];
  const float* a3b     = (const float*)d_in[9];
  const float* enter_w = (const float*)d_in[10];
  const float* enter_b = (const float*)d_in[11];
  const float* filt_w  = (const float*)d_in[12];
  const float* filt_b  = (const float*)d_in[13];
  const float* gate_w  = (const float*)d_in[14];
  const float* gate_b  = (const float*)d_in[15];
  const float* skp_w   = (const float*)d_in[16];
  const float* skp_b   = (const float*)d_in[17];
  const float* gc_w    = (const float*)d_in[18];
  const float* gc_b    = (const float*)d_in[19];
  const float* bn_g    = (const float*)d_in[20];
  const float* bn_b    = (const float*)d_in[21];
  const float* o1w     = (const float*)d_in[22];
  const float* o1b     = (const float*)d_in[23];
  const float* o2w     = (const float*)d_in[24];
  const float* o2b     = (const float*)d_in[25];
  (void)in_sizes; (void)n_in; (void)out_size; (void)ws_size;

  float* ws = (float*)d_ws;
  float* v      = ws + OFF_V;
  float* adj    = ws + OFF_ADJ;
  float* AT     = ws + OFF_AT;
  float* proj   = ws + OFF_PROJ;
  float* skipb  = ws + OFF_SKIP;
  float* psum   = ws + OFF_PSUM;
  float* psumsq = ws + OFF_PSUMSQ;
  float* stat   = ws + OFF_STAT;
  float* X      = ws + OFF_X;
  float* Xn     = ws + OFF_XN;
  float* G      = ws + OFF_G;
  float* D      = ws + OFF_D;
  float* Y1     = ws + OFF_Y1;

  float* y_out   = (float*)d_out;
  float* sup_out = y_out + BB*NPREDC*NN;   // 192000

  // adaptive supports
  k_v<<<NN, 32, 0, stream>>>(factor, map_w, map_b, v);
  k_pair<<<NN, 256, 0, stream>>>(v, a1w, a1b, a2w, a2b, a3w, a3b, adj);
  k_softmax<<<2*NN, 256, 0, stream>>>(adj, sup_out, AT);

  // input split + enter
  k_proj<<<BB*TT, 64, 0, stream>>>(inputs, factor, proj);
  k_enter<<<(BB*NN*TX+255)/256, 256, 0, stream>>>(inputs, factor, proj, enter_w, enter_b, X);

  float* Xc = X; float* Xo = Xn;
  int t = TX;
  static const int dil[8]={1,2,1,2,1,2,1,2};
  for (int l=0;l<8;l++){
    int d=dil[l], t_out=t-d;
    k_gated<<<BNN,256,0,stream>>>(Xc, G, filt_w + l*2048, filt_b + l*32,
                                  gate_w + l*2048, gate_b + l*32, d, t, t_out);
    k_skip<<<BNN,256,0,stream>>>(G, skp_w + l*8192, skp_b + l*256, skipb, t_out, l==0?1:0);
    int qmax = t_out*CC;
    dim3 g1(8, (qmax+63)/64, 64);
    k_diffuse<<<g1,256,0,stream>>>(AT, G, G, D+0*DSZ, D+2*DSZ, qmax);
    k_diffuse<<<g1,256,0,stream>>>(AT, D+0*DSZ, D+2*DSZ, D+1*DSZ, D+3*DSZ, qmax);
    k_gc<<<BNN,256,0,stream>>>(G, D, Xc, Xo, gc_w + l*5120, gc_b + l*32,
                               psum, psumsq, d, t_out);
    k_bnstat<<<32,256,0,stream>>>(psum, psumsq, bn_g + l*32, bn_b + l*32,
                                  stat, 1.f/(float)(BNN*t_out));
    k_bnapply<<<2048,256,0,stream>>>(Xo, stat, t_out);
    float* tmp=Xc; Xc=Xo; Xo=tmp;
    t = t_out;
  }

  dim3 gh(BNN/64, NENDC/64);
  k_head1<<<gh,256,0,stream>>>(skipb, o1w, o1b, Y1);
  k_head2<<<(BNN+255)/256,256,0,stream>>>(Y1, o2w, o2b, y_out);
}

// Round 2
// 2827.513 us; speedup vs baseline: 2.9278x; 2.9278x over previous
//
#include <hip/hip_runtime.h>
#include <math.h>

// ---- static config ----
#define BB 32
#define TT 12
#define NN 500
#define UU 32
#define CC 32          // NRES == NDIL
#define NSKIPC 256
#define NENDC 512
#define NPREDC 12
#define TX 13          // padded time length / X stride
#define TG 12          // G/D stride
#define BNN (BB*NN)    // 16000
#define DSZ (BNN*TG*CC)
#define BN_EPS 1e-5f

// ---- workspace offsets (floats) ----
#define OFF_V      0u
#define OFF_ADJ    16000u
#define OFF_PROJ   1016000u
#define OFF_GLAST  1018048u     // 16000*256 = 4096000
#define OFF_WSTACK 5114048u     // 65536
#define OFF_BSUM   5179584u     // 256
#define OFF_STAT   5179840u     // 8*64
#define OFF_PART   5180352u     // 1500*64 = 96000
#define OFF_X      5276352u     // 6656000
#define OFF_XN     11932352u    // 6656000
#define OFF_G      18588352u    // 6144000
#define OFF_D      24732352u    // 4*6144000 -> ends 49308352 (197 MB)
#define OFF_SKIPV  OFF_D
#define OFF_Y1     (OFF_D + 4096000u)

// ================= adaptive supports =================

__global__ void k_v(const float* __restrict__ factor, const float* __restrict__ map_w,
                    const float* __restrict__ map_b, float* __restrict__ v) {
  int n = blockIdx.x; int d = threadIdx.x; // 32 threads
  __shared__ float fr[UU];
  fr[d] = factor[n*UU + d];
  __syncthreads();
  float acc = map_b[d];
#pragma unroll
  for (int u=0;u<UU;u++) acc += fr[u]*map_w[u*32+d];
  v[n*32+d] = fmaxf(acc, 0.f);
}

__global__ __launch_bounds__(256) void k_pair(const float* __restrict__ v,
    const float* __restrict__ a1w, const float* __restrict__ a1b,
    const float* __restrict__ a2w, const float* __restrict__ a2b,
    const float* __restrict__ a3w, const float* __restrict__ a3b,
    float* __restrict__ adj) {
  int i = blockIdx.x;
  __shared__ float w1[64*64];
  __shared__ float w2[64*32];
  __shared__ float vi[32];
  __shared__ float dsti[64];
  __shared__ float w3s[64];
  for (int idx=threadIdx.x; idx<64*64; idx+=256) w1[idx]=a1w[idx];
  for (int idx=threadIdx.x; idx<64*32; idx+=256) w2[idx]=a2w[idx];
  if (threadIdx.x<64) w3s[threadIdx.x] = a3w[threadIdx.x];
  if (threadIdx.x<32) vi[threadIdx.x] = v[i*32+threadIdx.x];
  __syncthreads();
  if (threadIdx.x<64) {
    int o=threadIdx.x; float a=a1b[o];
#pragma unroll
    for(int u=0;u<32;u++) a += vi[u]*w1[(32+u)*64+o];
    dsti[o]=a;
  }
  __syncthreads();
  float b2_0 = a3b[0], b2_1 = a3b[1];
  for (int j=threadIdx.x; j<NN; j+=256) {
    float vj[32];
#pragma unroll
    for(int u=0;u<32;u++) vj[u]=v[j*32+u];
    float h1[64];
#pragma unroll
    for(int o=0;o<64;o++){
      float a=dsti[o];
#pragma unroll
      for(int u=0;u<32;u++) a += vj[u]*w1[u*64+o];
      h1[o]=fmaxf(a,0.f);
    }
    float h2[32];
#pragma unroll
    for(int o=0;o<32;o++){
      float a=a2b[o];
#pragma unroll
      for(int k=0;k<64;k++) a += h1[k]*w2[k*32+o];
      h2[o]=fmaxf(a,0.f);
    }
    float e0=b2_0, e1=b2_1;
#pragma unroll
    for(int k=0;k<32;k++){ e0+=h2[k]*w3s[k*2]; e1+=h2[k]*w3s[k*2+1]; }
    adj[i*NN + j] = e0;
    adj[250000 + i*NN + j] = e1;
  }
}

__global__ __launch_bounds__(256) void k_softmax(const float* __restrict__ adj,
    float* __restrict__ sup_out) {
  int row = blockIdx.x;           // e*500 + i
  int e = row/NN, i = row%NN;
  const float* a = adj + e*250000 + i*NN;
  __shared__ float red[64];
  float m = -1e30f;
  for (int j=threadIdx.x;j<NN;j+=256) m = fmaxf(m, a[j]);
#pragma unroll
  for (int off=32; off; off>>=1) m = fmaxf(m, __shfl_down(m, off));
  int lane = threadIdx.x & 63, wid = threadIdx.x >> 6;
  if (lane==0) red[wid]=m;
  __syncthreads();
  if (threadIdx.x==0){ float mm=red[0]; for(int w=1;w<4;w++) mm=fmaxf(mm,red[w]); red[32]=mm; }
  __syncthreads();
  m = red[32];
  float s=0.f;
  for (int j=threadIdx.x;j<NN;j+=256) s += __expf(a[j]-m);
#pragma unroll
  for (int off=32; off; off>>=1) s += __shfl_down(s, off);
  if (lane==0) red[wid]=s;
  __syncthreads();
  if (threadIdx.x==0){ float ss=0; for(int w=0;w<4;w++) ss+=red[w]; red[33]=ss; }
  __syncthreads();
  float inv = 1.f/red[33];
  for (int j=threadIdx.x;j<NN;j+=256) {
    float val = __expf(a[j]-m)*inv;
    if (j==i) val = 1.f;
    sup_out[e*250000 + i*NN + j] = val;
  }
}

// ================= input projection / enter conv =================

__global__ void k_proj(const float* __restrict__ inputs, const float* __restrict__ factor,
                       float* __restrict__ proj) {
  int bt = blockIdx.x;
  __shared__ float xin[NN*2];
  for (int idx=threadIdx.x; idx<NN*2; idx+=64) xin[idx] = inputs[bt*NN*2 + idx];
  __syncthreads();
  int u = threadIdx.x>>1, f = threadIdx.x&1;
  float acc=0.f;
  for (int n=0;n<NN;n++) acc += xin[n*2+f]*factor[n*UU+u];
  proj[bt*64 + u*2+f] = acc;
}

__global__ __launch_bounds__(256) void k_enter(const float* __restrict__ inputs,
    const float* __restrict__ factor, const float* __restrict__ proj,
    const float* __restrict__ ew, const float* __restrict__ eb, float* __restrict__ X) {
  int idx = blockIdx.x*256+threadIdx.x;
  if (idx >= BB*NN*TX) return;
  int t = idx % TX; int n = (idx/TX)%NN; int b = idx/(TX*NN);
  float x4[4]={0.f,0.f,0.f,0.f};
  if (t>0) {
    int tt=t-1;
    float s0=0.f,s1=0.f;
    const float* pr = proj + (b*TT+tt)*64;
    const float* fr = factor + n*UU;
#pragma unroll
    for(int u=0;u<UU;u++){ s0 += pr[u*2]*fr[u]; s1 += pr[u*2+1]*fr[u]; }
    float i0 = inputs[((b*TT+tt)*NN+n)*2];
    float i1 = inputs[((b*TT+tt)*NN+n)*2+1];
    x4[0]=s0; x4[1]=s1; x4[2]=i0-s0; x4[3]=i1-s1;
  }
  float* xp = X + ((size_t)(b*NN+n)*TX + t)*CC;
#pragma unroll
  for(int o=0;o<CC;o++){
    xp[o] = eb[o] + ew[o*4]*x4[0] + ew[o*4+1]*x4[1] + ew[o*4+2]*x4[2] + ew[o*4+3]*x4[3];
  }
}

// ================= gated temporal conv (tiled GEMM, M=BNN*t_out, N=64, K=64) =========

__global__ __launch_bounds__(256) void k_gated2(const float* __restrict__ X,
    float* __restrict__ G, float* __restrict__ Glast,
    const float* __restrict__ fw, const float* __restrict__ fb,
    const float* __restrict__ gw, const float* __restrict__ gb,
    const float* __restrict__ stat, int use_stat, int d, int t_out, int lidx) {
  __shared__ __align__(16) float As[64][68];
  __shared__ __align__(16) float Ws[64][64];
  __shared__ __align__(16) float scs[32];
  __shared__ __align__(16) float shs[32];
  int tid = threadIdx.x;
  if (tid < 32) {
    scs[tid] = use_stat ? stat[tid] : 1.0f;
    shs[tid] = use_stat ? stat[32 + tid] : 0.0f;
  }
  for (int i = tid; i < 2048; i += 256) {
    int o = i >> 6, k = i & 63;
    Ws[k][o] = fw[i];        // Ws[k][o]    = fw[o*64+k] since i = o*64+k
    Ws[k][32 + o] = gw[i];
  }
  __syncthreads();
  int m0 = blockIdx.x * 64;
  {
    int mm = tid & 63;
    int kb = (tid >> 6) * 16;
    int c0 = kb >> 1;
    int m = m0 + mm;
    int bn = m / t_out, t = m - bn * t_out;
    const float* xr = X + (size_t)bn * (TX * CC);
    float4 a0 = *(const float4*)(xr + t * 32 + c0);
    float4 a1 = *(const float4*)(xr + t * 32 + c0 + 4);
    float4 b0 = *(const float4*)(xr + (t + d) * 32 + c0);
    float4 b1 = *(const float4*)(xr + (t + d) * 32 + c0 + 4);
    float va[8] = {a0.x,a0.y,a0.z,a0.w,a1.x,a1.y,a1.z,a1.w};
    float vb[8] = {b0.x,b0.y,b0.z,b0.w,b1.x,b1.y,b1.z,b1.w};
#pragma unroll
    for (int j = 0; j < 8; j++) {
      float sc = scs[c0+j], sh = shs[c0+j];
      As[kb + 2*j][mm]     = va[j]*sc + sh;
      As[kb + 2*j + 1][mm] = vb[j]*sc + sh;
    }
  }
  __syncthreads();
  int tm = tid >> 4, tn = tid & 15;
  float acc[4][4] = {};
#pragma unroll 8
  for (int k = 0; k < 64; k++) {
    float4 av = *(const float4*)&As[k][tm*4];
    float4 bv = *(const float4*)&Ws[k][tn*4];
    acc[0][0]+=av.x*bv.x; acc[0][1]+=av.x*bv.y; acc[0][2]+=av.x*bv.z; acc[0][3]+=av.x*bv.w;
    acc[1][0]+=av.y*bv.x; acc[1][1]+=av.y*bv.y; acc[1][2]+=av.y*bv.z; acc[1][3]+=av.y*bv.w;
    acc[2][0]+=av.z*bv.x; acc[2][1]+=av.z*bv.y; acc[2][2]+=av.z*bv.z; acc[2][3]+=av.z*bv.w;
    acc[3][0]+=av.w*bv.x; acc[3][1]+=av.w*bv.y; acc[3][2]+=av.w*bv.z; acc[3][3]+=av.w*bv.w;
  }
  // exchange: tn<8 holds f (n=tn*4+j), tn>=8 holds g (n-32)
  float gx[4][4];
#pragma unroll
  for (int i=0;i<4;i++)
#pragma unroll
    for (int j=0;j<4;j++) gx[i][j] = __shfl_xor(acc[i][j], 8);
  if (tn < 8) {
    int o0 = tn*4;
    float4 fb4 = *(const float4*)(fb + o0);
    float4 gb4 = *(const float4*)(gb + o0);
    float fbv[4] = {fb4.x,fb4.y,fb4.z,fb4.w};
    float gbv[4] = {gb4.x,gb4.y,gb4.z,gb4.w};
#pragma unroll
    for (int i=0;i<4;i++) {
      int m = m0 + tm*4 + i;
      int bn = m / t_out, t = m - bn*t_out;
      float ov[4];
#pragma unroll
      for (int j=0;j<4;j++) {
        float f = acc[i][j] + fbv[j];
        float g = gx[i][j] + gbv[j];
        float th = 2.f/(1.f+__expf(-2.f*f)) - 1.f;
        float sg = 1.f/(1.f+__expf(-g));
        ov[j] = th*sg;
      }
      float4 o4 = make_float4(ov[0],ov[1],ov[2],ov[3]);
      *(float4*)(G + (size_t)bn*(TG*CC) + t*32 + o0) = o4;
      if (t == t_out-1)
        *(float4*)(Glast + (size_t)bn*256 + lidx*32 + o0) = o4;
    }
  }
}

// ======= graph diffusion: OUT[w][q] = sum_v S[v][w] * IN[v][q] ===========

__global__ __launch_bounds__(256) void k_diffuse(const float* __restrict__ S,
    const float* __restrict__ in0, const float* __restrict__ in1,
    float* __restrict__ out0, float* __restrict__ out1, int qmax) {
  int e = blockIdx.z & 1, b = blockIdx.z >> 1;
  int w0 = blockIdx.x * 64, q0 = blockIdx.y * 64;
  const float* A  = S + e*250000;
  const float* IN = (e ? in1 : in0) + (size_t)b*NN*TG*CC;
  float* OUT      = (e ? out1 : out0) + (size_t)b*NN*TG*CC;
  __shared__ __align__(16) float As[16][64];  // [k][w]
  __shared__ __align__(16) float Bs[16][64];  // [k][q]
  float acc[4][4] = {};
  int tw = threadIdx.x>>4, tq = threadIdx.x&15;
  int ks = threadIdx.x>>4, c4 = (threadIdx.x&15)*4;
  for (int v0=0; v0<NN; v0+=16) {
    float4 va = make_float4(0,0,0,0), vb = make_float4(0,0,0,0);
    if (v0+ks < NN && w0+c4 < NN)   va = *(const float4*)(A + (size_t)(v0+ks)*NN + w0+c4);
    if (v0+ks < NN && q0+c4 < qmax) vb = *(const float4*)(IN + (size_t)(v0+ks)*(TG*CC) + q0+c4);
    __syncthreads();
    *(float4*)&As[ks][c4] = va;
    *(float4*)&Bs[ks][c4] = vb;
    __syncthreads();
#pragma unroll
    for (int k=0;k<16;k++){
      float4 av = *(const float4*)&As[k][tw*4];
      float4 bv = *(const float4*)&Bs[k][tq*4];
      acc[0][0]+=av.x*bv.x; acc[0][1]+=av.x*bv.y; acc[0][2]+=av.x*bv.z; acc[0][3]+=av.x*bv.w;
      acc[1][0]+=av.y*bv.x; acc[1][1]+=av.y*bv.y; acc[1][2]+=av.y*bv.z; acc[1][3]+=av.y*bv.w;
      acc[2][0]+=av.z*bv.x; acc[2][1]+=av.z*bv.y; acc[2][2]+=av.z*bv.z; acc[2][3]+=av.z*bv.w;
      acc[3][0]+=av.w*bv.x; acc[3][1]+=av.w*bv.y; acc[3][2]+=av.w*bv.z; acc[3][3]+=av.w*bv.w;
    }
    __syncthreads();
  }
#pragma unroll
  for (int i=0;i<4;i++){
    int w = w0 + tw*4 + i;
    if (w >= NN) continue;
    int q = q0 + tq*4;
    if (q < qmax) *(float4*)(OUT + (size_t)w*TG*CC + q) = make_float4(acc[i][0],acc[i][1],acc[i][2],acc[i][3]);
  }
}

// ======= graph-conv 1x1 (M=BNN*t_out tile 128, N=32, K=160) + residual + BN partials ====

__global__ __launch_bounds__(256) void k_gc2(const float* __restrict__ G,
    const float* __restrict__ D, const float* __restrict__ Xc, float* __restrict__ Xn,
    const float* __restrict__ gcw, const float* __restrict__ gcb,
    const float* __restrict__ stat, int use_stat,
    float* __restrict__ part, int d, int t_out) {
  __shared__ __align__(16) float As[32][132];
  __shared__ __align__(16) float Ws[160][32];
  __shared__ __align__(16) float scs[32];
  __shared__ __align__(16) float shs[32];
  __shared__ __align__(16) float wred[4][64];
  int tid = threadIdx.x;
  if (tid < 32) {
    scs[tid] = use_stat ? stat[tid] : 1.0f;
    shs[tid] = use_stat ? stat[32 + tid] : 0.0f;
  }
  for (int i = tid; i < 5120; i += 256) {
    int kk = i >> 5, o = i & 31;
    Ws[kk][o] = gcw[o*160 + kk];
  }
  int m0 = blockIdx.x * 128;
  int tm = tid >> 3, tn = tid & 7;
  float acc[4][4] = {};
  int mm = tid & 127, kb = (tid >> 7) * 16;
  int m_s = m0 + mm;
  int bn_s = m_s / t_out, t_s = m_s - bn_s*t_out;
  size_t soff = (size_t)bn_s*(TG*CC) + t_s*32 + kb;
  const float* srcs[5] = {G, D, D+DSZ, D+2*(size_t)DSZ, D+3*(size_t)DSZ};
  for (int s = 0; s < 5; s++) {
    const float* sr = srcs[s] + soff;
    float4 r0 = *(const float4*)(sr);
    float4 r1 = *(const float4*)(sr+4);
    float4 r2 = *(const float4*)(sr+8);
    float4 r3 = *(const float4*)(sr+12);
    __syncthreads();
    float vv[16] = {r0.x,r0.y,r0.z,r0.w, r1.x,r1.y,r1.z,r1.w,
                    r2.x,r2.y,r2.z,r2.w, r3.x,r3.y,r3.z,r3.w};
#pragma unroll
    for (int j=0;j<16;j++) As[kb+j][mm] = vv[j];
    __syncthreads();
#pragma unroll 8
    for (int k=0;k<32;k++) {
      float4 av = *(const float4*)&As[k][tm*4];
      float4 bv = *(const float4*)&Ws[s*32+k][tn*4];
      acc[0][0]+=av.x*bv.x; acc[0][1]+=av.x*bv.y; acc[0][2]+=av.x*bv.z; acc[0][3]+=av.x*bv.w;
      acc[1][0]+=av.y*bv.x; acc[1][1]+=av.y*bv.y; acc[1][2]+=av.y*bv.z; acc[1][3]+=av.y*bv.w;
      acc[2][0]+=av.z*bv.x; acc[2][1]+=av.z*bv.y; acc[2][2]+=av.z*bv.z; acc[2][3]+=av.z*bv.w;
      acc[3][0]+=av.w*bv.x; acc[3][1]+=av.w*bv.y; acc[3][2]+=av.w*bv.z; acc[3][3]+=av.w*bv.w;
    }
  }
  // epilogue
  int n0 = tn*4;
  float4 gcb4 = *(const float4*)(gcb + n0);
  float scv[4] = {scs[n0],scs[n0+1],scs[n0+2],scs[n0+3]};
  float shv[4] = {shs[n0],shs[n0+1],shs[n0+2],shs[n0+3]};
  float gb4[4] = {gcb4.x,gcb4.y,gcb4.z,gcb4.w};
  float s_sum[4] = {0,0,0,0}, s_ssq[4] = {0,0,0,0};
#pragma unroll
  for (int i=0;i<4;i++){
    int m = m0 + tm*4 + i;
    int bn = m / t_out, t = m - bn*t_out;
    float4 res = *(const float4*)(Xc + (size_t)bn*(TX*CC) + (t+d)*32 + n0);
    float rv[4] = {res.x,res.y,res.z,res.w};
    float ov[4];
#pragma unroll
    for (int j=0;j<4;j++){
      float val = acc[i][j] + gb4[j] + rv[j]*scv[j] + shv[j];
      ov[j] = val;
      s_sum[j] += val;
      s_ssq[j] += val*val;
    }
    *(float4*)(Xn + (size_t)bn*(TX*CC) + t*32 + n0) = make_float4(ov[0],ov[1],ov[2],ov[3]);
  }
  // reduce over lanes sharing tn (stride 8 within wave)
#pragma unroll
  for (int off=8; off<=32; off<<=1){
#pragma unroll
    for (int j=0;j<4;j++){
      s_sum[j] += __shfl_xor(s_sum[j], off);
      s_ssq[j] += __shfl_xor(s_ssq[j], off);
    }
  }
  int lane = tid & 63, wid = tid >> 6;
  if (lane < 8){
#pragma unroll
    for (int j=0;j<4;j++){
      wred[wid][lane*4+j]      = s_sum[j];
      wred[wid][32+lane*4+j]   = s_ssq[j];
    }
  }
  __syncthreads();
  if (tid < 64){
    float vsum = wred[0][tid]+wred[1][tid]+wred[2][tid]+wred[3][tid];
    part[(size_t)blockIdx.x*64 + tid] = vsum;
  }
}

__global__ __launch_bounds__(256) void k_stat(const float* __restrict__ part, int nblk,
    const float* __restrict__ g, const float* __restrict__ b,
    float* __restrict__ statout, float cntinv) {
  __shared__ float red[4][64];
  int tid = threadIdx.x;
  int slot = tid & 63, grp = tid >> 6;
  float acc = 0.f;
  for (int i = grp; i < nblk; i += 4) acc += part[(size_t)i*64 + slot];
  red[grp][slot] = acc;
  __syncthreads();
  if (tid < 64) red[0][tid] = red[0][tid]+red[1][tid]+red[2][tid]+red[3][tid];
  __syncthreads();
  if (tid < 32){
    float s = red[0][tid], ss = red[0][32+tid];
    float m = s*cntinv, var = ss*cntinv - m*m;
    float sc = rsqrtf(var + BN_EPS)*g[tid];
    statout[tid] = sc;
    statout[32+tid] = b[tid] - m*sc;
  }
}

// ================= output head =================

__global__ void k_wstack(const float* __restrict__ skp_w, const float* __restrict__ skp_b,
                         float* __restrict__ Wst, float* __restrict__ bsum) {
  int idx = blockIdx.x*256 + threadIdx.x;   // grid 256 -> 65536
  int kk = idx >> 8, o = idx & 255;
  Wst[idx] = skp_w[(kk>>5)*8192 + o*32 + (kk&31)];
  if (idx < 256){
    float s=0.f;
    for (int l=0;l<8;l++) s += skp_b[l*256+idx];
    bsum[idx]=s;
  }
}

// skipv = relu(Glast @ Wst + bsum)   [16000,256]x[256,256]
__global__ __launch_bounds__(256) void k_skipgemm(const float* __restrict__ Gl,
    const float* __restrict__ Wst, const float* __restrict__ bsum, float* __restrict__ skipv) {
  int m0 = blockIdx.x*64, n0 = blockIdx.y*64;
  __shared__ __align__(16) float As[16][64];
  __shared__ __align__(16) float Bs[16][64];
  float acc[4][4]={};
  int tm=threadIdx.x>>4, tn=threadIdx.x&15;
  int mm = threadIdx.x>>2, k4=(threadIdx.x&3)*4;
  int ks = threadIdx.x>>4, n4 = (threadIdx.x&15)*4;
  for (int k0=0;k0<256;k0+=16){
    float4 va = *(const float4*)(Gl + (size_t)(m0+mm)*256 + k0+k4);
    float4 vb = *(const float4*)(Wst + (size_t)(k0+ks)*256 + n0+n4);
    __syncthreads();
    As[k4+0][mm]=va.x; As[k4+1][mm]=va.y; As[k4+2][mm]=va.z; As[k4+3][mm]=va.w;
    *(float4*)&Bs[ks][n4] = vb;
    __syncthreads();
#pragma unroll
    for (int k=0;k<16;k++){
      float4 av = *(const float4*)&As[k][tm*4];
      float4 bv = *(const float4*)&Bs[k][tn*4];
      acc[0][0]+=av.x*bv.x; acc[0][1]+=av.x*bv.y; acc[0][2]+=av.x*bv.z; acc[0][3]+=av.x*bv.w;
      acc[1][0]+=av.y*bv.x; acc[1][1]+=av.y*bv.y; acc[1][2]+=av.y*bv.z; acc[1][3]+=av.y*bv.w;
      acc[2][0]+=av.z*bv.x; acc[2][1]+=av.z*bv.y; acc[2][2]+=av.z*bv.z; acc[2][3]+=av.z*bv.w;
      acc[3][0]+=av.w*bv.x; acc[3][1]+=av.w*bv.y; acc[3][2]+=av.w*bv.z; acc[3][3]+=av.w*bv.w;
    }
    __syncthreads();
  }
  float4 bs4 = *(const float4*)(bsum + n0 + tn*4);
  float bv[4] = {bs4.x,bs4.y,bs4.z,bs4.w};
#pragma unroll
  for (int i=0;i<4;i++){
    int m = m0 + tm*4 + i;
    float4 r;
    r.x = fmaxf(acc[i][0]+bv[0], 0.f);
    r.y = fmaxf(acc[i][1]+bv[1], 0.f);
    r.z = fmaxf(acc[i][2]+bv[2], 0.f);
    r.w = fmaxf(acc[i][3]+bv[3], 0.f);
    *(float4*)(skipv + (size_t)m*256 + n0 + tn*4) = r;
  }
}

// Y1 = relu(skipv @ o1w^T + o1b)   [16000,256]x[256->512]
__global__ __launch_bounds__(256) void k_head1(const float* __restrict__ skipv,
    const float* __restrict__ o1w, const float* __restrict__ o1b, float* __restrict__ Y1) {
  int m0 = blockIdx.x*64, n0 = blockIdx.y*64;
  __shared__ __align__(16) float As[16][64];
  __shared__ __align__(16) float Bs[16][64];
  float acc[4][4]={};
  int tm=threadIdx.x>>4, tn=threadIdx.x&15;
  int mm = threadIdx.x>>2, k4=(threadIdx.x&3)*4;
  for (int k0=0;k0<NSKIPC;k0+=16){
    float4 va = *(const float4*)(skipv + (size_t)(m0+mm)*NSKIPC + k0+k4);
    float4 vb = *(const float4*)(o1w + (size_t)(n0+mm)*NSKIPC + k0+k4);
    __syncthreads();
    As[k4+0][mm]=va.x; As[k4+1][mm]=va.y; As[k4+2][mm]=va.z; As[k4+3][mm]=va.w;
    Bs[k4+0][mm]=vb.x; Bs[k4+1][mm]=vb.y; Bs[k4+2][mm]=vb.z; Bs[k4+3][mm]=vb.w;
    __syncthreads();
#pragma unroll
    for (int k=0;k<16;k++){
      float4 av = *(const float4*)&As[k][tm*4];
      float4 bv = *(const float4*)&Bs[k][tn*4];
      acc[0][0]+=av.x*bv.x; acc[0][1]+=av.x*bv.y; acc[0][2]+=av.x*bv.z; acc[0][3]+=av.x*bv.w;
      acc[1][0]+=av.y*bv.x; acc[1][1]+=av.y*bv.y; acc[1][2]+=av.y*bv.z; acc[1][3]+=av.y*bv.w;
      acc[2][0]+=av.z*bv.x; acc[2][1]+=av.z*bv.y; acc[2][2]+=av.z*bv.z; acc[2][3]+=av.z*bv.w;
      acc[3][0]+=av.w*bv.x; acc[3][1]+=av.w*bv.y; acc[3][2]+=av.w*bv.z; acc[3][3]+=av.w*bv.w;
    }
    __syncthreads();
  }
  float4 bias = *(const float4*)(o1b + n0 + tn*4);
  float bv[4] = {bias.x,bias.y,bias.z,bias.w};
#pragma unroll
  for (int i=0;i<4;i++){
    int m = m0 + tm*4 + i;
    float4 r;
    r.x = fmaxf(acc[i][0]+bv[0], 0.f);
    r.y = fmaxf(acc[i][1]+bv[1], 0.f);
    r.z = fmaxf(acc[i][2]+bv[2], 0.f);
    r.w = fmaxf(acc[i][3]+bv[3], 0.f);
    *(float4*)(Y1 + (size_t)m*NENDC + n0 + tn*4) = r;
  }
}

__global__ __launch_bounds__(256) void k_head2(const float* __restrict__ Y1,
    const float* __restrict__ o2w, const float* __restrict__ o2b, float* __restrict__ y) {
  int m = blockIdx.x*256+threadIdx.x;
  if (m >= BNN) return;
  float accs[NPREDC];
#pragma unroll
  for (int p=0;p<NPREDC;p++) accs[p]=o2b[p];
  for (int e=0;e<NENDC;e+=4){
    float4 yv = *(const float4*)(Y1 + (size_t)m*NENDC + e);
#pragma unroll
    for (int p=0;p<NPREDC;p++){
      accs[p] += o2w[p*NENDC+e]*yv.x + o2w[p*NENDC+e+1]*yv.y
               + o2w[p*NENDC+e+2]*yv.z + o2w[p*NENDC+e+3]*yv.w;
    }
  }
  int b=m/NN, n=m%NN;
#pragma unroll
  for (int p=0;p<NPREDC;p++) y[(b*NPREDC+p)*NN+n]=accs[p];
}

// ================= host =================

extern "C" void kernel_launch(void* const* d_in, const int* in_sizes, int n_in,
                              void* d_out, int out_size, void* d_ws, size_t ws_size,
                              hipStream_t stream) {
  const float* inputs  = (const float*)d_in[0];
  const float* factor  = (const float*)d_in[1];
  const float* map_w   = (const float*)d_in[2];
  const float* map_b   = (const float*)d_in[3];
  const float* a1w     = (const float*)d_in[4];
  const float* a1b     = (const float*)d_in[5];
  const float* a2w     = (const float*)d_in[6];
  const float* a2b     = (const float*)d_in[7];
  const float* a3w     = (const float*)d_in[8];
  const float* a3b     = (const float*)d_in[9];
  const float* enter_w = (const float*)d_in[10];
  const float* enter_b = (const float*)d_in[11];
  const float* filt_w  = (const float*)d_in[12];
  const float* filt_b  = (const float*)d_in[13];
  const float* gate_w  = (const float*)d_in[14];
  const float* gate_b  = (const float*)d_in[15];
  const float* skp_w   = (const float*)d_in[16];
  const float* skp_b   = (const float*)d_in[17];
  const float* gc_w    = (const float*)d_in[18];
  const float* gc_b    = (const float*)d_in[19];
  const float* bn_g    = (const float*)d_in[20];
  const float* bn_b    = (const float*)d_in[21];
  const float* o1w     = (const float*)d_in[22];
  const float* o1b     = (const float*)d_in[23];
  const float* o2w     = (const float*)d_in[24];
  const float* o2b     = (const float*)d_in[25];
  (void)in_sizes; (void)n_in; (void)out_size; (void)ws_size;

  float* ws = (float*)d_ws;
  float* v      = ws + OFF_V;
  float* adj    = ws + OFF_ADJ;
  float* proj   = ws + OFF_PROJ;
  float* Glast  = ws + OFF_GLAST;
  float* Wst    = ws + OFF_WSTACK;
  float* bsum   = ws + OFF_BSUM;
  float* statb  = ws + OFF_STAT;
  float* part   = ws + OFF_PART;
  float* X      = ws + OFF_X;
  float* Xn     = ws + OFF_XN;
  float* G      = ws + OFF_G;
  float* D      = ws + OFF_D;
  float* skipv  = ws + OFF_SKIPV;
  float* Y1     = ws + OFF_Y1;

  float* y_out   = (float*)d_out;
  float* sup_out = y_out + BB*NPREDC*NN;   // 192000

  // adaptive supports
  k_v<<<NN, 32, 0, stream>>>(factor, map_w, map_b, v);
  k_pair<<<NN, 256, 0, stream>>>(v, a1w, a1b, a2w, a2b, a3w, a3b, adj);
  k_softmax<<<2*NN, 256, 0, stream>>>(adj, sup_out);

  // input split + enter
  k_proj<<<BB*TT, 64, 0, stream>>>(inputs, factor, proj);
  k_enter<<<(BB*NN*TX+255)/256, 256, 0, stream>>>(inputs, factor, proj, enter_w, enter_b, X);

  // skip weight stack (independent)
  k_wstack<<<256, 256, 0, stream>>>(skp_w, skp_b, Wst, bsum);

  float* Xc = X; float* Xo = Xn;
  int t = TX;
  static const int dil[8]={1,2,1,2,1,2,1,2};
  for (int l=0;l<7;l++){
    int d=dil[l], t_out=t-d;
    const float* st = statb + (l>0 ? (l-1)*64 : 0);
    k_gated2<<<250*t_out,256,0,stream>>>(Xc, G, Glast, filt_w + l*2048, filt_b + l*32,
                                         gate_w + l*2048, gate_b + l*32, st, l>0, d, t_out, l);
    int qmax = t_out*CC;
    dim3 g1(8, (qmax+63)/64, 64);
    k_diffuse<<<g1,256,0,stream>>>(sup_out, G, G, D+0*(size_t)DSZ, D+2*(size_t)DSZ, qmax);
    k_diffuse<<<g1,256,0,stream>>>(sup_out, D+0*(size_t)DSZ, D+2*(size_t)DSZ,
                                   D+1*(size_t)DSZ, D+3*(size_t)DSZ, qmax);
    int ntiles = 125*t_out;
    k_gc2<<<ntiles,256,0,stream>>>(G, D, Xc, Xo, gc_w + l*5120, gc_b + l*32,
                                   st, l>0, part, d, t_out);
    k_stat<<<1,256,0,stream>>>(part, ntiles, bn_g + l*32, bn_b + l*32,
                               statb + l*64, 1.f/(16000.f*(float)t_out));
    float* tmp=Xc; Xc=Xo; Xo=tmp;
    t = t_out;
  }
  // layer 8 (l=7): only gated conv feeds skip; diffusion/GC/BN are dead
  k_gated2<<<250*1,256,0,stream>>>(Xc, G, Glast, filt_w + 7*2048, filt_b + 7*32,
                                   gate_w + 7*2048, gate_b + 7*32, statb + 6*64, 1, 2, 1, 7);

  // head
  dim3 gs(BNN/64, 256/64);
  k_skipgemm<<<gs,256,0,stream>>>(Glast, Wst, bsum, skipv);
  dim3 gh(BNN/64, NENDC/64);
  k_head1<<<gh,256,0,stream>>>(skipv, o1w, o1b, Y1);
  k_head2<<<(BNN+255)/256,256,0,stream>>>(Y1, o2w, o2b, y_out);
}

// Round 3
// 1633.680 us; speedup vs baseline: 5.0673x; 1.7308x over previous
//
#include <hip/hip_runtime.h>
#include <math.h>

// ---- static config ----
#define BB 32
#define TT 12
#define NN 500
#define UU 32
#define CC 32          // NRES == NDIL
#define NSKIPC 256
#define NENDC 512
#define NPREDC 12
#define TX 13          // padded time length / X stride
#define TG 12          // G/D stride
#define QS 384         // TG*CC
#define VS 512         // padded node dim
#define BNN (BB*NN)    // 16000
#define DSZ (BNN*TG*CC)        // 6,144,000 floats per diffusion buffer
#define DTE (32*384*512)       // shorts per e in DT / size of GT in shorts
#define BN_EPS 1e-5f

// ---- workspace offsets (floats) ----
#define OFF_V      0u
#define OFF_ADJ    16000u
#define OFF_ASRC   516000u
#define OFF_PROJ   548000u
#define OFF_GLAST  550048u
#define OFF_WSTACK 4646048u
#define OFF_BSUM   4711584u
#define OFF_STAT   4711840u
#define OFF_PART   4712352u
#define OFF_X      4808352u
#define OFF_XN     11464352u
#define OFF_G      18120352u
#define OFF_D      24264352u    // 4*6144000 -> ends 48840352
#define OFF_SKIPV  OFF_D
#define OFF_Y1     (OFF_D + 4096000u)
#define OFF_ST     48840352u    // shorts: 2*512*512 = 524288 (262144 floats)
#define OFF_GT     49102496u    // shorts: 6291456 (3145728 floats)
#define OFF_DT     52248224u    // shorts: 2*6291456 (6291456 floats) -> ends 58539680

typedef __attribute__((ext_vector_type(8))) short bf16x8;
typedef __attribute__((ext_vector_type(4))) float f32x4;

__device__ inline unsigned short f2bf(float f) {
  union { float f; unsigned u; } x; x.f = f;
  unsigned r = x.u + 0x7FFFu + ((x.u >> 16) & 1u);
  return (unsigned short)(r >> 16);
}
__device__ inline int pk2(float a, float b) {
  return (int)((unsigned)f2bf(a) | ((unsigned)f2bf(b) << 16));
}

// ================= adaptive supports =================

__global__ void k_v(const float* __restrict__ factor, const float* __restrict__ map_w,
                    const float* __restrict__ map_b, float* __restrict__ v) {
  int n = blockIdx.x; int d = threadIdx.x; // 32 threads
  __shared__ float fr[UU];
  fr[d] = factor[n*UU + d];
  __syncthreads();
  float acc = map_b[d];
#pragma unroll
  for (int u=0;u<UU;u++) acc += fr[u]*map_w[u*32+d];
  v[n*32+d] = fmaxf(acc, 0.f);
}

__global__ void k_asrc(const float* __restrict__ v, const float* __restrict__ a1w,
                       float* __restrict__ asrc) {
  int j = blockIdx.x; int o = threadIdx.x; // 64 threads
  __shared__ float vj[32];
  if (o < 32) vj[o] = v[j*32+o];
  __syncthreads();
  float a = 0.f;
#pragma unroll
  for (int u=0;u<32;u++) a += vj[u]*a1w[u*64+o];
  asrc[j*64+o] = a;
}

__global__ __launch_bounds__(256) void k_pair2(const float* __restrict__ v,
    const float* __restrict__ asrc,
    const float* __restrict__ a1w, const float* __restrict__ a1b,
    const float* __restrict__ a2w, const float* __restrict__ a2b,
    const float* __restrict__ a3w, const float* __restrict__ a3b,
    float* __restrict__ adj) {
  int i = blockIdx.x;
  __shared__ float w2[64*32];
  __shared__ float w3s[64];
  __shared__ float dsti[64];
  __shared__ float vi[32];
  for (int idx=threadIdx.x; idx<2048; idx+=256) w2[idx]=a2w[idx];
  if (threadIdx.x<64) w3s[threadIdx.x] = a3w[threadIdx.x];
  if (threadIdx.x<32) vi[threadIdx.x] = v[i*32+threadIdx.x];
  __syncthreads();
  if (threadIdx.x<64) {
    int o=threadIdx.x; float a=a1b[o];
#pragma unroll
    for(int u=0;u<32;u++) a += vi[u]*a1w[(32+u)*64+o];
    dsti[o]=a;
  }
  __syncthreads();
  float b2_0 = a3b[0], b2_1 = a3b[1];
  for (int j=threadIdx.x; j<NN; j+=256) {
    const float* as = asrc + j*64;
    float h1[64];
#pragma unroll
    for (int o4=0;o4<16;o4++){
      f32x4 a4 = *(const f32x4*)(as + o4*4);
      h1[o4*4+0]=fmaxf(a4.x+dsti[o4*4+0],0.f);
      h1[o4*4+1]=fmaxf(a4.y+dsti[o4*4+1],0.f);
      h1[o4*4+2]=fmaxf(a4.z+dsti[o4*4+2],0.f);
      h1[o4*4+3]=fmaxf(a4.w+dsti[o4*4+3],0.f);
    }
    float h2[32];
#pragma unroll
    for(int o=0;o<32;o++){
      float a=a2b[o];
#pragma unroll
      for(int k=0;k<64;k++) a += h1[k]*w2[k*32+o];
      h2[o]=fmaxf(a,0.f);
    }
    float e0=b2_0, e1=b2_1;
#pragma unroll
    for(int k=0;k<32;k++){ e0+=h2[k]*w3s[k*2]; e1+=h2[k]*w3s[k*2+1]; }
    adj[i*NN + j] = e0;
    adj[250000 + i*NN + j] = e1;
  }
}

__global__ __launch_bounds__(256) void k_softmax(const float* __restrict__ adj,
    float* __restrict__ sup_out) {
  int row = blockIdx.x;           // e*500 + i
  int e = row/NN, i = row%NN;
  const float* a = adj + e*250000 + i*NN;
  __shared__ float red[64];
  float m = -1e30f;
  for (int j=threadIdx.x;j<NN;j+=256) m = fmaxf(m, a[j]);
#pragma unroll
  for (int off=32; off; off>>=1) m = fmaxf(m, __shfl_down(m, off));
  int lane = threadIdx.x & 63, wid = threadIdx.x >> 6;
  if (lane==0) red[wid]=m;
  __syncthreads();
  if (threadIdx.x==0){ float mm=red[0]; for(int w=1;w<4;w++) mm=fmaxf(mm,red[w]); red[32]=mm; }
  __syncthreads();
  m = red[32];
  float s=0.f;
  for (int j=threadIdx.x;j<NN;j+=256) s += __expf(a[j]-m);
#pragma unroll
  for (int off=32; off; off>>=1) s += __shfl_down(s, off);
  if (lane==0) red[wid]=s;
  __syncthreads();
  if (threadIdx.x==0){ float ss=0; for(int w=0;w<4;w++) ss+=red[w]; red[33]=ss; }
  __syncthreads();
  float inv = 1.f/red[33];
  for (int j=threadIdx.x;j<NN;j+=256) {
    float val = __expf(a[j]-m)*inv;
    if (j==i) val = 1.f;
    sup_out[e*250000 + i*NN + j] = val;
  }
}

// ST[e][w][v] (bf16, 512x512, zero-padded) from sup[e][v][w] (fp32, 500x500)
__global__ __launch_bounds__(256) void k_tposeS(const float* __restrict__ sup,
    short* __restrict__ ST) {
  __shared__ float ts[64][68];
  int e = blockIdx.z;
  int v0 = blockIdx.x*64, w0 = blockIdx.y*64;
  int tid = threadIdx.x;
  int vv = tid>>2, wc = (tid&3)*16;
  bool vok = (v0+vv) < 500;
#pragma unroll
  for (int c=0;c<4;c++){
    f32x4 val = {0,0,0,0};
    int wg = w0 + wc + c*4;
    if (vok && wg < 500) val = *(const f32x4*)(sup + e*250000 + (size_t)(v0+vv)*500 + wg);
    *(f32x4*)&ts[vv][wc + c*4] = val;
  }
  __syncthreads();
  int w = tid>>2, vc = (tid&3)*16;
  unsigned short u[16];
#pragma unroll
  for (int j=0;j<16;j++) u[j] = f2bf(ts[vc+j][w]);
  int4 o0, o1;
  o0.x = u[0]|(u[1]<<16);  o0.y = u[2]|(u[3]<<16);
  o0.z = u[4]|(u[5]<<16);  o0.w = u[6]|(u[7]<<16);
  o1.x = u[8]|(u[9]<<16);  o1.y = u[10]|(u[11]<<16);
  o1.z = u[12]|(u[13]<<16); o1.w = u[14]|(u[15]<<16);
  short* op = ST + (size_t)e*(512*512) + (size_t)(w0+w)*VS + v0 + vc;
  *(int4*)(op) = o0;
  *(int4*)(op+8) = o1;
}

// GT[b][q][v] (bf16, v padded to 512 w/ zeros) from G[bn][q] fp32
__global__ __launch_bounds__(256) void k_tposeG(const float* __restrict__ G,
    short* __restrict__ GT, int qmax) {
  __shared__ float ts[64][68];
  int b = blockIdx.z;
  int v0 = blockIdx.x*64, q0 = blockIdx.y*64;
  int tid = threadIdx.x;
  int vv = tid>>2, qc = (tid&3)*16;
  bool vok = (v0+vv) < 500;
  const float* gp = G + (size_t)(b*NN + v0+vv)*QS + q0 + qc;
#pragma unroll
  for (int c=0;c<4;c++){
    f32x4 val = {0,0,0,0};
    if (vok && (q0+qc+c*4) < qmax) val = *(const f32x4*)(gp + c*4);
    *(f32x4*)&ts[vv][qc + c*4] = val;
  }
  __syncthreads();
  int q = tid>>2, vc = (tid&3)*16;
  if (q0 + q < qmax) {
    unsigned short u[16];
#pragma unroll
    for (int j=0;j<16;j++) u[j] = f2bf(ts[vc+j][q]);
    int4 o0, o1;
    o0.x = u[0]|(u[1]<<16);  o0.y = u[2]|(u[3]<<16);
    o0.z = u[4]|(u[5]<<16);  o0.w = u[6]|(u[7]<<16);
    o1.x = u[8]|(u[9]<<16);  o1.y = u[10]|(u[11]<<16);
    o1.z = u[12]|(u[13]<<16); o1.w = u[14]|(u[15]<<16);
    short* op = GT + ((size_t)b*QS + q0+q)*VS + v0 + vc;
    *(int4*)(op) = o0;
    *(int4*)(op+8) = o1;
  }
}

// ======= MFMA graph diffusion: OUT[w][q] = sum_v S[v][w]*IN[v][q] ==========
// A = ST[e][w][v] (bf16), B = BT[...][q][v] (bf16). C[m=w][n=q].
template<int WRITE_T>
__global__ __launch_bounds__(256) void k_hop(const short* __restrict__ ST,
    const short* __restrict__ BT, long est_b,
    float* __restrict__ OUT, short* __restrict__ OTT, int qmax) {
  __shared__ __align__(16) short As[64*72];
  __shared__ __align__(16) short Bs[64*72];
  int e = blockIdx.z & 1, b = blockIdx.z >> 1;
  int w0 = blockIdx.x*64, q0 = blockIdx.y*64;
  const short* Ab = ST + (size_t)e*(512*512);
  const short* Bb = BT + (size_t)e*est_b + (size_t)b*(QS*VS);
  int tid = threadIdx.x;
  int row = tid>>2, col = (tid&3)*16;
  const short* ap = Ab + (size_t)(w0+row)*VS + col;
  const short* bp = Bb + (size_t)(q0+row)*VS + col;
  bool bok = (q0+row) < qmax;
  f32x4 zero4 = {0,0,0,0};
  f32x4 ra0 = *(const f32x4*)(ap);
  f32x4 ra1 = *(const f32x4*)(ap+8);
  f32x4 rb0 = bok ? *(const f32x4*)(bp) : zero4;
  f32x4 rb1 = bok ? *(const f32x4*)(bp+8) : zero4;
  int wid = tid>>6, lane = tid&63;
  int wr = wid>>1, wc = wid&1;
  int lm = lane&15, lk = (lane>>4)*8;
  f32x4 acc[2][2] = {};
  short* aw = As + row*72 + col;
  short* bw = Bs + row*72 + col;
  for (int kk=0; kk<8; kk++) {
    __syncthreads();
    *(f32x4*)(aw) = ra0; *(f32x4*)(aw+8) = ra1;
    *(f32x4*)(bw) = rb0; *(f32x4*)(bw+8) = rb1;
    __syncthreads();
    if (kk < 7) {
      const short* ap2 = ap + (kk+1)*64;
      const short* bp2 = bp + (kk+1)*64;
      ra0 = *(const f32x4*)(ap2); ra1 = *(const f32x4*)(ap2+8);
      rb0 = bok ? *(const f32x4*)(bp2) : zero4;
      rb1 = bok ? *(const f32x4*)(bp2+8) : zero4;
    }
#pragma unroll
    for (int ks=0; ks<2; ks++) {
      bf16x8 af0 = *(const bf16x8*)(As + (wr*32 + lm)*72 + ks*32 + lk);
      bf16x8 af1 = *(const bf16x8*)(As + (wr*32 + 16 + lm)*72 + ks*32 + lk);
      bf16x8 bq0 = *(const bf16x8*)(Bs + (wc*32 + lm)*72 + ks*32 + lk);
      bf16x8 bq1 = *(const bf16x8*)(Bs + (wc*32 + 16 + lm)*72 + ks*32 + lk);
      acc[0][0] = __builtin_amdgcn_mfma_f32_16x16x32_bf16(af0, bq0, acc[0][0], 0,0,0);
      acc[0][1] = __builtin_amdgcn_mfma_f32_16x16x32_bf16(af0, bq1, acc[0][1], 0,0,0);
      acc[1][0] = __builtin_amdgcn_mfma_f32_16x16x32_bf16(af1, bq0, acc[1][0], 0,0,0);
      acc[1][1] = __builtin_amdgcn_mfma_f32_16x16x32_bf16(af1, bq1, acc[1][1], 0,0,0);
    }
  }
  float* Ob = OUT + (size_t)e*(2*(size_t)DSZ) + (size_t)b*(NN*QS);
#pragma unroll
  for (int fm=0; fm<2; fm++) {
    int wb4 = w0 + wr*32 + fm*16 + (lane>>4)*4;
#pragma unroll
    for (int fn=0; fn<2; fn++) {
      int q = q0 + wc*32 + fn*16 + lm;
      if (q < qmax) {
        f32x4 v4 = acc[fm][fn];
        if (wb4 < 500) {
          float* op = Ob + (size_t)wb4*QS + q;
          op[0*QS] = v4.x; op[1*QS] = v4.y; op[2*QS] = v4.z; op[3*QS] = v4.w;
        }
        if (WRITE_T) {
          int2 pv = {0,0};
          if (wb4 < 500) { pv.x = pk2(v4.x, v4.y); pv.y = pk2(v4.z, v4.w); }
          short* tp = OTT + (size_t)e*DTE + (size_t)b*(QS*VS) + (size_t)q*VS + wb4;
          *(int2*)(tp) = pv;
        }
      }
    }
  }
}

// ================= input projection / enter conv =================

__global__ void k_proj(const float* __restrict__ inputs, const float* __restrict__ factor,
                       float* __restrict__ proj) {
  int bt = blockIdx.x;
  __shared__ float xin[NN*2];
  for (int idx=threadIdx.x; idx<NN*2; idx+=64) xin[idx] = inputs[bt*NN*2 + idx];
  __syncthreads();
  int u = threadIdx.x>>1, f = threadIdx.x&1;
  float acc=0.f;
  for (int n=0;n<NN;n++) acc += xin[n*2+f]*factor[n*UU+u];
  proj[bt*64 + u*2+f] = acc;
}

__global__ __launch_bounds__(256) void k_enter(const float* __restrict__ inputs,
    const float* __restrict__ factor, const float* __restrict__ proj,
    const float* __restrict__ ew, const float* __restrict__ eb, float* __restrict__ X) {
  int idx = blockIdx.x*256+threadIdx.x;
  if (idx >= BB*NN*TX) return;
  int t = idx % TX; int n = (idx/TX)%NN; int b = idx/(TX*NN);
  float x4[4]={0.f,0.f,0.f,0.f};
  if (t>0) {
    int tt=t-1;
    float s0=0.f,s1=0.f;
    const float* pr = proj + (b*TT+tt)*64;
    const float* fr = factor + n*UU;
#pragma unroll
    for(int u=0;u<UU;u++){ s0 += pr[u*2]*fr[u]; s1 += pr[u*2+1]*fr[u]; }
    float i0 = inputs[((b*TT+tt)*NN+n)*2];
    float i1 = inputs[((b*TT+tt)*NN+n)*2+1];
    x4[0]=s0; x4[1]=s1; x4[2]=i0-s0; x4[3]=i1-s1;
  }
  float* xp = X + ((size_t)(b*NN+n)*TX + t)*CC;
#pragma unroll
  for(int o=0;o<CC;o++){
    xp[o] = eb[o] + ew[o*4]*x4[0] + ew[o*4+1]*x4[1] + ew[o*4+2]*x4[2] + ew[o*4+3]*x4[3];
  }
}

// ================= gated temporal conv =================

__global__ __launch_bounds__(256) void k_gated2(const float* __restrict__ X,
    float* __restrict__ G, float* __restrict__ Glast,
    const float* __restrict__ fw, const float* __restrict__ fb,
    const float* __restrict__ gw, const float* __restrict__ gb,
    const float* __restrict__ stat, int use_stat, int d, int t_out, int lidx) {
  __shared__ __align__(16) float As[64][68];
  __shared__ __align__(16) float Ws[64][64];
  __shared__ __align__(16) float scs[32];
  __shared__ __align__(16) float shs[32];
  int tid = threadIdx.x;
  if (tid < 32) {
    scs[tid] = use_stat ? stat[tid] : 1.0f;
    shs[tid] = use_stat ? stat[32 + tid] : 0.0f;
  }
  for (int i = tid; i < 2048; i += 256) {
    int o = i >> 6, k = i & 63;
    Ws[k][o] = fw[i];
    Ws[k][32 + o] = gw[i];
  }
  __syncthreads();
  int m0 = blockIdx.x * 64;
  {
    int mm = tid & 63;
    int kb = (tid >> 6) * 16;
    int c0 = kb >> 1;
    int m = m0 + mm;
    int bn = m / t_out, t = m - bn * t_out;
    const float* xr = X + (size_t)bn * (TX * CC);
    float4 a0 = *(const float4*)(xr + t * 32 + c0);
    float4 a1 = *(const float4*)(xr + t * 32 + c0 + 4);
    float4 b0 = *(const float4*)(xr + (t + d) * 32 + c0);
    float4 b1 = *(const float4*)(xr + (t + d) * 32 + c0 + 4);
    float va[8] = {a0.x,a0.y,a0.z,a0.w,a1.x,a1.y,a1.z,a1.w};
    float vb[8] = {b0.x,b0.y,b0.z,b0.w,b1.x,b1.y,b1.z,b1.w};
#pragma unroll
    for (int j = 0; j < 8; j++) {
      float sc = scs[c0+j], sh = shs[c0+j];
      As[kb + 2*j][mm]     = va[j]*sc + sh;
      As[kb + 2*j + 1][mm] = vb[j]*sc + sh;
    }
  }
  __syncthreads();
  int tm = tid >> 4, tn = tid & 15;
  float acc[4][4] = {};
#pragma unroll 8
  for (int k = 0; k < 64; k++) {
    float4 av = *(const float4*)&As[k][tm*4];
    float4 bv = *(const float4*)&Ws[k][tn*4];
    acc[0][0]+=av.x*bv.x; acc[0][1]+=av.x*bv.y; acc[0][2]+=av.x*bv.z; acc[0][3]+=av.x*bv.w;
    acc[1][0]+=av.y*bv.x; acc[1][1]+=av.y*bv.y; acc[1][2]+=av.y*bv.z; acc[1][3]+=av.y*bv.w;
    acc[2][0]+=av.z*bv.x; acc[2][1]+=av.z*bv.y; acc[2][2]+=av.z*bv.z; acc[2][3]+=av.z*bv.w;
    acc[3][0]+=av.w*bv.x; acc[3][1]+=av.w*bv.y; acc[3][2]+=av.w*bv.z; acc[3][3]+=av.w*bv.w;
  }
  float gx[4][4];
#pragma unroll
  for (int i=0;i<4;i++)
#pragma unroll
    for (int j=0;j<4;j++) gx[i][j] = __shfl_xor(acc[i][j], 8);
  if (tn < 8) {
    int o0 = tn*4;
    float4 fb4 = *(const float4*)(fb + o0);
    float4 gb4 = *(const float4*)(gb + o0);
    float fbv[4] = {fb4.x,fb4.y,fb4.z,fb4.w};
    float gbv[4] = {gb4.x,gb4.y,gb4.z,gb4.w};
#pragma unroll
    for (int i=0;i<4;i++) {
      int m = m0 + tm*4 + i;
      int bn = m / t_out, t = m - bn*t_out;
      float ov[4];
#pragma unroll
      for (int j=0;j<4;j++) {
        float f = acc[i][j] + fbv[j];
        float g = gx[i][j] + gbv[j];
        float th = 2.f/(1.f+__expf(-2.f*f)) - 1.f;
        float sg = 1.f/(1.f+__expf(-g));
        ov[j] = th*sg;
      }
      float4 o4 = make_float4(ov[0],ov[1],ov[2],ov[3]);
      *(float4*)(G + (size_t)bn*(TG*CC) + t*32 + o0) = o4;
      if (t == t_out-1)
        *(float4*)(Glast + (size_t)bn*256 + lidx*32 + o0) = o4;
    }
  }
}

// ======= graph-conv 1x1 + residual + BN partials ====

__global__ __launch_bounds__(256) void k_gc2(const float* __restrict__ G,
    const float* __restrict__ D, const float* __restrict__ Xc, float* __restrict__ Xn,
    const float* __restrict__ gcw, const float* __restrict__ gcb,
    const float* __restrict__ stat, int use_stat,
    float* __restrict__ part, int d, int t_out) {
  __shared__ __align__(16) float As[32][132];
  __shared__ __align__(16) float Ws[160][32];
  __shared__ __align__(16) float scs[32];
  __shared__ __align__(16) float shs[32];
  __shared__ __align__(16) float wred[4][64];
  int tid = threadIdx.x;
  if (tid < 32) {
    scs[tid] = use_stat ? stat[tid] : 1.0f;
    shs[tid] = use_stat ? stat[32 + tid] : 0.0f;
  }
  for (int i = tid; i < 5120; i += 256) {
    int kk = i >> 5, o = i & 31;
    Ws[kk][o] = gcw[o*160 + kk];
  }
  int m0 = blockIdx.x * 128;
  int tm = tid >> 3, tn = tid & 7;
  float acc[4][4] = {};
  int mm = tid & 127, kb = (tid >> 7) * 16;
  int m_s = m0 + mm;
  int bn_s = m_s / t_out, t_s = m_s - bn_s*t_out;
  size_t soff = (size_t)bn_s*(TG*CC) + t_s*32 + kb;
  const float* srcs[5] = {G, D, D+DSZ, D+2*(size_t)DSZ, D+3*(size_t)DSZ};
  for (int s = 0; s < 5; s++) {
    const float* sr = srcs[s] + soff;
    float4 r0 = *(const float4*)(sr);
    float4 r1 = *(const float4*)(sr+4);
    float4 r2 = *(const float4*)(sr+8);
    float4 r3 = *(const float4*)(sr+12);
    __syncthreads();
    float vv[16] = {r0.x,r0.y,r0.z,r0.w, r1.x,r1.y,r1.z,r1.w,
                    r2.x,r2.y,r2.z,r2.w, r3.x,r3.y,r3.z,r3.w};
#pragma unroll
    for (int j=0;j<16;j++) As[kb+j][mm] = vv[j];
    __syncthreads();
#pragma unroll 8
    for (int k=0;k<32;k++) {
      float4 av = *(const float4*)&As[k][tm*4];
      float4 bv = *(const float4*)&Ws[s*32+k][tn*4];
      acc[0][0]+=av.x*bv.x; acc[0][1]+=av.x*bv.y; acc[0][2]+=av.x*bv.z; acc[0][3]+=av.x*bv.w;
      acc[1][0]+=av.y*bv.x; acc[1][1]+=av.y*bv.y; acc[1][2]+=av.y*bv.z; acc[1][3]+=av.y*bv.w;
      acc[2][0]+=av.z*bv.x; acc[2][1]+=av.z*bv.y; acc[2][2]+=av.z*bv.z; acc[2][3]+=av.z*bv.w;
      acc[3][0]+=av.w*bv.x; acc[3][1]+=av.w*bv.y; acc[3][2]+=av.w*bv.z; acc[3][3]+=av.w*bv.w;
    }
  }
  int n0 = tn*4;
  float4 gcb4 = *(const float4*)(gcb + n0);
  float scv[4] = {scs[n0],scs[n0+1],scs[n0+2],scs[n0+3]};
  float shv[4] = {shs[n0],shs[n0+1],shs[n0+2],shs[n0+3]};
  float gb4[4] = {gcb4.x,gcb4.y,gcb4.z,gcb4.w};
  float s_sum[4] = {0,0,0,0}, s_ssq[4] = {0,0,0,0};
#pragma unroll
  for (int i=0;i<4;i++){
    int m = m0 + tm*4 + i;
    int bn = m / t_out, t = m - bn*t_out;
    float4 res = *(const float4*)(Xc + (size_t)bn*(TX*CC) + (t+d)*32 + n0);
    float rv[4] = {res.x,res.y,res.z,res.w};
    float ov[4];
#pragma unroll
    for (int j=0;j<4;j++){
      float val = acc[i][j] + gb4[j] + rv[j]*scv[j] + shv[j];
      ov[j] = val;
      s_sum[j] += val;
      s_ssq[j] += val*val;
    }
    *(float4*)(Xn + (size_t)bn*(TX*CC) + t*32 + n0) = make_float4(ov[0],ov[1],ov[2],ov[3]);
  }
#pragma unroll
  for (int off=8; off<=32; off<<=1){
#pragma unroll
    for (int j=0;j<4;j++){
      s_sum[j] += __shfl_xor(s_sum[j], off);
      s_ssq[j] += __shfl_xor(s_ssq[j], off);
    }
  }
  int lane = tid & 63, wid = tid >> 6;
  if (lane < 8){
#pragma unroll
    for (int j=0;j<4;j++){
      wred[wid][lane*4+j]      = s_sum[j];
      wred[wid][32+lane*4+j]   = s_ssq[j];
    }
  }
  __syncthreads();
  if (tid < 64){
    float vsum = wred[0][tid]+wred[1][tid]+wred[2][tid]+wred[3][tid];
    part[(size_t)blockIdx.x*64 + tid] = vsum;
  }
}

__global__ __launch_bounds__(256) void k_stat(const float* __restrict__ part, int nblk,
    const float* __restrict__ g, const float* __restrict__ b,
    float* __restrict__ statout, float cntinv) {
  __shared__ float red[4][64];
  int tid = threadIdx.x;
  int slot = tid & 63, grp = tid >> 6;
  float acc = 0.f;
  for (int i = grp; i < nblk; i += 4) acc += part[(size_t)i*64 + slot];
  red[grp][slot] = acc;
  __syncthreads();
  if (tid < 64) red[0][tid] = red[0][tid]+red[1][tid]+red[2][tid]+red[3][tid];
  __syncthreads();
  if (tid < 32){
    float s = red[0][tid], ss = red[0][32+tid];
    float m = s*cntinv, var = ss*cntinv - m*m;
    float sc = rsqrtf(var + BN_EPS)*g[tid];
    statout[tid] = sc;
    statout[32+tid] = b[tid] - m*sc;
  }
}

// ================= output head =================

__global__ void k_wstack(const float* __restrict__ skp_w, const float* __restrict__ skp_b,
                         float* __restrict__ Wst, float* __restrict__ bsum) {
  int idx = blockIdx.x*256 + threadIdx.x;
  int kk = idx >> 8, o = idx & 255;
  Wst[idx] = skp_w[(kk>>5)*8192 + o*32 + (kk&31)];
  if (idx < 256){
    float s=0.f;
    for (int l=0;l<8;l++) s += skp_b[l*256+idx];
    bsum[idx]=s;
  }
}

__global__ __launch_bounds__(256) void k_skipgemm(const float* __restrict__ Gl,
    const float* __restrict__ Wst, const float* __restrict__ bsum, float* __restrict__ skipv) {
  int m0 = blockIdx.x*64, n0 = blockIdx.y*64;
  __shared__ __align__(16) float As[16][64];
  __shared__ __align__(16) float Bs[16][64];
  float acc[4][4]={};
  int tm=threadIdx.x>>4, tn=threadIdx.x&15;
  int mm = threadIdx.x>>2, k4=(threadIdx.x&3)*4;
  int ks = threadIdx.x>>4, n4 = (threadIdx.x&15)*4;
  for (int k0=0;k0<256;k0+=16){
    float4 va = *(const float4*)(Gl + (size_t)(m0+mm)*256 + k0+k4);
    float4 vb = *(const float4*)(Wst + (size_t)(k0+ks)*256 + n0+n4);
    __syncthreads();
    As[k4+0][mm]=va.x; As[k4+1][mm]=va.y; As[k4+2][mm]=va.z; As[k4+3][mm]=va.w;
    *(float4*)&Bs[ks][n4] = vb;
    __syncthreads();
#pragma unroll
    for (int k=0;k<16;k++){
      float4 av = *(const float4*)&As[k][tm*4];
      float4 bv = *(const float4*)&Bs[k][tn*4];
      acc[0][0]+=av.x*bv.x; acc[0][1]+=av.x*bv.y; acc[0][2]+=av.x*bv.z; acc[0][3]+=av.x*bv.w;
      acc[1][0]+=av.y*bv.x; acc[1][1]+=av.y*bv.y; acc[1][2]+=av.y*bv.z; acc[1][3]+=av.y*bv.w;
      acc[2][0]+=av.z*bv.x; acc[2][1]+=av.z*bv.y; acc[2][2]+=av.z*bv.z; acc[2][3]+=av.z*bv.w;
      acc[3][0]+=av.w*bv.x; acc[3][1]+=av.w*bv.y; acc[3][2]+=av.w*bv.z; acc[3][3]+=av.w*bv.w;
    }
    __syncthreads();
  }
  float4 bs4 = *(const float4*)(bsum + n0 + tn*4);
  float bv[4] = {bs4.x,bs4.y,bs4.z,bs4.w};
#pragma unroll
  for (int i=0;i<4;i++){
    int m = m0 + tm*4 + i;
    float4 r;
    r.x = fmaxf(acc[i][0]+bv[0], 0.f);
    r.y = fmaxf(acc[i][1]+bv[1], 0.f);
    r.z = fmaxf(acc[i][2]+bv[2], 0.f);
    r.w = fmaxf(acc[i][3]+bv[3], 0.f);
    *(float4*)(skipv + (size_t)m*256 + n0 + tn*4) = r;
  }
}

__global__ __launch_bounds__(256) void k_head1(const float* __restrict__ skipv,
    const float* __restrict__ o1w, const float* __restrict__ o1b, float* __restrict__ Y1) {
  int m0 = blockIdx.x*64, n0 = blockIdx.y*64;
  __shared__ __align__(16) float As[16][64];
  __shared__ __align__(16) float Bs[16][64];
  float acc[4][4]={};
  int tm=threadIdx.x>>4, tn=threadIdx.x&15;
  int mm = threadIdx.x>>2, k4=(threadIdx.x&3)*4;
  for (int k0=0;k0<NSKIPC;k0+=16){
    float4 va = *(const float4*)(skipv + (size_t)(m0+mm)*NSKIPC + k0+k4);
    float4 vb = *(const float4*)(o1w + (size_t)(n0+mm)*NSKIPC + k0+k4);
    __syncthreads();
    As[k4+0][mm]=va.x; As[k4+1][mm]=va.y; As[k4+2][mm]=va.z; As[k4+3][mm]=va.w;
    Bs[k4+0][mm]=vb.x; Bs[k4+1][mm]=vb.y; Bs[k4+2][mm]=vb.z; Bs[k4+3][mm]=vb.w;
    __syncthreads();
#pragma unroll
    for (int k=0;k<16;k++){
      float4 av = *(const float4*)&As[k][tm*4];
      float4 bv = *(const float4*)&Bs[k][tn*4];
      acc[0][0]+=av.x*bv.x; acc[0][1]+=av.x*bv.y; acc[0][2]+=av.x*bv.z; acc[0][3]+=av.x*bv.w;
      acc[1][0]+=av.y*bv.x; acc[1][1]+=av.y*bv.y; acc[1][2]+=av.y*bv.z; acc[1][3]+=av.y*bv.w;
      acc[2][0]+=av.z*bv.x; acc[2][1]+=av.z*bv.y; acc[2][2]+=av.z*bv.z; acc[2][3]+=av.z*bv.w;
      acc[3][0]+=av.w*bv.x; acc[3][1]+=av.w*bv.y; acc[3][2]+=av.w*bv.z; acc[3][3]+=av.w*bv.w;
    }
    __syncthreads();
  }
  float4 bias = *(const float4*)(o1b + n0 + tn*4);
  float bv[4] = {bias.x,bias.y,bias.z,bias.w};
#pragma unroll
  for (int i=0;i<4;i++){
    int m = m0 + tm*4 + i;
    float4 r;
    r.x = fmaxf(acc[i][0]+bv[0], 0.f);
    r.y = fmaxf(acc[i][1]+bv[1], 0.f);
    r.z = fmaxf(acc[i][2]+bv[2], 0.f);
    r.w = fmaxf(acc[i][3]+bv[3], 0.f);
    *(float4*)(Y1 + (size_t)m*NENDC + n0 + tn*4) = r;
  }
}

__global__ __launch_bounds__(256) void k_head2(const float* __restrict__ Y1,
    const float* __restrict__ o2w, const float* __restrict__ o2b, float* __restrict__ y) {
  int m = blockIdx.x*256+threadIdx.x;
  if (m >= BNN) return;
  float accs[NPREDC];
#pragma unroll
  for (int p=0;p<NPREDC;p++) accs[p]=o2b[p];
  for (int e=0;e<NENDC;e+=4){
    float4 yv = *(const float4*)(Y1 + (size_t)m*NENDC + e);
#pragma unroll
    for (int p=0;p<NPREDC;p++){
      accs[p] += o2w[p*NENDC+e]*yv.x + o2w[p*NENDC+e+1]*yv.y
               + o2w[p*NENDC+e+2]*yv.z + o2w[p*NENDC+e+3]*yv.w;
    }
  }
  int b=m/NN, n=m%NN;
#pragma unroll
  for (int p=0;p<NPREDC;p++) y[(b*NPREDC+p)*NN+n]=accs[p];
}

// ================= host =================

extern "C" void kernel_launch(void* const* d_in, const int* in_sizes, int n_in,
                              void* d_out, int out_size, void* d_ws, size_t ws_size,
                              hipStream_t stream) {
  const float* inputs  = (const float*)d_in[0];
  const float* factor  = (const float*)d_in[1];
  const float* map_w   = (const float*)d_in[2];
  const float* map_b   = (const float*)d_in[3];
  const float* a1w     = (const float*)d_in[4];
  const float* a1b     = (const float*)d_in[5];
  const float* a2w     = (const float*)d_in[6];
  const float* a2b     = (const float*)d_in[7];
  const float* a3w     = (const float*)d_in[8];
  const float* a3b     = (const float*)d_in[9];
  const float* enter_w = (const float*)d_in[10];
  const float* enter_b = (const float*)d_in[11];
  const float* filt_w  = (const float*)d_in[12];
  const float* filt_b  = (const float*)d_in[13];
  const float* gate_w  = (const float*)d_in[14];
  const float* gate_b  = (const float*)d_in[15];
  const float* skp_w   = (const float*)d_in[16];
  const float* skp_b   = (const float*)d_in[17];
  const float* gc_w    = (const float*)d_in[18];
  const float* gc_b    = (const float*)d_in[19];
  const float* bn_g    = (const float*)d_in[20];
  const float* bn_b    = (const float*)d_in[21];
  const float* o1w     = (const float*)d_in[22];
  const float* o1b     = (const float*)d_in[23];
  const float* o2w     = (const float*)d_in[24];
  const float* o2b     = (const float*)d_in[25];
  (void)in_sizes; (void)n_in; (void)out_size; (void)ws_size;

  float* ws = (float*)d_ws;
  float* v      = ws + OFF_V;
  float* adj    = ws + OFF_ADJ;
  float* asrc   = ws + OFF_ASRC;
  float* proj   = ws + OFF_PROJ;
  float* Glast  = ws + OFF_GLAST;
  float* Wst    = ws + OFF_WSTACK;
  float* bsum   = ws + OFF_BSUM;
  float* statb  = ws + OFF_STAT;
  float* part   = ws + OFF_PART;
  float* X      = ws + OFF_X;
  float* Xn     = ws + OFF_XN;
  float* G      = ws + OFF_G;
  float* D      = ws + OFF_D;
  float* skipv  = ws + OFF_SKIPV;
  float* Y1     = ws + OFF_Y1;
  short* ST     = (short*)(ws + OFF_ST);
  short* GT     = (short*)(ws + OFF_GT);
  short* DT     = (short*)(ws + OFF_DT);

  float* y_out   = (float*)d_out;
  float* sup_out = y_out + BB*NPREDC*NN;   // 192000

  // adaptive supports
  k_v<<<NN, 32, 0, stream>>>(factor, map_w, map_b, v);
  k_asrc<<<NN, 64, 0, stream>>>(v, a1w, asrc);
  k_pair2<<<NN, 256, 0, stream>>>(v, asrc, a1w, a1b, a2w, a2b, a3w, a3b, adj);
  k_softmax<<<2*NN, 256, 0, stream>>>(adj, sup_out);
  {
    dim3 gt(8, 8, 2);
    k_tposeS<<<gt, 256, 0, stream>>>(sup_out, ST);
  }

  // input split + enter
  k_proj<<<BB*TT, 64, 0, stream>>>(inputs, factor, proj);
  k_enter<<<(BB*NN*TX+255)/256, 256, 0, stream>>>(inputs, factor, proj, enter_w, enter_b, X);

  // skip weight stack (independent)
  k_wstack<<<256, 256, 0, stream>>>(skp_w, skp_b, Wst, bsum);

  float* Xc = X; float* Xo = Xn;
  int t = TX;
  static const int dil[8]={1,2,1,2,1,2,1,2};
  for (int l=0;l<7;l++){
    int d=dil[l], t_out=t-d;
    const float* st = statb + (l>0 ? (l-1)*64 : 0);
    k_gated2<<<250*t_out,256,0,stream>>>(Xc, G, Glast, filt_w + l*2048, filt_b + l*32,
                                         gate_w + l*2048, gate_b + l*32, st, l>0, d, t_out, l);
    int qmax = t_out*CC;
    int qt = (qmax+63)/64;
    dim3 gtp(8, qt, 32);
    k_tposeG<<<gtp,256,0,stream>>>(G, GT, qmax);
    dim3 ghp(8, qt, 64);
    k_hop<1><<<ghp,256,0,stream>>>(ST, GT, (long)0, D, DT, qmax);
    k_hop<0><<<ghp,256,0,stream>>>(ST, DT, (long)DTE, D+DSZ, DT, qmax);
    int ntiles = 125*t_out;
    k_gc2<<<ntiles,256,0,stream>>>(G, D, Xc, Xo, gc_w + l*5120, gc_b + l*32,
                                   st, l>0, part, d, t_out);
    k_stat<<<1,256,0,stream>>>(part, ntiles, bn_g + l*32, bn_b + l*32,
                               statb + l*64, 1.f/(16000.f*(float)t_out));
    float* tmp=Xc; Xc=Xo; Xo=tmp;
    t = t_out;
  }
  // layer 8 (l=7): only gated conv feeds skip; diffusion/GC/BN are dead
  k_gated2<<<250*1,256,0,stream>>>(Xc, G, Glast, filt_w + 7*2048, filt_b + 7*32,
                                   gate_w + 7*2048, gate_b + 7*32, statb + 6*64, 1, 2, 1, 7);

  // head
  dim3 gs(BNN/64, 256/64);
  k_skipgemm<<<gs,256,0,stream>>>(Glast, Wst, bsum, skipv);
  dim3 gh(BNN/64, NENDC/64);
  k_head1<<<gh,256,0,stream>>>(skipv, o1w, o1b, Y1);
  k_head2<<<(BNN+255)/256,256,0,stream>>>(Y1, o2w, o2b, y_out);
}

// Round 4
// 1279.044 us; speedup vs baseline: 6.4723x; 1.2773x over previous
//
#include <hip/hip_runtime.h>
#include <math.h>

// ---- static config ----
#define BB 32
#define TT 12
#define NN 500
#define UU 32
#define CC 32
#define NSKIPC 256
#define NENDC 512
#define NPREDC 12
#define TX 13
#define TG 12
#define QS 384
#define VS 512
#define BNN (BB*NN)
#define DSZ (BNN*TG*CC)
#define BN_EPS 1e-5f

// ---- workspace offsets (floats) ----
#define OFF_V      0u
#define OFF_ADJ    16000u
#define OFF_ASRC   516000u
#define OFF_ADST   548000u
#define OFF_PROJ   580000u
#define OFF_GLAST  582048u
#define OFF_WSTACK 4678048u
#define OFF_BSUM   4743584u
#define OFF_STAT   4743840u
#define OFF_PART   4744352u
#define OFF_X      4936352u
#define OFF_XN     11592352u
#define OFF_G      18248352u
#define OFF_D      24392352u     // 4*6144000 -> ends 48968352
#define OFF_SKIPV  OFF_D
#define OFF_Y1     (OFF_D + 4096000u)
#define OFF_ST     48968352u     // bf16 2*512*512 = 262144 floats
#define OFF_SB     49230496u     // bf16 2*512*512
#define OFF_ST2    49492640u     // bf16 2*512*512 -> ends 49754784

typedef __attribute__((ext_vector_type(8))) short bf16x8;
typedef __attribute__((ext_vector_type(4))) float f32x4;

__device__ inline unsigned short f2bf(float f) {
  union { float f; unsigned u; } x; x.f = f;
  unsigned r = x.u + 0x7FFFu + ((x.u >> 16) & 1u);
  return (unsigned short)(r >> 16);
}
__device__ inline int pk2(float a, float b) {
  return (int)((unsigned)f2bf(a) | ((unsigned)f2bf(b) << 16));
}
__device__ inline bf16x8 pack8(f32x4 a, f32x4 b) {
  union { int i[4]; bf16x8 v; } u;
  u.i[0]=pk2(a.x,a.y); u.i[1]=pk2(a.z,a.w);
  u.i[2]=pk2(b.x,b.y); u.i[3]=pk2(b.z,b.w);
  return u.v;
}
__device__ inline f32x4 reluadd(f32x4 a, f32x4 b) {
  f32x4 r;
  r.x=fmaxf(a.x+b.x,0.f); r.y=fmaxf(a.y+b.y,0.f);
  r.z=fmaxf(a.z+b.z,0.f); r.w=fmaxf(a.w+b.w,0.f);
  return r;
}

// ================= adaptive supports =================

__global__ void k_v(const float* __restrict__ factor, const float* __restrict__ map_w,
                    const float* __restrict__ map_b, float* __restrict__ v) {
  int n = blockIdx.x; int d = threadIdx.x;
  __shared__ float fr[UU];
  fr[d] = factor[n*UU + d];
  __syncthreads();
  float acc = map_b[d];
#pragma unroll
  for (int u=0;u<UU;u++) acc += fr[u]*map_w[u*32+d];
  v[n*32+d] = fmaxf(acc, 0.f);
}

// asrc[n][o] = sum_u v[n][u]*a1w[u][o];  adst[n][o] = a1b[o] + sum_u v[n][u]*a1w[32+u][o]
__global__ void k_asrc2(const float* __restrict__ v, const float* __restrict__ a1w,
                        const float* __restrict__ a1b,
                        float* __restrict__ asrc, float* __restrict__ adst) {
  int n = blockIdx.x; int o = threadIdx.x; // 64 threads
  __shared__ float vn[32];
  if (o < 32) vn[o] = v[n*32+o];
  __syncthreads();
  float s = 0.f, dst = a1b[o];
#pragma unroll
  for (int u=0;u<32;u++){ s += vn[u]*a1w[u*64+o]; dst += vn[u]*a1w[(32+u)*64+o]; }
  asrc[n*64+o] = s;
  adst[n*64+o] = dst;
}

// MFMA pair MLP: adj[e][i][j]
__global__ __launch_bounds__(256) void k_pair3(const float* __restrict__ asrc,
    const float* __restrict__ adst, const float* __restrict__ a2w,
    const float* __restrict__ a2b, const float* __restrict__ a3w,
    const float* __restrict__ a3b, float* __restrict__ adj) {
  int i = blockIdx.x;
  int tid = threadIdx.x;
  int wid = tid>>6, lane = tid&63;
  int lm = lane&15, g = lane>>4, lk8 = g*8;
  int jb = blockIdx.y*256 + wid*64;
  bf16x8 wf[2][2];
#pragma unroll
  for (int ks=0;ks<2;ks++)
#pragma unroll
    for (int nh=0;nh<2;nh++){
      int n = nh*16+lm;
      f32x4 lo, hi;
      lo.x=a2w[(ks*32+lk8+0)*32+n]; lo.y=a2w[(ks*32+lk8+1)*32+n];
      lo.z=a2w[(ks*32+lk8+2)*32+n]; lo.w=a2w[(ks*32+lk8+3)*32+n];
      hi.x=a2w[(ks*32+lk8+4)*32+n]; hi.y=a2w[(ks*32+lk8+5)*32+n];
      hi.z=a2w[(ks*32+lk8+6)*32+n]; hi.w=a2w[(ks*32+lk8+7)*32+n];
      wf[ks][nh] = pack8(lo, hi);
    }
  float b20 = a2b[lm], b21 = a2b[16+lm];
  float w3e0n0 = a3w[lm*2],      w3e1n0 = a3w[lm*2+1];
  float w3e0n1 = a3w[(16+lm)*2], w3e1n1 = a3w[(16+lm)*2+1];
  float b30 = a3b[0], b31 = a3b[1];
  const float* dp = adst + i*64;
  f32x4 d00 = *(const f32x4*)(dp + lk8);
  f32x4 d01 = *(const f32x4*)(dp + lk8 + 4);
  f32x4 d10 = *(const f32x4*)(dp + 32 + lk8);
  f32x4 d11 = *(const f32x4*)(dp + 32 + lk8 + 4);
#pragma unroll
  for (int mg=0; mg<4; mg++){
    int j = jb + mg*16 + lm;
    int jc = j < 500 ? j : 0;
    const float* ap = asrc + jc*64;
    f32x4 s00=*(const f32x4*)(ap+lk8),    s01=*(const f32x4*)(ap+lk8+4);
    f32x4 s10=*(const f32x4*)(ap+32+lk8), s11=*(const f32x4*)(ap+32+lk8+4);
    bf16x8 a0 = pack8(reluadd(s00,d00), reluadd(s01,d01));
    bf16x8 a1 = pack8(reluadd(s10,d10), reluadd(s11,d11));
    f32x4 acc0 = {b20,b20,b20,b20};
    f32x4 acc1 = {b21,b21,b21,b21};
    acc0 = __builtin_amdgcn_mfma_f32_16x16x32_bf16(a0, wf[0][0], acc0, 0,0,0);
    acc0 = __builtin_amdgcn_mfma_f32_16x16x32_bf16(a1, wf[1][0], acc0, 0,0,0);
    acc1 = __builtin_amdgcn_mfma_f32_16x16x32_bf16(a0, wf[0][1], acc1, 0,0,0);
    acc1 = __builtin_amdgcn_mfma_f32_16x16x32_bf16(a1, wf[1][1], acc1, 0,0,0);
    float e0[4], e1[4];
#pragma unroll
    for (int r=0;r<4;r++){
      float h2a = fmaxf(acc0[r],0.f), h2b = fmaxf(acc1[r],0.f);
      e0[r] = h2a*w3e0n0 + h2b*w3e0n1;
      e1[r] = h2a*w3e1n0 + h2b*w3e1n1;
    }
#pragma unroll
    for (int off=1; off<16; off<<=1){
#pragma unroll
      for (int r=0;r<4;r++){ e0[r]+=__shfl_xor(e0[r],off); e1[r]+=__shfl_xor(e1[r],off); }
    }
    if (lm==0){
      int j4 = jb + mg*16 + g*4;
      if (j4 < 500){
        f32x4 v0={e0[0]+b30,e0[1]+b30,e0[2]+b30,e0[3]+b30};
        f32x4 v1={e1[0]+b31,e1[1]+b31,e1[2]+b31,e1[3]+b31};
        *(f32x4*)(adj + i*500 + j4) = v0;
        *(f32x4*)(adj + 250000 + i*500 + j4) = v1;
      }
    }
  }
}

__global__ __launch_bounds__(256) void k_softmax(const float* __restrict__ adj,
    float* __restrict__ sup_out) {
  int row = blockIdx.x;
  int e = row/NN, i = row%NN;
  const float* a = adj + e*250000 + i*NN;
  __shared__ float red[64];
  float m = -1e30f;
  for (int j=threadIdx.x;j<NN;j+=256) m = fmaxf(m, a[j]);
#pragma unroll
  for (int off=32; off; off>>=1) m = fmaxf(m, __shfl_down(m, off));
  int lane = threadIdx.x & 63, wid = threadIdx.x >> 6;
  if (lane==0) red[wid]=m;
  __syncthreads();
  if (threadIdx.x==0){ float mm=red[0]; for(int w=1;w<4;w++) mm=fmaxf(mm,red[w]); red[32]=mm; }
  __syncthreads();
  m = red[32];
  float s=0.f;
  for (int j=threadIdx.x;j<NN;j+=256) s += __expf(a[j]-m);
#pragma unroll
  for (int off=32; off; off>>=1) s += __shfl_down(s, off);
  if (lane==0) red[wid]=s;
  __syncthreads();
  if (threadIdx.x==0){ float ss=0; for(int w=0;w<4;w++) ss+=red[w]; red[33]=ss; }
  __syncthreads();
  float inv = 1.f/red[33];
  for (int j=threadIdx.x;j<NN;j+=256) {
    float val = __expf(a[j]-m)*inv;
    if (j==i) val = 1.f;
    sup_out[e*250000 + i*NN + j] = val;
  }
}

// ST[e][w][v] (bf16 transposed, padded) + SB[e][v][w] (bf16 cast, padded)
__global__ __launch_bounds__(256) void k_tposeS(const float* __restrict__ sup,
    short* __restrict__ ST, short* __restrict__ SB) {
  __shared__ float ts[64][68];
  int e = blockIdx.z;
  int v0 = blockIdx.x*64, w0 = blockIdx.y*64;
  int tid = threadIdx.x;
  int vv = tid>>2, wc = (tid&3)*16;
  bool vok = (v0+vv) < 500;
#pragma unroll
  for (int c=0;c<4;c++){
    f32x4 val = {0,0,0,0};
    int wg = w0 + wc + c*4;
    if (vok && wg < 500) val = *(const f32x4*)(sup + e*250000 + (size_t)(v0+vv)*500 + wg);
    *(f32x4*)&ts[vv][wc + c*4] = val;
    int2 pv; pv.x = pk2(val.x, val.y); pv.y = pk2(val.z, val.w);
    *(int2*)(SB + (size_t)e*(512*512) + (size_t)(v0+vv)*VS + wg) = pv;
  }
  __syncthreads();
  int w = tid>>2, vc = (tid&3)*16;
  unsigned short u[16];
#pragma unroll
  for (int j=0;j<16;j++) u[j] = f2bf(ts[vc+j][w]);
  int4 o0, o1;
  o0.x = u[0]|(u[1]<<16);  o0.y = u[2]|(u[3]<<16);
  o0.z = u[4]|(u[5]<<16);  o0.w = u[6]|(u[7]<<16);
  o1.x = u[8]|(u[9]<<16);  o1.y = u[10]|(u[11]<<16);
  o1.z = u[12]|(u[13]<<16); o1.w = u[14]|(u[15]<<16);
  short* op = ST + (size_t)e*(512*512) + (size_t)(w0+w)*VS + v0 + vc;
  *(int4*)(op) = o0;
  *(int4*)(op+8) = o1;
}

// ST2[e] = (S@S)^T : C[u][w] = sum_v SB[u][v]*ST[w][v], stored transposed
__global__ __launch_bounds__(256) void k_ssq(const short* __restrict__ SB,
    const short* __restrict__ ST, short* __restrict__ ST2) {
  __shared__ __align__(16) short As[64*72];
  __shared__ __align__(16) short Bs[64*72];
  int e = blockIdx.z;
  int u0 = blockIdx.x*64, w0 = blockIdx.y*64;
  const short* Ab = SB + (size_t)e*(512*512);
  const short* Bb = ST + (size_t)e*(512*512);
  int tid = threadIdx.x;
  int row = tid>>2, col = (tid&3)*16;
  const short* ap = Ab + (size_t)(u0+row)*VS + col;
  const short* bp = Bb + (size_t)(w0+row)*VS + col;
  f32x4 ra0 = *(const f32x4*)(ap);
  f32x4 ra1 = *(const f32x4*)(ap+8);
  f32x4 rb0 = *(const f32x4*)(bp);
  f32x4 rb1 = *(const f32x4*)(bp+8);
  int wid = tid>>6, lane = tid&63;
  int wr = wid>>1, wc = wid&1;
  int lm = lane&15, lk = (lane>>4)*8;
  f32x4 acc[2][2] = {};
  short* aw = As + row*72 + col;
  short* bw = Bs + row*72 + col;
  for (int kk=0; kk<8; kk++) {
    __syncthreads();
    *(f32x4*)(aw) = ra0; *(f32x4*)(aw+8) = ra1;
    *(f32x4*)(bw) = rb0; *(f32x4*)(bw+8) = rb1;
    __syncthreads();
    if (kk < 7) {
      const short* ap2 = ap + (kk+1)*64;
      const short* bp2 = bp + (kk+1)*64;
      ra0 = *(const f32x4*)(ap2); ra1 = *(const f32x4*)(ap2+8);
      rb0 = *(const f32x4*)(bp2); rb1 = *(const f32x4*)(bp2+8);
    }
#pragma unroll
    for (int ks=0; ks<2; ks++) {
      bf16x8 af0 = *(const bf16x8*)(As + (wr*32 + lm)*72 + ks*32 + lk);
      bf16x8 af1 = *(const bf16x8*)(As + (wr*32 + 16 + lm)*72 + ks*32 + lk);
      bf16x8 bq0 = *(const bf16x8*)(Bs + (wc*32 + lm)*72 + ks*32 + lk);
      bf16x8 bq1 = *(const bf16x8*)(Bs + (wc*32 + 16 + lm)*72 + ks*32 + lk);
      acc[0][0] = __builtin_amdgcn_mfma_f32_16x16x32_bf16(af0, bq0, acc[0][0], 0,0,0);
      acc[0][1] = __builtin_amdgcn_mfma_f32_16x16x32_bf16(af0, bq1, acc[0][1], 0,0,0);
      acc[1][0] = __builtin_amdgcn_mfma_f32_16x16x32_bf16(af1, bq0, acc[1][0], 0,0,0);
      acc[1][1] = __builtin_amdgcn_mfma_f32_16x16x32_bf16(af1, bq1, acc[1][1], 0,0,0);
    }
  }
#pragma unroll
  for (int fm=0; fm<2; fm++) {
    int u4 = u0 + wr*32 + fm*16 + (lane>>4)*4;
#pragma unroll
    for (int fn=0; fn<2; fn++) {
      int w = w0 + wc*32 + fn*16 + lm;
      f32x4 v4 = acc[fm][fn];
      int2 pv; pv.x = pk2(v4.x, v4.y); pv.y = pk2(v4.z, v4.w);
      *(int2*)(ST2 + (size_t)e*(512*512) + (size_t)w*VS + u4) = pv;
    }
  }
}

// GT[b][q][v] (bf16, padded) from G fp32
__global__ __launch_bounds__(256) void k_tposeG(const float* __restrict__ G,
    short* __restrict__ GT, int qmax) {
  __shared__ float ts[64][68];
  int b = blockIdx.z;
  int v0 = blockIdx.x*64, q0 = blockIdx.y*64;
  int tid = threadIdx.x;
  int vv = tid>>2, qc = (tid&3)*16;
  bool vok = (v0+vv) < 500;
  const float* gp = G + (size_t)(b*NN + v0+vv)*QS + q0 + qc;
#pragma unroll
  for (int c=0;c<4;c++){
    f32x4 val = {0,0,0,0};
    if (vok && (q0+qc+c*4) < qmax) val = *(const f32x4*)(gp + c*4);
    *(f32x4*)&ts[vv][qc + c*4] = val;
  }
  __syncthreads();
  int q = tid>>2, vc = (tid&3)*16;
  if (q0 + q < qmax) {
    unsigned short u[16];
#pragma unroll
    for (int j=0;j<16;j++) u[j] = f2bf(ts[vc+j][q]);
    int4 o0, o1;
    o0.x = u[0]|(u[1]<<16);  o0.y = u[2]|(u[3]<<16);
    o0.z = u[4]|(u[5]<<16);  o0.w = u[6]|(u[7]<<16);
    o1.x = u[8]|(u[9]<<16);  o1.y = u[10]|(u[11]<<16);
    o1.z = u[12]|(u[13]<<16); o1.w = u[14]|(u[15]<<16);
    short* op = GT + ((size_t)b*QS + q0+q)*VS + v0 + vc;
    *(int4*)(op) = o0;
    *(int4*)(op+8) = o1;
  }
}

// MFMA diffusion hop: OUT[w][q] = sum_v A[w][v]*GT[q][v]
__global__ __launch_bounds__(256) void k_hop(const short* __restrict__ A,
    const short* __restrict__ GT, float* __restrict__ OUT, int qmax) {
  __shared__ __align__(16) short As[64*72];
  __shared__ __align__(16) short Bs[64*72];
  int e = blockIdx.z & 1, b = blockIdx.z >> 1;
  int w0 = blockIdx.x*64, q0 = blockIdx.y*64;
  const short* Ab = A + (size_t)e*(512*512);
  const short* Bb = GT + (size_t)b*(QS*VS);
  int tid = threadIdx.x;
  int row = tid>>2, col = (tid&3)*16;
  const short* ap = Ab + (size_t)(w0+row)*VS + col;
  const short* bp = Bb + (size_t)(q0+row)*VS + col;
  bool bok = (q0+row) < qmax;
  f32x4 zero4 = {0,0,0,0};
  f32x4 ra0 = *(const f32x4*)(ap);
  f32x4 ra1 = *(const f32x4*)(ap+8);
  f32x4 rb0 = bok ? *(const f32x4*)(bp) : zero4;
  f32x4 rb1 = bok ? *(const f32x4*)(bp+8) : zero4;
  int wid = tid>>6, lane = tid&63;
  int wr = wid>>1, wc = wid&1;
  int lm = lane&15, lk = (lane>>4)*8;
  f32x4 acc[2][2] = {};
  short* aw = As + row*72 + col;
  short* bw = Bs + row*72 + col;
  for (int kk=0; kk<8; kk++) {
    __syncthreads();
    *(f32x4*)(aw) = ra0; *(f32x4*)(aw+8) = ra1;
    *(f32x4*)(bw) = rb0; *(f32x4*)(bw+8) = rb1;
    __syncthreads();
    if (kk < 7) {
      const short* ap2 = ap + (kk+1)*64;
      const short* bp2 = bp + (kk+1)*64;
      ra0 = *(const f32x4*)(ap2); ra1 = *(const f32x4*)(ap2+8);
      rb0 = bok ? *(const f32x4*)(bp2) : zero4;
      rb1 = bok ? *(const f32x4*)(bp2+8) : zero4;
    }
#pragma unroll
    for (int ks=0; ks<2; ks++) {
      bf16x8 af0 = *(const bf16x8*)(As + (wr*32 + lm)*72 + ks*32 + lk);
      bf16x8 af1 = *(const bf16x8*)(As + (wr*32 + 16 + lm)*72 + ks*32 + lk);
      bf16x8 bq0 = *(const bf16x8*)(Bs + (wc*32 + lm)*72 + ks*32 + lk);
      bf16x8 bq1 = *(const bf16x8*)(Bs + (wc*32 + 16 + lm)*72 + ks*32 + lk);
      acc[0][0] = __builtin_amdgcn_mfma_f32_16x16x32_bf16(af0, bq0, acc[0][0], 0,0,0);
      acc[0][1] = __builtin_amdgcn_mfma_f32_16x16x32_bf16(af0, bq1, acc[0][1], 0,0,0);
      acc[1][0] = __builtin_amdgcn_mfma_f32_16x16x32_bf16(af1, bq0, acc[1][0], 0,0,0);
      acc[1][1] = __builtin_amdgcn_mfma_f32_16x16x32_bf16(af1, bq1, acc[1][1], 0,0,0);
    }
  }
  float* Ob = OUT + (size_t)e*(2*(size_t)DSZ) + (size_t)b*(NN*QS);
#pragma unroll
  for (int fm=0; fm<2; fm++) {
    int wb4 = w0 + wr*32 + fm*16 + (lane>>4)*4;
    if (wb4 >= 500) continue;
#pragma unroll
    for (int fn=0; fn<2; fn++) {
      int q = q0 + wc*32 + fn*16 + lm;
      if (q < qmax) {
        f32x4 v4 = acc[fm][fn];
        float* op = Ob + (size_t)wb4*QS + q;
        op[0*QS] = v4.x; op[1*QS] = v4.y; op[2*QS] = v4.z; op[3*QS] = v4.w;
      }
    }
  }
}

// ================= input projection / enter conv =================

__global__ void k_proj(const float* __restrict__ inputs, const float* __restrict__ factor,
                       float* __restrict__ proj) {
  int bt = blockIdx.x;
  __shared__ float xin[NN*2];
  for (int idx=threadIdx.x; idx<NN*2; idx+=64) xin[idx] = inputs[bt*NN*2 + idx];
  __syncthreads();
  int u = threadIdx.x>>1, f = threadIdx.x&1;
  float acc=0.f;
  for (int n=0;n<NN;n++) acc += xin[n*2+f]*factor[n*UU+u];
  proj[bt*64 + u*2+f] = acc;
}

__global__ __launch_bounds__(256) void k_enter(const float* __restrict__ inputs,
    const float* __restrict__ factor, const float* __restrict__ proj,
    const float* __restrict__ ew, const float* __restrict__ eb, float* __restrict__ X) {
  int idx = blockIdx.x*256+threadIdx.x;
  if (idx >= BB*NN*TX) return;
  int t = idx % TX; int n = (idx/TX)%NN; int b = idx/(TX*NN);
  float x4[4]={0.f,0.f,0.f,0.f};
  if (t>0) {
    int tt=t-1;
    float s0=0.f,s1=0.f;
    const float* pr = proj + (b*TT+tt)*64;
    const float* fr = factor + n*UU;
#pragma unroll
    for(int u=0;u<UU;u++){ s0 += pr[u*2]*fr[u]; s1 += pr[u*2+1]*fr[u]; }
    float i0 = inputs[((b*TT+tt)*NN+n)*2];
    float i1 = inputs[((b*TT+tt)*NN+n)*2+1];
    x4[0]=s0; x4[1]=s1; x4[2]=i0-s0; x4[3]=i1-s1;
  }
  float* xp = X + ((size_t)(b*NN+n)*TX + t)*CC;
#pragma unroll
  for(int o=0;o<CC;o++){
    xp[o] = eb[o] + ew[o*4]*x4[0] + ew[o*4+1]*x4[1] + ew[o*4+2]*x4[2] + ew[o*4+3]*x4[3];
  }
}

// ================= gated temporal conv =================

__global__ __launch_bounds__(256) void k_gated2(const float* __restrict__ X,
    float* __restrict__ G, float* __restrict__ Glast,
    const float* __restrict__ fw, const float* __restrict__ fb,
    const float* __restrict__ gw, const float* __restrict__ gb,
    const float* __restrict__ stat, int use_stat, int d, int t_out, int lidx) {
  __shared__ __align__(16) float As[64][68];
  __shared__ __align__(16) float Ws[64][64];
  __shared__ __align__(16) float scs[32];
  __shared__ __align__(16) float shs[32];
  int tid = threadIdx.x;
  if (tid < 32) {
    scs[tid] = use_stat ? stat[tid] : 1.0f;
    shs[tid] = use_stat ? stat[32 + tid] : 0.0f;
  }
  for (int i = tid; i < 2048; i += 256) {
    int o = i >> 6, k = i & 63;
    Ws[k][o] = fw[i];
    Ws[k][32 + o] = gw[i];
  }
  __syncthreads();
  int m0 = blockIdx.x * 64;
  {
    int mm = tid & 63;
    int kb = (tid >> 6) * 16;
    int c0 = kb >> 1;
    int m = m0 + mm;
    int bn = m / t_out, t = m - bn * t_out;
    const float* xr = X + (size_t)bn * (TX * CC);
    float4 a0 = *(const float4*)(xr + t * 32 + c0);
    float4 a1 = *(const float4*)(xr + t * 32 + c0 + 4);
    float4 b0 = *(const float4*)(xr + (t + d) * 32 + c0);
    float4 b1 = *(const float4*)(xr + (t + d) * 32 + c0 + 4);
    float va[8] = {a0.x,a0.y,a0.z,a0.w,a1.x,a1.y,a1.z,a1.w};
    float vb[8] = {b0.x,b0.y,b0.z,b0.w,b1.x,b1.y,b1.z,b1.w};
#pragma unroll
    for (int j = 0; j < 8; j++) {
      float sc = scs[c0+j], sh = shs[c0+j];
      As[kb + 2*j][mm]     = va[j]*sc + sh;
      As[kb + 2*j + 1][mm] = vb[j]*sc + sh;
    }
  }
  __syncthreads();
  int tm = tid >> 4, tn = tid & 15;
  float acc[4][4] = {};
#pragma unroll 8
  for (int k = 0; k < 64; k++) {
    float4 av = *(const float4*)&As[k][tm*4];
    float4 bv = *(const float4*)&Ws[k][tn*4];
    acc[0][0]+=av.x*bv.x; acc[0][1]+=av.x*bv.y; acc[0][2]+=av.x*bv.z; acc[0][3]+=av.x*bv.w;
    acc[1][0]+=av.y*bv.x; acc[1][1]+=av.y*bv.y; acc[1][2]+=av.y*bv.z; acc[1][3]+=av.y*bv.w;
    acc[2][0]+=av.z*bv.x; acc[2][1]+=av.z*bv.y; acc[2][2]+=av.z*bv.z; acc[2][3]+=av.z*bv.w;
    acc[3][0]+=av.w*bv.x; acc[3][1]+=av.w*bv.y; acc[3][2]+=av.w*bv.z; acc[3][3]+=av.w*bv.w;
  }
  float gx[4][4];
#pragma unroll
  for (int i=0;i<4;i++)
#pragma unroll
    for (int j=0;j<4;j++) gx[i][j] = __shfl_xor(acc[i][j], 8);
  if (tn < 8) {
    int o0 = tn*4;
    float4 fb4 = *(const float4*)(fb + o0);
    float4 gb4 = *(const float4*)(gb + o0);
    float fbv[4] = {fb4.x,fb4.y,fb4.z,fb4.w};
    float gbv[4] = {gb4.x,gb4.y,gb4.z,gb4.w};
#pragma unroll
    for (int i=0;i<4;i++) {
      int m = m0 + tm*4 + i;
      int bn = m / t_out, t = m - bn*t_out;
      float ov[4];
#pragma unroll
      for (int j=0;j<4;j++) {
        float f = acc[i][j] + fbv[j];
        float g = gx[i][j] + gbv[j];
        float th = 2.f/(1.f+__expf(-2.f*f)) - 1.f;
        float sg = 1.f/(1.f+__expf(-g));
        ov[j] = th*sg;
      }
      float4 o4 = make_float4(ov[0],ov[1],ov[2],ov[3]);
      *(float4*)(G + (size_t)bn*(TG*CC) + t*32 + o0) = o4;
      if (t == t_out-1)
        *(float4*)(Glast + (size_t)bn*256 + lidx*32 + o0) = o4;
    }
  }
}

// ======= MFMA graph-conv 1x1 + residual + BN partials =======

template<int TOUT>
__global__ __launch_bounds__(64) void k_gc3(const float* __restrict__ G,
    const float* __restrict__ D, const float* __restrict__ Xc, float* __restrict__ Xn,
    const float* __restrict__ gcw, const float* __restrict__ gcb,
    const float* __restrict__ stat, int use_stat, float* __restrict__ part, int d) {
  int tid = threadIdx.x;
  int lm = tid&15, g = tid>>4, lk8 = g*8;
  const float* srcs[5] = {G, D, D+(size_t)DSZ, D+2*(size_t)DSZ, D+3*(size_t)DSZ};
  bf16x8 wf[5][2];
#pragma unroll
  for (int ks=0;ks<5;ks++)
#pragma unroll
    for (int nh=0;nh<2;nh++){
      const float* wp = gcw + (nh*16+lm)*160 + ks*32 + lk8;
      wf[ks][nh] = pack8(*(const f32x4*)wp, *(const f32x4*)(wp+4));
    }
  float scn0 = use_stat ? stat[lm]    : 1.f;
  float scn1 = use_stat ? stat[16+lm] : 1.f;
  float shn0 = use_stat ? stat[32+lm] : 0.f;
  float shn1 = use_stat ? stat[48+lm] : 0.f;
  float gb0 = gcb[lm], gb1 = gcb[16+lm];
  int m0 = blockIdx.x*64;
  float ss0=0.f, sq0=0.f, ss1=0.f, sq1=0.f;
#pragma unroll
  for (int mg=0; mg<4; mg++){
    int m = m0 + mg*16 + lm;
    int bn = m / TOUT; int t = m - bn*TOUT;
    size_t off = (size_t)bn*(TG*CC) + t*32 + lk8;
    f32x4 acc0={0,0,0,0}, acc1={0,0,0,0};
#pragma unroll
    for (int ks=0;ks<5;ks++){
      const float* sp = srcs[ks] + off;
      bf16x8 af = pack8(*(const f32x4*)sp, *(const f32x4*)(sp+4));
      acc0 = __builtin_amdgcn_mfma_f32_16x16x32_bf16(af, wf[ks][0], acc0, 0,0,0);
      acc1 = __builtin_amdgcn_mfma_f32_16x16x32_bf16(af, wf[ks][1], acc1, 0,0,0);
    }
#pragma unroll
    for (int r=0;r<4;r++){
      int mr = m0 + mg*16 + g*4 + r;
      int bnr = mr / TOUT; int tr = mr - bnr*TOUT;
      size_t xoff = (size_t)bnr*(TX*CC);
      float r0 = Xc[xoff + (tr+d)*32 + lm];
      float r1 = Xc[xoff + (tr+d)*32 + 16 + lm];
      float v0 = acc0[r] + gb0 + r0*scn0 + shn0;
      float v1 = acc1[r] + gb1 + r1*scn1 + shn1;
      Xn[xoff + tr*32 + lm] = v0;
      Xn[xoff + tr*32 + 16 + lm] = v1;
      ss0+=v0; sq0+=v0*v0; ss1+=v1; sq1+=v1*v1;
    }
  }
#pragma unroll
  for (int off=16; off<64; off<<=1){
    ss0+=__shfl_xor(ss0,off); sq0+=__shfl_xor(sq0,off);
    ss1+=__shfl_xor(ss1,off); sq1+=__shfl_xor(sq1,off);
  }
  if (tid<16){
    float* pp = part + (size_t)blockIdx.x*64;
    pp[tid]=ss0; pp[16+tid]=ss1; pp[32+tid]=sq0; pp[48+tid]=sq1;
  }
}

__global__ __launch_bounds__(256) void k_stat2(const float* __restrict__ part, int nblk,
    const float* __restrict__ g, const float* __restrict__ b,
    float* __restrict__ statout, float cntinv) {
  __shared__ float red[16][64];
  int tid = threadIdx.x;
  int s4 = (tid&15)*4, rg = tid>>4;
  f32x4 acc = {0,0,0,0};
  for (int i=rg; i<nblk; i+=16){
    const f32x4 v = *(const f32x4*)(part + (size_t)i*64 + s4);
    acc.x+=v.x; acc.y+=v.y; acc.z+=v.z; acc.w+=v.w;
  }
  *(f32x4*)&red[rg][s4] = acc;
  __syncthreads();
  if (tid < 64){
    float s=0.f;
#pragma unroll
    for (int r=0;r<16;r++) s += red[r][tid];
    red[0][tid] = s;
  }
  __syncthreads();
  if (tid < 32){
    float s = red[0][tid], sq = red[0][32+tid];
    float m = s*cntinv, var = sq*cntinv - m*m;
    float sc = rsqrtf(var + BN_EPS)*g[tid];
    statout[tid] = sc;
    statout[32+tid] = b[tid] - m*sc;
  }
}

// ================= output head =================

__global__ void k_wstack(const float* __restrict__ skp_w, const float* __restrict__ skp_b,
                         float* __restrict__ Wst, float* __restrict__ bsum) {
  int idx = blockIdx.x*256 + threadIdx.x;
  int kk = idx >> 8, o = idx & 255;
  Wst[idx] = skp_w[(kk>>5)*8192 + o*32 + (kk&31)];
  if (idx < 256){
    float s=0.f;
    for (int l=0;l<8;l++) s += skp_b[l*256+idx];
    bsum[idx]=s;
  }
}

__global__ __launch_bounds__(256) void k_skipgemm(const float* __restrict__ Gl,
    const float* __restrict__ Wst, const float* __restrict__ bsum, float* __restrict__ skipv) {
  int m0 = blockIdx.x*64, n0 = blockIdx.y*64;
  __shared__ __align__(16) float As[16][64];
  __shared__ __align__(16) float Bs[16][64];
  float acc[4][4]={};
  int tm=threadIdx.x>>4, tn=threadIdx.x&15;
  int mm = threadIdx.x>>2, k4=(threadIdx.x&3)*4;
  int ks = threadIdx.x>>4, n4 = (threadIdx.x&15)*4;
  for (int k0=0;k0<256;k0+=16){
    float4 va = *(const float4*)(Gl + (size_t)(m0+mm)*256 + k0+k4);
    float4 vb = *(const float4*)(Wst + (size_t)(k0+ks)*256 + n0+n4);
    __syncthreads();
    As[k4+0][mm]=va.x; As[k4+1][mm]=va.y; As[k4+2][mm]=va.z; As[k4+3][mm]=va.w;
    *(float4*)&Bs[ks][n4] = vb;
    __syncthreads();
#pragma unroll
    for (int k=0;k<16;k++){
      float4 av = *(const float4*)&As[k][tm*4];
      float4 bv = *(const float4*)&Bs[k][tn*4];
      acc[0][0]+=av.x*bv.x; acc[0][1]+=av.x*bv.y; acc[0][2]+=av.x*bv.z; acc[0][3]+=av.x*bv.w;
      acc[1][0]+=av.y*bv.x; acc[1][1]+=av.y*bv.y; acc[1][2]+=av.y*bv.z; acc[1][3]+=av.y*bv.w;
      acc[2][0]+=av.z*bv.x; acc[2][1]+=av.z*bv.y; acc[2][2]+=av.z*bv.z; acc[2][3]+=av.z*bv.w;
      acc[3][0]+=av.w*bv.x; acc[3][1]+=av.w*bv.y; acc[3][2]+=av.w*bv.z; acc[3][3]+=av.w*bv.w;
    }
    __syncthreads();
  }
  float4 bs4 = *(const float4*)(bsum + n0 + tn*4);
  float bv[4] = {bs4.x,bs4.y,bs4.z,bs4.w};
#pragma unroll
  for (int i=0;i<4;i++){
    int m = m0 + tm*4 + i;
    float4 r;
    r.x = fmaxf(acc[i][0]+bv[0], 0.f);
    r.y = fmaxf(acc[i][1]+bv[1], 0.f);
    r.z = fmaxf(acc[i][2]+bv[2], 0.f);
    r.w = fmaxf(acc[i][3]+bv[3], 0.f);
    *(float4*)(skipv + (size_t)m*256 + n0 + tn*4) = r;
  }
}

__global__ __launch_bounds__(256) void k_head1(const float* __restrict__ skipv,
    const float* __restrict__ o1w, const float* __restrict__ o1b, float* __restrict__ Y1) {
  int m0 = blockIdx.x*64, n0 = blockIdx.y*64;
  __shared__ __align__(16) float As[16][64];
  __shared__ __align__(16) float Bs[16][64];
  float acc[4][4]={};
  int tm=threadIdx.x>>4, tn=threadIdx.x&15;
  int mm = threadIdx.x>>2, k4=(threadIdx.x&3)*4;
  for (int k0=0;k0<NSKIPC;k0+=16){
    float4 va = *(const float4*)(skipv + (size_t)(m0+mm)*NSKIPC + k0+k4);
    float4 vb = *(const float4*)(o1w + (size_t)(n0+mm)*NSKIPC + k0+k4);
    __syncthreads();
    As[k4+0][mm]=va.x; As[k4+1][mm]=va.y; As[k4+2][mm]=va.z; As[k4+3][mm]=va.w;
    Bs[k4+0][mm]=vb.x; Bs[k4+1][mm]=vb.y; Bs[k4+2][mm]=vb.z; Bs[k4+3][mm]=vb.w;
    __syncthreads();
#pragma unroll
    for (int k=0;k<16;k++){
      float4 av = *(const float4*)&As[k][tm*4];
      float4 bv = *(const float4*)&Bs[k][tn*4];
      acc[0][0]+=av.x*bv.x; acc[0][1]+=av.x*bv.y; acc[0][2]+=av.x*bv.z; acc[0][3]+=av.x*bv.w;
      acc[1][0]+=av.y*bv.x; acc[1][1]+=av.y*bv.y; acc[1][2]+=av.y*bv.z; acc[1][3]+=av.y*bv.w;
      acc[2][0]+=av.z*bv.x; acc[2][1]+=av.z*bv.y; acc[2][2]+=av.z*bv.z; acc[2][3]+=av.z*bv.w;
      acc[3][0]+=av.w*bv.x; acc[3][1]+=av.w*bv.y; acc[3][2]+=av.w*bv.z; acc[3][3]+=av.w*bv.w;
    }
    __syncthreads();
  }
  float4 bias = *(const float4*)(o1b + n0 + tn*4);
  float bv[4] = {bias.x,bias.y,bias.z,bias.w};
#pragma unroll
  for (int i=0;i<4;i++){
    int m = m0 + tm*4 + i;
    float4 r;
    r.x = fmaxf(acc[i][0]+bv[0], 0.f);
    r.y = fmaxf(acc[i][1]+bv[1], 0.f);
    r.z = fmaxf(acc[i][2]+bv[2], 0.f);
    r.w = fmaxf(acc[i][3]+bv[3], 0.f);
    *(float4*)(Y1 + (size_t)m*NENDC + n0 + tn*4) = r;
  }
}

__global__ __launch_bounds__(256) void k_head2b(const float* __restrict__ Y1,
    const float* __restrict__ o2w, const float* __restrict__ o2b, float* __restrict__ y) {
  int tid = threadIdx.x;
  int ml = tid>>2, kc = tid&3;        // 64 m x 4 k-chunks
  int m = blockIdx.x*64 + ml;
  float accs[NPREDC] = {};
  for (int e=kc*128; e<kc*128+128; e+=4){
    f32x4 yv = *(const f32x4*)(Y1 + (size_t)m*NENDC + e);
#pragma unroll
    for (int p=0;p<NPREDC;p++){
      accs[p] += o2w[p*NENDC+e]*yv.x + o2w[p*NENDC+e+1]*yv.y
               + o2w[p*NENDC+e+2]*yv.z + o2w[p*NENDC+e+3]*yv.w;
    }
  }
#pragma unroll
  for (int off=1; off<4; off<<=1)
#pragma unroll
    for (int p=0;p<NPREDC;p++) accs[p] += __shfl_xor(accs[p], off);
  if (kc==0){
    int b=m/NN, n=m%NN;
#pragma unroll
    for (int p=0;p<NPREDC;p++) y[(b*NPREDC+p)*NN+n] = accs[p] + o2b[p];
  }
}

// ================= host =================

extern "C" void kernel_launch(void* const* d_in, const int* in_sizes, int n_in,
                              void* d_out, int out_size, void* d_ws, size_t ws_size,
                              hipStream_t stream) {
  const float* inputs  = (const float*)d_in[0];
  const float* factor  = (const float*)d_in[1];
  const float* map_w   = (const float*)d_in[2];
  const float* map_b   = (const float*)d_in[3];
  const float* a1w     = (const float*)d_in[4];
  const float* a1b     = (const float*)d_in[5];
  const float* a2w     = (const float*)d_in[6];
  const float* a2b     = (const float*)d_in[7];
  const float* a3w     = (const float*)d_in[8];
  const float* a3b     = (const float*)d_in[9];
  const float* enter_w = (const float*)d_in[10];
  const float* enter_b = (const float*)d_in[11];
  const float* filt_w  = (const float*)d_in[12];
  const float* filt_b  = (const float*)d_in[13];
  const float* gate_w  = (const float*)d_in[14];
  const float* gate_b  = (const float*)d_in[15];
  const float* skp_w   = (const float*)d_in[16];
  const float* skp_b   = (const float*)d_in[17];
  const float* gc_w    = (const float*)d_in[18];
  const float* gc_b    = (const float*)d_in[19];
  const float* bn_g    = (const float*)d_in[20];
  const float* bn_b    = (const float*)d_in[21];
  const float* o1w     = (const float*)d_in[22];
  const float* o1b     = (const float*)d_in[23];
  const float* o2w     = (const float*)d_in[24];
  const float* o2b     = (const float*)d_in[25];
  (void)in_sizes; (void)n_in; (void)out_size; (void)ws_size;

  float* ws = (float*)d_ws;
  float* v      = ws + OFF_V;
  float* adj    = ws + OFF_ADJ;
  float* asrc   = ws + OFF_ASRC;
  float* adst   = ws + OFF_ADST;
  float* proj   = ws + OFF_PROJ;
  float* Glast  = ws + OFF_GLAST;
  float* Wst    = ws + OFF_WSTACK;
  float* bsum   = ws + OFF_BSUM;
  float* statb  = ws + OFF_STAT;
  float* part   = ws + OFF_PART;
  float* X      = ws + OFF_X;
  float* Xn     = ws + OFF_XN;
  float* G      = ws + OFF_G;
  float* D      = ws + OFF_D;
  float* skipv  = ws + OFF_SKIPV;
  float* Y1     = ws + OFF_Y1;
  short* ST     = (short*)(ws + OFF_ST);
  short* SB     = (short*)(ws + OFF_SB);
  short* ST2    = (short*)(ws + OFF_ST2);

  float* y_out   = (float*)d_out;
  float* sup_out = y_out + BB*NPREDC*NN;

  // adaptive supports
  k_v<<<NN, 32, 0, stream>>>(factor, map_w, map_b, v);
  k_asrc2<<<NN, 64, 0, stream>>>(v, a1w, a1b, asrc, adst);
  {
    dim3 gp(NN, 2);
    k_pair3<<<gp, 256, 0, stream>>>(asrc, adst, a2w, a2b, a3w, a3b, adj);
  }
  k_softmax<<<2*NN, 256, 0, stream>>>(adj, sup_out);
  {
    dim3 gt(8, 8, 2);
    k_tposeS<<<gt, 256, 0, stream>>>(sup_out, ST, SB);
    dim3 gq(8, 8, 2);
    k_ssq<<<gq, 256, 0, stream>>>(SB, ST, ST2);
  }

  // input split + enter
  k_proj<<<BB*TT, 64, 0, stream>>>(inputs, factor, proj);
  k_enter<<<(BB*NN*TX+255)/256, 256, 0, stream>>>(inputs, factor, proj, enter_w, enter_b, X);

  // skip weight stack
  k_wstack<<<256, 256, 0, stream>>>(skp_w, skp_b, Wst, bsum);

  float* Xc = X; float* Xo = Xn;
  int t = TX;
  static const int dil[8]={1,2,1,2,1,2,1,2};
  for (int l=0;l<7;l++){
    int d=dil[l], t_out=t-d;
    const float* st = statb + (l>0 ? (l-1)*64 : 0);
    k_gated2<<<250*t_out,256,0,stream>>>(Xc, G, Glast, filt_w + l*2048, filt_b + l*32,
                                         gate_w + l*2048, gate_b + l*32, st, l>0, d, t_out, l);
    int qmax = t_out*CC;
    int qt = (qmax+63)/64;
    dim3 gtp(8, qt, 32);
    k_tposeG<<<gtp,256,0,stream>>>(G, (short*)(ws + OFF_ST2) == ST2 ? (short*)(ws + 49102496u) : (short*)(ws + 49102496u), qmax); // placeholder never taken
    // NOTE: GT buffer lives right after ST2 region; define locally:
    ;
    dim3 ghp(8, qt, 64);
    short* GT = (short*)(ws + 49754784u);   // 6291456 shorts = 3145728 floats
    k_tposeG<<<gtp,256,0,stream>>>(G, GT, qmax);
    k_hop<<<ghp,256,0,stream>>>(ST,  GT, D,       qmax);
    k_hop<<<ghp,256,0,stream>>>(ST2, GT, D + (size_t)DSZ, qmax);
    int nblk = 250*t_out;
    const float* gcwl = gc_w + l*5120;
    const float* gcbl = gc_b + l*32;
    switch (t_out){
      case 12: k_gc3<12><<<nblk,64,0,stream>>>(G,D,Xc,Xo,gcwl,gcbl,st,l>0,part,d); break;
      case 10: k_gc3<10><<<nblk,64,0,stream>>>(G,D,Xc,Xo,gcwl,gcbl,st,l>0,part,d); break;
      case  9: k_gc3< 9><<<nblk,64,0,stream>>>(G,D,Xc,Xo,gcwl,gcbl,st,l>0,part,d); break;
      case  7: k_gc3< 7><<<nblk,64,0,stream>>>(G,D,Xc,Xo,gcwl,gcbl,st,l>0,part,d); break;
      case  6: k_gc3< 6><<<nblk,64,0,stream>>>(G,D,Xc,Xo,gcwl,gcbl,st,l>0,part,d); break;
      case  4: k_gc3< 4><<<nblk,64,0,stream>>>(G,D,Xc,Xo,gcwl,gcbl,st,l>0,part,d); break;
      default: k_gc3< 3><<<nblk,64,0,stream>>>(G,D,Xc,Xo,gcwl,gcbl,st,l>0,part,d); break;
    }
    k_stat2<<<1,256,0,stream>>>(part, nblk, bn_g + l*32, bn_b + l*32,
                                statb + l*64, 1.f/(16000.f*(float)t_out));
    float* tmp=Xc; Xc=Xo; Xo=tmp;
    t = t_out;
  }
  // layer 8: only gated conv feeds skip
  k_gated2<<<250*1,256,0,stream>>>(Xc, G, Glast, filt_w + 7*2048, filt_b + 7*32,
                                   gate_w + 7*2048, gate_b + 7*32, statb + 6*64, 1, 2, 1, 7);

  // head
  dim3 gs(BNN/64, 256/64);
  k_skipgemm<<<gs,256,0,stream>>>(Glast, Wst, bsum, skipv);
  dim3 gh(BNN/64, NENDC/64);
  k_head1<<<gh,256,0,stream>>>(skipv, o1w, o1b, Y1);
  k_head2b<<<BNN/64,256,0,stream>>>(Y1, o2w, o2b, y_out);
}

// Round 5
// 1004.026 us; speedup vs baseline: 8.2452x; 1.2739x over previous
//
#include <hip/hip_runtime.h>
#include <math.h>

// ---- static config ----
#define BB 32
#define TT 12
#define NN 500
#define UU 32
#define CC 32
#define NSKIPC 256
#define NENDC 512
#define NPREDC 12
#define TX 13
#define TG 12
#define QS 384
#define VS 512
#define BNN (BB*NN)
#define DSZ (BNN*TG*CC)
#define BN_EPS 1e-5f

// ---- workspace offsets (floats) ----
#define OFF_V      0u
#define OFF_ADJ    16000u
#define OFF_ASRC   516000u
#define OFF_ADST   548000u
#define OFF_PROJ   580000u
#define OFF_STAT   582048u
#define OFF_PART   582560u
#define OFF_BSUM   774560u
#define OFF_X      774816u
#define OFF_XN     7430816u
#define OFF_D      14086816u     // 4*6144000 -> 38662816
#define OFF_GBF    38662816u     // shorts 6144000 (G bf16 [16000][384])
#define OFF_GLB    41734816u     // shorts 4096000 (Glast bf16 [16000][256])
#define OFF_GT     43782816u     // shorts 6291456
#define OFF_ST     46928544u     // shorts 524288
#define OFF_SB     47190688u
#define OFF_ST2    47452832u
#define OFF_WSTB   47714976u     // shorts 65536
#define OFF_O1WB   47747744u     // shorts 131072
#define OFF_SKV    47813280u     // shorts 4096000 (skipv bf16)
#define OFF_Y1B    49861280u     // shorts 8192000 (Y1 bf16) -> ends 53957280

typedef __attribute__((ext_vector_type(8))) short bf16x8;
typedef __attribute__((ext_vector_type(4))) float f32x4;

__device__ inline unsigned short f2bf(float f) {
  union { float f; unsigned u; } x; x.f = f;
  unsigned r = x.u + 0x7FFFu + ((x.u >> 16) & 1u);
  return (unsigned short)(r >> 16);
}
__device__ inline float bf2f(short s) {
  union { float f; unsigned u; } x;
  x.u = ((unsigned)(unsigned short)s) << 16;
  return x.f;
}
__device__ inline int pk2(float a, float b) {
  return (int)((unsigned)f2bf(a) | ((unsigned)f2bf(b) << 16));
}
__device__ inline bf16x8 pack8(f32x4 a, f32x4 b) {
  union { int i[4]; bf16x8 v; } u;
  u.i[0]=pk2(a.x,a.y); u.i[1]=pk2(a.z,a.w);
  u.i[2]=pk2(b.x,b.y); u.i[3]=pk2(b.z,b.w);
  return u.v;
}
__device__ inline f32x4 reluadd(f32x4 a, f32x4 b) {
  f32x4 r;
  r.x=fmaxf(a.x+b.x,0.f); r.y=fmaxf(a.y+b.y,0.f);
  r.z=fmaxf(a.z+b.z,0.f); r.w=fmaxf(a.w+b.w,0.f);
  return r;
}

// ================= adaptive supports =================

__global__ void k_v(const float* __restrict__ factor, const float* __restrict__ map_w,
                    const float* __restrict__ map_b, float* __restrict__ v) {
  int n = blockIdx.x; int d = threadIdx.x;
  __shared__ float fr[UU];
  fr[d] = factor[n*UU + d];
  __syncthreads();
  float acc = map_b[d];
#pragma unroll
  for (int u=0;u<UU;u++) acc += fr[u]*map_w[u*32+d];
  v[n*32+d] = fmaxf(acc, 0.f);
}

__global__ void k_asrc2(const float* __restrict__ v, const float* __restrict__ a1w,
                        const float* __restrict__ a1b,
                        float* __restrict__ asrc, float* __restrict__ adst) {
  int n = blockIdx.x; int o = threadIdx.x; // 64 threads
  __shared__ float vn[32];
  if (o < 32) vn[o] = v[n*32+o];
  __syncthreads();
  float s = 0.f, dst = a1b[o];
#pragma unroll
  for (int u=0;u<32;u++){ s += vn[u]*a1w[u*64+o]; dst += vn[u]*a1w[(32+u)*64+o]; }
  asrc[n*64+o] = s;
  adst[n*64+o] = dst;
}

__global__ __launch_bounds__(256) void k_pair3(const float* __restrict__ asrc,
    const float* __restrict__ adst, const float* __restrict__ a2w,
    const float* __restrict__ a2b, const float* __restrict__ a3w,
    const float* __restrict__ a3b, float* __restrict__ adj) {
  int i = blockIdx.x;
  int tid = threadIdx.x;
  int wid = tid>>6, lane = tid&63;
  int lm = lane&15, g = lane>>4, lk8 = g*8;
  int jb = blockIdx.y*256 + wid*64;
  bf16x8 wf[2][2];
#pragma unroll
  for (int ks=0;ks<2;ks++)
#pragma unroll
    for (int nh=0;nh<2;nh++){
      int n = nh*16+lm;
      f32x4 lo, hi;
      lo.x=a2w[(ks*32+lk8+0)*32+n]; lo.y=a2w[(ks*32+lk8+1)*32+n];
      lo.z=a2w[(ks*32+lk8+2)*32+n]; lo.w=a2w[(ks*32+lk8+3)*32+n];
      hi.x=a2w[(ks*32+lk8+4)*32+n]; hi.y=a2w[(ks*32+lk8+5)*32+n];
      hi.z=a2w[(ks*32+lk8+6)*32+n]; hi.w=a2w[(ks*32+lk8+7)*32+n];
      wf[ks][nh] = pack8(lo, hi);
    }
  float b20 = a2b[lm], b21 = a2b[16+lm];
  float w3e0n0 = a3w[lm*2],      w3e1n0 = a3w[lm*2+1];
  float w3e0n1 = a3w[(16+lm)*2], w3e1n1 = a3w[(16+lm)*2+1];
  float b30 = a3b[0], b31 = a3b[1];
  const float* dp = adst + i*64;
  f32x4 d00 = *(const f32x4*)(dp + lk8);
  f32x4 d01 = *(const f32x4*)(dp + lk8 + 4);
  f32x4 d10 = *(const f32x4*)(dp + 32 + lk8);
  f32x4 d11 = *(const f32x4*)(dp + 32 + lk8 + 4);
#pragma unroll
  for (int mg=0; mg<4; mg++){
    int j = jb + mg*16 + lm;
    int jc = j < 500 ? j : 0;
    const float* ap = asrc + jc*64;
    f32x4 s00=*(const f32x4*)(ap+lk8),    s01=*(const f32x4*)(ap+lk8+4);
    f32x4 s10=*(const f32x4*)(ap+32+lk8), s11=*(const f32x4*)(ap+32+lk8+4);
    bf16x8 a0 = pack8(reluadd(s00,d00), reluadd(s01,d01));
    bf16x8 a1 = pack8(reluadd(s10,d10), reluadd(s11,d11));
    f32x4 acc0 = {b20,b20,b20,b20};
    f32x4 acc1 = {b21,b21,b21,b21};
    acc0 = __builtin_amdgcn_mfma_f32_16x16x32_bf16(a0, wf[0][0], acc0, 0,0,0);
    acc0 = __builtin_amdgcn_mfma_f32_16x16x32_bf16(a1, wf[1][0], acc0, 0,0,0);
    acc1 = __builtin_amdgcn_mfma_f32_16x16x32_bf16(a0, wf[0][1], acc1, 0,0,0);
    acc1 = __builtin_amdgcn_mfma_f32_16x16x32_bf16(a1, wf[1][1], acc1, 0,0,0);
    float e0[4], e1[4];
#pragma unroll
    for (int r=0;r<4;r++){
      float h2a = fmaxf(acc0[r],0.f), h2b = fmaxf(acc1[r],0.f);
      e0[r] = h2a*w3e0n0 + h2b*w3e0n1;
      e1[r] = h2a*w3e1n0 + h2b*w3e1n1;
    }
#pragma unroll
    for (int off=1; off<16; off<<=1){
#pragma unroll
      for (int r=0;r<4;r++){ e0[r]+=__shfl_xor(e0[r],off); e1[r]+=__shfl_xor(e1[r],off); }
    }
    if (lm==0){
      int j4 = jb + mg*16 + g*4;
      if (j4 < 500){
        f32x4 v0={e0[0]+b30,e0[1]+b30,e0[2]+b30,e0[3]+b30};
        f32x4 v1={e1[0]+b31,e1[1]+b31,e1[2]+b31,e1[3]+b31};
        *(f32x4*)(adj + i*500 + j4) = v0;
        *(f32x4*)(adj + 250000 + i*500 + j4) = v1;
      }
    }
  }
}

__global__ __launch_bounds__(256) void k_softmax(const float* __restrict__ adj,
    float* __restrict__ sup_out) {
  int row = blockIdx.x;
  int e = row/NN, i = row%NN;
  const float* a = adj + e*250000 + i*NN;
  __shared__ float red[64];
  float m = -1e30f;
  for (int j=threadIdx.x;j<NN;j+=256) m = fmaxf(m, a[j]);
#pragma unroll
  for (int off=32; off; off>>=1) m = fmaxf(m, __shfl_down(m, off));
  int lane = threadIdx.x & 63, wid = threadIdx.x >> 6;
  if (lane==0) red[wid]=m;
  __syncthreads();
  if (threadIdx.x==0){ float mm=red[0]; for(int w=1;w<4;w++) mm=fmaxf(mm,red[w]); red[32]=mm; }
  __syncthreads();
  m = red[32];
  float s=0.f;
  for (int j=threadIdx.x;j<NN;j+=256) s += __expf(a[j]-m);
#pragma unroll
  for (int off=32; off; off>>=1) s += __shfl_down(s, off);
  if (lane==0) red[wid]=s;
  __syncthreads();
  if (threadIdx.x==0){ float ss=0; for(int w=0;w<4;w++) ss+=red[w]; red[33]=ss; }
  __syncthreads();
  float inv = 1.f/red[33];
  for (int j=threadIdx.x;j<NN;j+=256) {
    float val = __expf(a[j]-m)*inv;
    if (j==i) val = 1.f;
    sup_out[e*250000 + i*NN + j] = val;
  }
}

// ST[e][w][v] transposed bf16 + SB[e][v][w] cast bf16 (both 512x512 zero-padded)
__global__ __launch_bounds__(256) void k_tposeS(const float* __restrict__ sup,
    short* __restrict__ ST, short* __restrict__ SB) {
  __shared__ float ts[64][68];
  int e = blockIdx.z;
  int v0 = blockIdx.x*64, w0 = blockIdx.y*64;
  int tid = threadIdx.x;
  int vv = tid>>2, wc = (tid&3)*16;
  bool vok = (v0+vv) < 500;
#pragma unroll
  for (int c=0;c<4;c++){
    f32x4 val = {0,0,0,0};
    int wg = w0 + wc + c*4;
    if (vok && wg < 500) val = *(const f32x4*)(sup + e*250000 + (size_t)(v0+vv)*500 + wg);
    *(f32x4*)&ts[vv][wc + c*4] = val;
    int2 pv; pv.x = pk2(val.x, val.y); pv.y = pk2(val.z, val.w);
    *(int2*)(SB + (size_t)e*(512*512) + (size_t)(v0+vv)*VS + wg) = pv;
  }
  __syncthreads();
  int w = tid>>2, vc = (tid&3)*16;
  unsigned short u[16];
#pragma unroll
  for (int j=0;j<16;j++) u[j] = f2bf(ts[vc+j][w]);
  int4 o0, o1;
  o0.x = u[0]|(u[1]<<16);  o0.y = u[2]|(u[3]<<16);
  o0.z = u[4]|(u[5]<<16);  o0.w = u[6]|(u[7]<<16);
  o1.x = u[8]|(u[9]<<16);  o1.y = u[10]|(u[11]<<16);
  o1.z = u[12]|(u[13]<<16); o1.w = u[14]|(u[15]<<16);
  short* op = ST + (size_t)e*(512*512) + (size_t)(w0+w)*VS + v0 + vc;
  *(int4*)(op) = o0;
  *(int4*)(op+8) = o1;
}

// ST2[e] = (S@S)^T stored [w][u]
__global__ __launch_bounds__(256) void k_ssq(const short* __restrict__ SB,
    const short* __restrict__ ST, short* __restrict__ ST2) {
  __shared__ __align__(16) short As[64*72];
  __shared__ __align__(16) short Bs[64*72];
  int e = blockIdx.z;
  int u0 = blockIdx.x*64, w0 = blockIdx.y*64;
  const short* Ab = SB + (size_t)e*(512*512);
  const short* Bb = ST + (size_t)e*(512*512);
  int tid = threadIdx.x;
  int row = tid>>2, col = (tid&3)*16;
  const short* ap = Ab + (size_t)(u0+row)*VS + col;
  const short* bp = Bb + (size_t)(w0+row)*VS + col;
  f32x4 ra0 = *(const f32x4*)(ap);
  f32x4 ra1 = *(const f32x4*)(ap+8);
  f32x4 rb0 = *(const f32x4*)(bp);
  f32x4 rb1 = *(const f32x4*)(bp+8);
  int wid = tid>>6, lane = tid&63;
  int wr = wid>>1, wc = wid&1;
  int lm = lane&15, lk = (lane>>4)*8;
  f32x4 acc[2][2] = {};
  short* aw = As + row*72 + col;
  short* bw = Bs + row*72 + col;
  for (int kk=0; kk<8; kk++) {
    __syncthreads();
    *(f32x4*)(aw) = ra0; *(f32x4*)(aw+8) = ra1;
    *(f32x4*)(bw) = rb0; *(f32x4*)(bw+8) = rb1;
    __syncthreads();
    if (kk < 7) {
      const short* ap2 = ap + (kk+1)*64;
      const short* bp2 = bp + (kk+1)*64;
      ra0 = *(const f32x4*)(ap2); ra1 = *(const f32x4*)(ap2+8);
      rb0 = *(const f32x4*)(bp2); rb1 = *(const f32x4*)(bp2+8);
    }
#pragma unroll
    for (int ks=0; ks<2; ks++) {
      bf16x8 af0 = *(const bf16x8*)(As + (wr*32 + lm)*72 + ks*32 + lk);
      bf16x8 af1 = *(const bf16x8*)(As + (wr*32 + 16 + lm)*72 + ks*32 + lk);
      bf16x8 bq0 = *(const bf16x8*)(Bs + (wc*32 + lm)*72 + ks*32 + lk);
      bf16x8 bq1 = *(const bf16x8*)(Bs + (wc*32 + 16 + lm)*72 + ks*32 + lk);
      acc[0][0] = __builtin_amdgcn_mfma_f32_16x16x32_bf16(af0, bq0, acc[0][0], 0,0,0);
      acc[0][1] = __builtin_amdgcn_mfma_f32_16x16x32_bf16(af0, bq1, acc[0][1], 0,0,0);
      acc[1][0] = __builtin_amdgcn_mfma_f32_16x16x32_bf16(af1, bq0, acc[1][0], 0,0,0);
      acc[1][1] = __builtin_amdgcn_mfma_f32_16x16x32_bf16(af1, bq1, acc[1][1], 0,0,0);
    }
  }
#pragma unroll
  for (int fm=0; fm<2; fm++) {
    int u4 = u0 + wr*32 + fm*16 + (lane>>4)*4;
#pragma unroll
    for (int fn=0; fn<2; fn++) {
      int w = w0 + wc*32 + fn*16 + lm;
      f32x4 v4 = acc[fm][fn];
      int2 pv; pv.x = pk2(v4.x, v4.y); pv.y = pk2(v4.z, v4.w);
      *(int2*)(ST2 + (size_t)e*(512*512) + (size_t)w*VS + u4) = pv;
    }
  }
}

// GT[b][q][v] bf16 from Gbf[b*NN+v][q] bf16
__global__ __launch_bounds__(256) void k_tposeGb(const short* __restrict__ Gbf,
    short* __restrict__ GT, int qmax) {
  __shared__ __align__(16) short ts[64][72];
  int b = blockIdx.z;
  int v0 = blockIdx.x*64, q0 = blockIdx.y*64;
  int tid = threadIdx.x;
  int vv = tid>>2, qc = (tid&3)*16;
  bool ok = ((v0+vv) < 500) && ((q0+qc) < qmax);
  int4 z4 = {0,0,0,0};
  int4 i0 = z4, i1 = z4;
  if (ok){
    const short* gp = Gbf + (size_t)(b*NN + v0+vv)*QS + q0 + qc;
    i0 = *(const int4*)(gp);
    i1 = *(const int4*)(gp+8);
  }
  *(int4*)&ts[vv][qc] = i0;
  *(int4*)&ts[vv][qc+8] = i1;
  __syncthreads();
  int q = tid>>2, vc = (tid&3)*16;
  if (q0 + q < qmax) {
    unsigned short u[16];
#pragma unroll
    for (int j=0;j<16;j++) u[j] = (unsigned short)ts[vc+j][q];
    int4 o0, o1;
    o0.x = u[0]|(u[1]<<16);  o0.y = u[2]|(u[3]<<16);
    o0.z = u[4]|(u[5]<<16);  o0.w = u[6]|(u[7]<<16);
    o1.x = u[8]|(u[9]<<16);  o1.y = u[10]|(u[11]<<16);
    o1.z = u[12]|(u[13]<<16); o1.w = u[14]|(u[15]<<16);
    short* op = GT + ((size_t)b*QS + q0+q)*VS + v0 + vc;
    *(int4*)(op) = o0;
    *(int4*)(op+8) = o1;
  }
}

// MFMA diffusion hop: OUT[w][q] = sum_v A[w][v]*GT[q][v]
__global__ __launch_bounds__(256) void k_hop(const short* __restrict__ A,
    const short* __restrict__ GT, float* __restrict__ OUT, int qmax) {
  __shared__ __align__(16) short As[64*72];
  __shared__ __align__(16) short Bs[64*72];
  int e = blockIdx.z & 1, b = blockIdx.z >> 1;
  int w0 = blockIdx.x*64, q0 = blockIdx.y*64;
  const short* Ab = A + (size_t)e*(512*512);
  const short* Bb = GT + (size_t)b*(QS*VS);
  int tid = threadIdx.x;
  int row = tid>>2, col = (tid&3)*16;
  const short* ap = Ab + (size_t)(w0+row)*VS + col;
  const short* bp = Bb + (size_t)(q0+row)*VS + col;
  bool bok = (q0+row) < qmax;
  f32x4 zero4 = {0,0,0,0};
  f32x4 ra0 = *(const f32x4*)(ap);
  f32x4 ra1 = *(const f32x4*)(ap+8);
  f32x4 rb0 = bok ? *(const f32x4*)(bp) : zero4;
  f32x4 rb1 = bok ? *(const f32x4*)(bp+8) : zero4;
  int wid = tid>>6, lane = tid&63;
  int wr = wid>>1, wc = wid&1;
  int lm = lane&15, lk = (lane>>4)*8;
  f32x4 acc[2][2] = {};
  short* aw = As + row*72 + col;
  short* bw = Bs + row*72 + col;
  for (int kk=0; kk<8; kk++) {
    __syncthreads();
    *(f32x4*)(aw) = ra0; *(f32x4*)(aw+8) = ra1;
    *(f32x4*)(bw) = rb0; *(f32x4*)(bw+8) = rb1;
    __syncthreads();
    if (kk < 7) {
      const short* ap2 = ap + (kk+1)*64;
      const short* bp2 = bp + (kk+1)*64;
      ra0 = *(const f32x4*)(ap2); ra1 = *(const f32x4*)(ap2+8);
      rb0 = bok ? *(const f32x4*)(bp2) : zero4;
      rb1 = bok ? *(const f32x4*)(bp2+8) : zero4;
    }
#pragma unroll
    for (int ks=0; ks<2; ks++) {
      bf16x8 af0 = *(const bf16x8*)(As + (wr*32 + lm)*72 + ks*32 + lk);
      bf16x8 af1 = *(const bf16x8*)(As + (wr*32 + 16 + lm)*72 + ks*32 + lk);
      bf16x8 bq0 = *(const bf16x8*)(Bs + (wc*32 + lm)*72 + ks*32 + lk);
      bf16x8 bq1 = *(const bf16x8*)(Bs + (wc*32 + 16 + lm)*72 + ks*32 + lk);
      acc[0][0] = __builtin_amdgcn_mfma_f32_16x16x32_bf16(af0, bq0, acc[0][0], 0,0,0);
      acc[0][1] = __builtin_amdgcn_mfma_f32_16x16x32_bf16(af0, bq1, acc[0][1], 0,0,0);
      acc[1][0] = __builtin_amdgcn_mfma_f32_16x16x32_bf16(af1, bq0, acc[1][0], 0,0,0);
      acc[1][1] = __builtin_amdgcn_mfma_f32_16x16x32_bf16(af1, bq1, acc[1][1], 0,0,0);
    }
  }
  float* Ob = OUT + (size_t)e*(2*(size_t)DSZ) + (size_t)b*(NN*QS);
#pragma unroll
  for (int fm=0; fm<2; fm++) {
    int wb4 = w0 + wr*32 + fm*16 + (lane>>4)*4;
    if (wb4 >= 500) continue;
#pragma unroll
    for (int fn=0; fn<2; fn++) {
      int q = q0 + wc*32 + fn*16 + lm;
      if (q < qmax) {
        f32x4 v4 = acc[fm][fn];
        float* op = Ob + (size_t)wb4*QS + q;
        op[0*QS] = v4.x; op[1*QS] = v4.y; op[2*QS] = v4.z; op[3*QS] = v4.w;
      }
    }
  }
}

// ================= input projection / enter conv =================

__global__ void k_proj(const float* __restrict__ inputs, const float* __restrict__ factor,
                       float* __restrict__ proj) {
  int bt = blockIdx.x;
  __shared__ float xin[NN*2];
  for (int idx=threadIdx.x; idx<NN*2; idx+=64) xin[idx] = inputs[bt*NN*2 + idx];
  __syncthreads();
  int u = threadIdx.x>>1, f = threadIdx.x&1;
  float acc=0.f;
  for (int n=0;n<NN;n++) acc += xin[n*2+f]*factor[n*UU+u];
  proj[bt*64 + u*2+f] = acc;
}

__global__ __launch_bounds__(256) void k_enter(const float* __restrict__ inputs,
    const float* __restrict__ factor, const float* __restrict__ proj,
    const float* __restrict__ ew, const float* __restrict__ eb, float* __restrict__ X) {
  int idx = blockIdx.x*256+threadIdx.x;
  if (idx >= BB*NN*TX) return;
  int t = idx % TX; int n = (idx/TX)%NN; int b = idx/(TX*NN);
  float x4[4]={0.f,0.f,0.f,0.f};
  if (t>0) {
    int tt=t-1;
    float s0=0.f,s1=0.f;
    const float* pr = proj + (b*TT+tt)*64;
    const float* fr = factor + n*UU;
#pragma unroll
    for(int u=0;u<UU;u++){ s0 += pr[u*2]*fr[u]; s1 += pr[u*2+1]*fr[u]; }
    float i0 = inputs[((b*TT+tt)*NN+n)*2];
    float i1 = inputs[((b*TT+tt)*NN+n)*2+1];
    x4[0]=s0; x4[1]=s1; x4[2]=i0-s0; x4[3]=i1-s1;
  }
  float* xp = X + ((size_t)(b*NN+n)*TX + t)*CC;
#pragma unroll
  for(int o=0;o<CC;o++){
    xp[o] = eb[o] + ew[o*4]*x4[0] + ew[o*4+1]*x4[1] + ew[o*4+2]*x4[2] + ew[o*4+3]*x4[3];
  }
}

// ================= MFMA gated temporal conv =================

__global__ __launch_bounds__(256) void k_gated3(const float* __restrict__ X,
    short* __restrict__ Gbf, short* __restrict__ Glb,
    const float* __restrict__ fw, const float* __restrict__ fb,
    const float* __restrict__ gw, const float* __restrict__ gb,
    const float* __restrict__ stat, int use_stat, int d, int t_out, int lidx) {
  __shared__ __align__(16) short As[64*72];
  __shared__ __align__(16) short Wb[64*72];
  __shared__ float scs[32], shs[32];
  int tid = threadIdx.x;
  if (tid < 32) {
    scs[tid] = use_stat ? stat[tid] : 1.0f;
    shs[tid] = use_stat ? stat[32 + tid] : 0.0f;
  }
  for (int i = tid; i < 2048; i += 256) {
    int o = i >> 6, k = i & 63;
    Wb[o*72 + k]      = (short)f2bf(fw[i]);
    Wb[(32+o)*72 + k] = (short)f2bf(gw[i]);
  }
  __syncthreads();
  int m0 = blockIdx.x * 64;
  {
    int mm = tid & 63;
    int kb = (tid >> 6) * 16;
    int c0 = kb >> 1;
    int m = m0 + mm;
    int bn = m / t_out, t = m - bn * t_out;
    const float* xr = X + (size_t)bn * (TX * CC);
    float4 a0 = *(const float4*)(xr + t * 32 + c0);
    float4 a1 = *(const float4*)(xr + t * 32 + c0 + 4);
    float4 b0 = *(const float4*)(xr + (t + d) * 32 + c0);
    float4 b1 = *(const float4*)(xr + (t + d) * 32 + c0 + 4);
    float va[8] = {a0.x,a0.y,a0.z,a0.w,a1.x,a1.y,a1.z,a1.w};
    float vb[8] = {b0.x,b0.y,b0.z,b0.w,b1.x,b1.y,b1.z,b1.w};
    int iv[8];
#pragma unroll
    for (int j = 0; j < 8; j++) {
      float sc = scs[c0+j], sh = shs[c0+j];
      iv[j] = pk2(va[j]*sc + sh, vb[j]*sc + sh);
    }
    int4 w0 = {iv[0],iv[1],iv[2],iv[3]};
    int4 w1 = {iv[4],iv[5],iv[6],iv[7]};
    *(int4*)(As + mm*72 + kb) = w0;
    *(int4*)(As + mm*72 + kb + 8) = w1;
  }
  __syncthreads();
  int wid = tid>>6, lane = tid&63;
  int lm = lane&15, g = lane>>4, lk8 = g*8;
  f32x4 acc[4] = {};
#pragma unroll
  for (int kk=0; kk<2; kk++){
    bf16x8 af = *(const bf16x8*)(As + (wid*16+lm)*72 + kk*32 + lk8);
#pragma unroll
    for (int fn=0; fn<4; fn++){
      bf16x8 bq = *(const bf16x8*)(Wb + (fn*16+lm)*72 + kk*32 + lk8);
      acc[fn] = __builtin_amdgcn_mfma_f32_16x16x32_bf16(af, bq, acc[fn], 0,0,0);
    }
  }
#pragma unroll
  for (int fn=0; fn<2; fn++){
    int o = fn*16 + lm;
    float fbv = fb[o], gbv = gb[o];
#pragma unroll
    for (int r=0; r<4; r++){
      int m = m0 + wid*16 + g*4 + r;
      int bn = m / t_out, t = m - bn*t_out;
      float f = acc[fn][r] + fbv;
      float gg = acc[fn+2][r] + gbv;
      float th = 2.f/(1.f+__expf(-2.f*f)) - 1.f;
      float sg = 1.f/(1.f+__expf(-gg));
      unsigned short ov = f2bf(th*sg);
      Gbf[(size_t)bn*QS + t*32 + o] = (short)ov;
      if (t == t_out-1) Glb[(size_t)bn*256 + lidx*32 + o] = (short)ov;
    }
  }
}

// ======= MFMA graph-conv 1x1 + residual + BN partials =======

template<int TOUT>
__global__ __launch_bounds__(64) void k_gc3(const short* __restrict__ Gbf,
    const float* __restrict__ D, const float* __restrict__ Xc, float* __restrict__ Xn,
    const float* __restrict__ gcw, const float* __restrict__ gcb,
    const float* __restrict__ stat, int use_stat, float* __restrict__ part, int d) {
  int tid = threadIdx.x;
  int lm = tid&15, g = tid>>4, lk8 = g*8;
  bf16x8 wf[5][2];
#pragma unroll
  for (int ks=0;ks<5;ks++)
#pragma unroll
    for (int nh=0;nh<2;nh++){
      const float* wp = gcw + (nh*16+lm)*160 + ks*32 + lk8;
      wf[ks][nh] = pack8(*(const f32x4*)wp, *(const f32x4*)(wp+4));
    }
  float scn0 = use_stat ? stat[lm]    : 1.f;
  float scn1 = use_stat ? stat[16+lm] : 1.f;
  float shn0 = use_stat ? stat[32+lm] : 0.f;
  float shn1 = use_stat ? stat[48+lm] : 0.f;
  float gb0 = gcb[lm], gb1 = gcb[16+lm];
  int m0 = blockIdx.x*64;
  float ss0=0.f, sq0=0.f, ss1=0.f, sq1=0.f;
#pragma unroll
  for (int mg=0; mg<4; mg++){
    int m = m0 + mg*16 + lm;
    int bn = m / TOUT; int t = m - bn*TOUT;
    size_t off = (size_t)bn*(TG*CC) + t*32 + lk8;
    f32x4 acc0={0,0,0,0}, acc1={0,0,0,0};
    {
      bf16x8 af = *(const bf16x8*)(Gbf + off);
      acc0 = __builtin_amdgcn_mfma_f32_16x16x32_bf16(af, wf[0][0], acc0, 0,0,0);
      acc1 = __builtin_amdgcn_mfma_f32_16x16x32_bf16(af, wf[0][1], acc1, 0,0,0);
    }
#pragma unroll
    for (int ks=1;ks<5;ks++){
      const float* sp = D + (size_t)(ks-1)*DSZ + off;
      bf16x8 af = pack8(*(const f32x4*)sp, *(const f32x4*)(sp+4));
      acc0 = __builtin_amdgcn_mfma_f32_16x16x32_bf16(af, wf[ks][0], acc0, 0,0,0);
      acc1 = __builtin_amdgcn_mfma_f32_16x16x32_bf16(af, wf[ks][1], acc1, 0,0,0);
    }
#pragma unroll
    for (int r=0;r<4;r++){
      int mr = m0 + mg*16 + g*4 + r;
      int bnr = mr / TOUT; int tr = mr - bnr*TOUT;
      size_t xoff = (size_t)bnr*(TX*CC);
      float r0 = Xc[xoff + (tr+d)*32 + lm];
      float r1 = Xc[xoff + (tr+d)*32 + 16 + lm];
      float v0 = acc0[r] + gb0 + r0*scn0 + shn0;
      float v1 = acc1[r] + gb1 + r1*scn1 + shn1;
      Xn[xoff + tr*32 + lm] = v0;
      Xn[xoff + tr*32 + 16 + lm] = v1;
      ss0+=v0; sq0+=v0*v0; ss1+=v1; sq1+=v1*v1;
    }
  }
#pragma unroll
  for (int off=16; off<64; off<<=1){
    ss0+=__shfl_xor(ss0,off); sq0+=__shfl_xor(sq0,off);
    ss1+=__shfl_xor(ss1,off); sq1+=__shfl_xor(sq1,off);
  }
  if (tid<16){
    float* pp = part + (size_t)blockIdx.x*64;
    pp[tid]=ss0; pp[16+tid]=ss1; pp[32+tid]=sq0; pp[48+tid]=sq1;
  }
}

__global__ __launch_bounds__(256) void k_stat2(const float* __restrict__ part, int nblk,
    const float* __restrict__ g, const float* __restrict__ b,
    float* __restrict__ statout, float cntinv) {
  __shared__ float red[16][64];
  int tid = threadIdx.x;
  int s4 = (tid&15)*4, rg = tid>>4;
  f32x4 acc = {0,0,0,0};
  for (int i=rg; i<nblk; i+=16){
    const f32x4 v = *(const f32x4*)(part + (size_t)i*64 + s4);
    acc.x+=v.x; acc.y+=v.y; acc.z+=v.z; acc.w+=v.w;
  }
  *(f32x4*)&red[rg][s4] = acc;
  __syncthreads();
  if (tid < 64){
    float s=0.f;
#pragma unroll
    for (int r=0;r<16;r++) s += red[r][tid];
    red[0][tid] = s;
  }
  __syncthreads();
  if (tid < 32){
    float s = red[0][tid], sq = red[0][32+tid];
    float m = s*cntinv, var = sq*cntinv - m*m;
    float sc = rsqrtf(var + BN_EPS)*g[tid];
    statout[tid] = sc;
    statout[32+tid] = b[tid] - m*sc;
  }
}

// ================= output head =================

// grid 768: blocks 0..255 build Wstb (bf16 [n=256][k=256]) + bsum; 256..767 cast o1w
__global__ void k_wstack2(const float* __restrict__ skp_w, const float* __restrict__ skp_b,
                          const float* __restrict__ o1w,
                          short* __restrict__ Wstb, short* __restrict__ o1wb,
                          float* __restrict__ bsum) {
  int bid = blockIdx.x;
  int idx = bid*256 + threadIdx.x;
  if (bid < 256){
    int kk = idx >> 8, o = idx & 255;
    Wstb[o*256 + kk] = (short)f2bf(skp_w[(kk>>5)*8192 + o*32 + (kk&31)]);
    if (idx < 256){
      float s=0.f;
      for (int l=0;l<8;l++) s += skp_b[l*256+idx];
      bsum[idx]=s;
    }
  } else {
    int j = idx - 65536;
    o1wb[j] = (short)f2bf(o1w[j]);
  }
}

// C[m][n] = relu(sum_k A[m][k]*B[n][k] + bias[n]) -> bf16 out
__global__ __launch_bounds__(256) void k_mm(const short* __restrict__ A,
    const short* __restrict__ B, const float* __restrict__ bias,
    short* __restrict__ out, int ldout, int K) {
  __shared__ __align__(16) short As[64*72];
  __shared__ __align__(16) short Bs[64*72];
  int m0 = blockIdx.x*64, n0 = blockIdx.y*64;
  int tid = threadIdx.x;
  int row = tid>>2, col = (tid&3)*16;
  const short* ap = A + (size_t)(m0+row)*K + col;
  const short* bp = B + (size_t)(n0+row)*K + col;
  f32x4 ra0 = *(const f32x4*)(ap);
  f32x4 ra1 = *(const f32x4*)(ap+8);
  f32x4 rb0 = *(const f32x4*)(bp);
  f32x4 rb1 = *(const f32x4*)(bp+8);
  int wid = tid>>6, lane = tid&63;
  int wr = wid>>1, wc = wid&1;
  int lm = lane&15, lk = (lane>>4)*8;
  f32x4 acc[2][2] = {};
  short* aw = As + row*72 + col;
  short* bw = Bs + row*72 + col;
  int nk = K>>6;
  for (int kk=0; kk<nk; kk++) {
    __syncthreads();
    *(f32x4*)(aw) = ra0; *(f32x4*)(aw+8) = ra1;
    *(f32x4*)(bw) = rb0; *(f32x4*)(bw+8) = rb1;
    __syncthreads();
    if (kk < nk-1) {
      const short* ap2 = ap + (kk+1)*64;
      const short* bp2 = bp + (kk+1)*64;
      ra0 = *(const f32x4*)(ap2); ra1 = *(const f32x4*)(ap2+8);
      rb0 = *(const f32x4*)(bp2); rb1 = *(const f32x4*)(bp2+8);
    }
#pragma unroll
    for (int ks=0; ks<2; ks++) {
      bf16x8 af0 = *(const bf16x8*)(As + (wr*32 + lm)*72 + ks*32 + lk);
      bf16x8 af1 = *(const bf16x8*)(As + (wr*32 + 16 + lm)*72 + ks*32 + lk);
      bf16x8 bq0 = *(const bf16x8*)(Bs + (wc*32 + lm)*72 + ks*32 + lk);
      bf16x8 bq1 = *(const bf16x8*)(Bs + (wc*32 + 16 + lm)*72 + ks*32 + lk);
      acc[0][0] = __builtin_amdgcn_mfma_f32_16x16x32_bf16(af0, bq0, acc[0][0], 0,0,0);
      acc[0][1] = __builtin_amdgcn_mfma_f32_16x16x32_bf16(af0, bq1, acc[0][1], 0,0,0);
      acc[1][0] = __builtin_amdgcn_mfma_f32_16x16x32_bf16(af1, bq0, acc[1][0], 0,0,0);
      acc[1][1] = __builtin_amdgcn_mfma_f32_16x16x32_bf16(af1, bq1, acc[1][1], 0,0,0);
    }
  }
#pragma unroll
  for (int fm=0; fm<2; fm++) {
    int mb = m0 + wr*32 + fm*16 + (lane>>4)*4;
#pragma unroll
    for (int fn=0; fn<2; fn++) {
      int n = n0 + wc*32 + fn*16 + lm;
      float bv = bias[n];
      f32x4 v4 = acc[fm][fn];
#pragma unroll
      for (int r=0;r<4;r++)
        out[(size_t)(mb+r)*ldout + n] = (short)f2bf(fmaxf(v4[r]+bv, 0.f));
    }
  }
}

__global__ __launch_bounds__(256) void k_head2c(const short* __restrict__ Y1b,
    const float* __restrict__ o2w, const float* __restrict__ o2b, float* __restrict__ y) {
  int tid = threadIdx.x;
  int ml = tid>>2, kc = tid&3;
  int m = blockIdx.x*64 + ml;
  float accs[NPREDC] = {};
  for (int e=kc*128; e<kc*128+128; e+=8){
    bf16x8 yv = *(const bf16x8*)(Y1b + (size_t)m*NENDC + e);
    float yf[8];
#pragma unroll
    for (int j=0;j<8;j++) yf[j] = bf2f(yv[j]);
#pragma unroll
    for (int p=0;p<NPREDC;p++){
      const float* wp = o2w + p*NENDC + e;
      float a = 0.f;
#pragma unroll
      for (int j=0;j<8;j++) a += wp[j]*yf[j];
      accs[p] += a;
    }
  }
#pragma unroll
  for (int off=1; off<4; off<<=1)
#pragma unroll
    for (int p=0;p<NPREDC;p++) accs[p] += __shfl_xor(accs[p], off);
  if (kc==0){
    int b=m/NN, n=m%NN;
#pragma unroll
    for (int p=0;p<NPREDC;p++) y[(b*NPREDC+p)*NN+n] = accs[p] + o2b[p];
  }
}

// ================= host =================

extern "C" void kernel_launch(void* const* d_in, const int* in_sizes, int n_in,
                              void* d_out, int out_size, void* d_ws, size_t ws_size,
                              hipStream_t stream) {
  const float* inputs  = (const float*)d_in[0];
  const float* factor  = (const float*)d_in[1];
  const float* map_w   = (const float*)d_in[2];
  const float* map_b   = (const float*)d_in[3];
  const float* a1w     = (const float*)d_in[4];
  const float* a1b     = (const float*)d_in[5];
  const float* a2w     = (const float*)d_in[6];
  const float* a2b     = (const float*)d_in[7];
  const float* a3w     = (const float*)d_in[8];
  const float* a3b     = (const float*)d_in[9];
  const float* enter_w = (const float*)d_in[10];
  const float* enter_b = (const float*)d_in[11];
  const float* filt_w  = (const float*)d_in[12];
  const float* filt_b  = (const float*)d_in[13];
  const float* gate_w  = (const float*)d_in[14];
  const float* gate_b  = (const float*)d_in[15];
  const float* skp_w   = (const float*)d_in[16];
  const float* skp_b   = (const float*)d_in[17];
  const float* gc_w    = (const float*)d_in[18];
  const float* gc_b    = (const float*)d_in[19];
  const float* bn_g    = (const float*)d_in[20];
  const float* bn_b    = (const float*)d_in[21];
  const float* o1w     = (const float*)d_in[22];
  const float* o1b     = (const float*)d_in[23];
  const float* o2w     = (const float*)d_in[24];
  const float* o2b     = (const float*)d_in[25];
  (void)in_sizes; (void)n_in; (void)out_size; (void)ws_size;

  float* ws = (float*)d_ws;
  float* v      = ws + OFF_V;
  float* adj    = ws + OFF_ADJ;
  float* asrc   = ws + OFF_ASRC;
  float* adst   = ws + OFF_ADST;
  float* proj   = ws + OFF_PROJ;
  float* statb  = ws + OFF_STAT;
  float* part   = ws + OFF_PART;
  float* bsum   = ws + OFF_BSUM;
  float* X      = ws + OFF_X;
  float* Xn     = ws + OFF_XN;
  float* D      = ws + OFF_D;
  short* Gbf    = (short*)(ws + OFF_GBF);
  short* Glb    = (short*)(ws + OFF_GLB);
  short* GT     = (short*)(ws + OFF_GT);
  short* ST     = (short*)(ws + OFF_ST);
  short* SB     = (short*)(ws + OFF_SB);
  short* ST2    = (short*)(ws + OFF_ST2);
  short* Wstb   = (short*)(ws + OFF_WSTB);
  short* o1wb   = (short*)(ws + OFF_O1WB);
  short* skvb   = (short*)(ws + OFF_SKV);
  short* Y1b    = (short*)(ws + OFF_Y1B);

  float* y_out   = (float*)d_out;
  float* sup_out = y_out + BB*NPREDC*NN;

  // adaptive supports
  k_v<<<NN, 32, 0, stream>>>(factor, map_w, map_b, v);
  k_asrc2<<<NN, 64, 0, stream>>>(v, a1w, a1b, asrc, adst);
  {
    dim3 gp(NN, 2);
    k_pair3<<<gp, 256, 0, stream>>>(asrc, adst, a2w, a2b, a3w, a3b, adj);
  }
  k_softmax<<<2*NN, 256, 0, stream>>>(adj, sup_out);
  {
    dim3 gt(8, 8, 2);
    k_tposeS<<<gt, 256, 0, stream>>>(sup_out, ST, SB);
    k_ssq<<<gt, 256, 0, stream>>>(SB, ST, ST2);
  }

  // input split + enter
  k_proj<<<BB*TT, 64, 0, stream>>>(inputs, factor, proj);
  k_enter<<<(BB*NN*TX+255)/256, 256, 0, stream>>>(inputs, factor, proj, enter_w, enter_b, X);

  // head weight prep (independent)
  k_wstack2<<<768, 256, 0, stream>>>(skp_w, skp_b, o1w, Wstb, o1wb, bsum);

  float* Xc = X; float* Xo = Xn;
  int t = TX;
  static const int dil[8]={1,2,1,2,1,2,1,2};
  for (int l=0;l<7;l++){
    int d=dil[l], t_out=t-d;
    const float* st = statb + (l>0 ? (l-1)*64 : 0);
    k_gated3<<<250*t_out,256,0,stream>>>(Xc, Gbf, Glb, filt_w + l*2048, filt_b + l*32,
                                         gate_w + l*2048, gate_b + l*32, st, l>0, d, t_out, l);
    int qmax = t_out*CC;
    int qt = (qmax+63)/64;
    dim3 gtp(8, qt, 32);
    k_tposeGb<<<gtp,256,0,stream>>>(Gbf, GT, qmax);
    dim3 ghp(8, qt, 64);
    k_hop<<<ghp,256,0,stream>>>(ST,  GT, D,                 qmax);
    k_hop<<<ghp,256,0,stream>>>(ST2, GT, D + (size_t)DSZ,   qmax);
    int nblk = 250*t_out;
    const float* gcwl = gc_w + l*5120;
    const float* gcbl = gc_b + l*32;
    switch (t_out){
      case 12: k_gc3<12><<<nblk,64,0,stream>>>(Gbf,D,Xc,Xo,gcwl,gcbl,st,l>0,part,d); break;
      case 10: k_gc3<10><<<nblk,64,0,stream>>>(Gbf,D,Xc,Xo,gcwl,gcbl,st,l>0,part,d); break;
      case  9: k_gc3< 9><<<nblk,64,0,stream>>>(Gbf,D,Xc,Xo,gcwl,gcbl,st,l>0,part,d); break;
      case  7: k_gc3< 7><<<nblk,64,0,stream>>>(Gbf,D,Xc,Xo,gcwl,gcbl,st,l>0,part,d); break;
      case  6: k_gc3< 6><<<nblk,64,0,stream>>>(Gbf,D,Xc,Xo,gcwl,gcbl,st,l>0,part,d); break;
      case  4: k_gc3< 4><<<nblk,64,0,stream>>>(Gbf,D,Xc,Xo,gcwl,gcbl,st,l>0,part,d); break;
      default: k_gc3< 3><<<nblk,64,0,stream>>>(Gbf,D,Xc,Xo,gcwl,gcbl,st,l>0,part,d); break;
    }
    k_stat2<<<1,256,0,stream>>>(part, nblk, bn_g + l*32, bn_b + l*32,
                                statb + l*64, 1.f/(16000.f*(float)t_out));
    float* tmp=Xc; Xc=Xo; Xo=tmp;
    t = t_out;
  }
  // layer 8: only gated conv feeds skip
  k_gated3<<<250*1,256,0,stream>>>(Xc, Gbf, Glb, filt_w + 7*2048, filt_b + 7*32,
                                   gate_w + 7*2048, gate_b + 7*32, statb + 6*64, 1, 2, 1, 7);

  // head: skip GEMM -> head1 -> head2
  {
    dim3 gs(BNN/64, NSKIPC/64);
    k_mm<<<gs,256,0,stream>>>(Glb, Wstb, bsum, skvb, NSKIPC, 256);
    dim3 gh(BNN/64, NENDC/64);
    k_mm<<<gh,256,0,stream>>>(skvb, o1wb, o1b, Y1b, NENDC, 256);
    k_head2c<<<BNN/64,256,0,stream>>>(Y1b, o2w, o2b, y_out);
  }
}

// Round 6
// 792.291 us; speedup vs baseline: 10.4487x; 1.2672x over previous
//
#include <hip/hip_runtime.h>
#include <math.h>

// ---- static config ----
#define BB 32
#define TT 12
#define NN 500
#define UU 32
#define CC 32
#define NSKIPC 256
#define NENDC 512
#define NPREDC 12
#define TX 13
#define TG 12
#define QS 384
#define VS 512
#define BNN (BB*NN)
#define DSZ (BNN*TG*CC)
#define BN_EPS 1e-5f

// ---- workspace offsets (floats) ----
#define OFF_V      0u
#define OFF_ADJ    16000u        // adj 500000; tail reused as part2 (4096) after supports
#define OFF_ASRC   516000u
#define OFF_ADST   548000u
#define OFF_PROJ   580000u
#define OFF_STAT   582048u
#define OFF_PART   582560u
#define OFF_BSUM   774560u
#define OFF_X      774816u
#define OFF_XN     7430816u
#define OFF_D      14086816u     // shorts 4*6144000 = 24576000 (12288000 floats)
#define OFF_GBF    38662816u     // shorts 6144000 (G bf16 [16000][384])
#define OFF_GLB    41734816u     // shorts 4096000 (Glast bf16 [16000][256])
#define OFF_GT     43782816u     // shorts 6291456
#define OFF_ST     46928544u     // shorts 524288
#define OFF_SB     47190688u
#define OFF_ST2    47452832u
#define OFF_WSTB   47714976u     // shorts 65536
#define OFF_O1WB   47747744u     // shorts 131072
#define OFF_SKV    47813280u     // shorts 4096000 (skipv bf16)
#define OFF_Y1B    49861280u     // shorts 8192000 (Y1 bf16) -> ends 53957280

typedef __attribute__((ext_vector_type(8))) short bf16x8;
typedef __attribute__((ext_vector_type(4))) float f32x4;

__device__ inline unsigned short f2bf(float f) {
  union { float f; unsigned u; } x; x.f = f;
  unsigned r = x.u + 0x7FFFu + ((x.u >> 16) & 1u);
  return (unsigned short)(r >> 16);
}
__device__ inline float bf2f(short s) {
  union { float f; unsigned u; } x;
  x.u = ((unsigned)(unsigned short)s) << 16;
  return x.f;
}
__device__ inline int pk2(float a, float b) {
  return (int)((unsigned)f2bf(a) | ((unsigned)f2bf(b) << 16));
}
__device__ inline bf16x8 pack8(f32x4 a, f32x4 b) {
  union { int i[4]; bf16x8 v; } u;
  u.i[0]=pk2(a.x,a.y); u.i[1]=pk2(a.z,a.w);
  u.i[2]=pk2(b.x,b.y); u.i[3]=pk2(b.z,b.w);
  return u.v;
}
__device__ inline f32x4 reluadd(f32x4 a, f32x4 b) {
  f32x4 r;
  r.x=fmaxf(a.x+b.x,0.f); r.y=fmaxf(a.y+b.y,0.f);
  r.z=fmaxf(a.z+b.z,0.f); r.w=fmaxf(a.w+b.w,0.f);
  return r;
}

// ================= adaptive supports =================

__global__ void k_v(const float* __restrict__ factor, const float* __restrict__ map_w,
                    const float* __restrict__ map_b, float* __restrict__ v) {
  int n = blockIdx.x; int d = threadIdx.x;
  __shared__ float fr[UU];
  fr[d] = factor[n*UU + d];
  __syncthreads();
  float acc = map_b[d];
#pragma unroll
  for (int u=0;u<UU;u++) acc += fr[u]*map_w[u*32+d];
  v[n*32+d] = fmaxf(acc, 0.f);
}

__global__ void k_asrc2(const float* __restrict__ v, const float* __restrict__ a1w,
                        const float* __restrict__ a1b,
                        float* __restrict__ asrc, float* __restrict__ adst) {
  int n = blockIdx.x; int o = threadIdx.x; // 64 threads
  __shared__ float vn[32];
  if (o < 32) vn[o] = v[n*32+o];
  __syncthreads();
  float s = 0.f, dst = a1b[o];
#pragma unroll
  for (int u=0;u<32;u++){ s += vn[u]*a1w[u*64+o]; dst += vn[u]*a1w[(32+u)*64+o]; }
  asrc[n*64+o] = s;
  adst[n*64+o] = dst;
}

__global__ __launch_bounds__(256) void k_pair3(const float* __restrict__ asrc,
    const float* __restrict__ adst, const float* __restrict__ a2w,
    const float* __restrict__ a2b, const float* __restrict__ a3w,
    const float* __restrict__ a3b, float* __restrict__ adj) {
  int i = blockIdx.x;
  int tid = threadIdx.x;
  int wid = tid>>6, lane = tid&63;
  int lm = lane&15, g = lane>>4, lk8 = g*8;
  int jb = blockIdx.y*256 + wid*64;
  bf16x8 wf[2][2];
#pragma unroll
  for (int ks=0;ks<2;ks++)
#pragma unroll
    for (int nh=0;nh<2;nh++){
      int n = nh*16+lm;
      f32x4 lo, hi;
      lo.x=a2w[(ks*32+lk8+0)*32+n]; lo.y=a2w[(ks*32+lk8+1)*32+n];
      lo.z=a2w[(ks*32+lk8+2)*32+n]; lo.w=a2w[(ks*32+lk8+3)*32+n];
      hi.x=a2w[(ks*32+lk8+4)*32+n]; hi.y=a2w[(ks*32+lk8+5)*32+n];
      hi.z=a2w[(ks*32+lk8+6)*32+n]; hi.w=a2w[(ks*32+lk8+7)*32+n];
      wf[ks][nh] = pack8(lo, hi);
    }
  float b20 = a2b[lm], b21 = a2b[16+lm];
  float w3e0n0 = a3w[lm*2],      w3e1n0 = a3w[lm*2+1];
  float w3e0n1 = a3w[(16+lm)*2], w3e1n1 = a3w[(16+lm)*2+1];
  float b30 = a3b[0], b31 = a3b[1];
  const float* dp = adst + i*64;
  f32x4 d00 = *(const f32x4*)(dp + lk8);
  f32x4 d01 = *(const f32x4*)(dp + lk8 + 4);
  f32x4 d10 = *(const f32x4*)(dp + 32 + lk8);
  f32x4 d11 = *(const f32x4*)(dp + 32 + lk8 + 4);
#pragma unroll
  for (int mg=0; mg<4; mg++){
    int j = jb + mg*16 + lm;
    int jc = j < 500 ? j : 0;
    const float* ap = asrc + jc*64;
    f32x4 s00=*(const f32x4*)(ap+lk8),    s01=*(const f32x4*)(ap+lk8+4);
    f32x4 s10=*(const f32x4*)(ap+32+lk8), s11=*(const f32x4*)(ap+32+lk8+4);
    bf16x8 a0 = pack8(reluadd(s00,d00), reluadd(s01,d01));
    bf16x8 a1 = pack8(reluadd(s10,d10), reluadd(s11,d11));
    f32x4 acc0 = {b20,b20,b20,b20};
    f32x4 acc1 = {b21,b21,b21,b21};
    acc0 = __builtin_amdgcn_mfma_f32_16x16x32_bf16(a0, wf[0][0], acc0, 0,0,0);
    acc0 = __builtin_amdgcn_mfma_f32_16x16x32_bf16(a1, wf[1][0], acc0, 0,0,0);
    acc1 = __builtin_amdgcn_mfma_f32_16x16x32_bf16(a0, wf[0][1], acc1, 0,0,0);
    acc1 = __builtin_amdgcn_mfma_f32_16x16x32_bf16(a1, wf[1][1], acc1, 0,0,0);
    float e0[4], e1[4];
#pragma unroll
    for (int r=0;r<4;r++){
      float h2a = fmaxf(acc0[r],0.f), h2b = fmaxf(acc1[r],0.f);
      e0[r] = h2a*w3e0n0 + h2b*w3e0n1;
      e1[r] = h2a*w3e1n0 + h2b*w3e1n1;
    }
#pragma unroll
    for (int off=1; off<16; off<<=1){
#pragma unroll
      for (int r=0;r<4;r++){ e0[r]+=__shfl_xor(e0[r],off); e1[r]+=__shfl_xor(e1[r],off); }
    }
    if (lm==0){
      int j4 = jb + mg*16 + g*4;
      if (j4 < 500){
        f32x4 v0={e0[0]+b30,e0[1]+b30,e0[2]+b30,e0[3]+b30};
        f32x4 v1={e1[0]+b31,e1[1]+b31,e1[2]+b31,e1[3]+b31};
        *(f32x4*)(adj + i*500 + j4) = v0;
        *(f32x4*)(adj + 250000 + i*500 + j4) = v1;
      }
    }
  }
}

__global__ __launch_bounds__(256) void k_softmax(const float* __restrict__ adj,
    float* __restrict__ sup_out) {
  int row = blockIdx.x;
  int e = row/NN, i = row%NN;
  const float* a = adj + e*250000 + i*NN;
  __shared__ float red[64];
  float m = -1e30f;
  for (int j=threadIdx.x;j<NN;j+=256) m = fmaxf(m, a[j]);
#pragma unroll
  for (int off=32; off; off>>=1) m = fmaxf(m, __shfl_down(m, off));
  int lane = threadIdx.x & 63, wid = threadIdx.x >> 6;
  if (lane==0) red[wid]=m;
  __syncthreads();
  if (threadIdx.x==0){ float mm=red[0]; for(int w=1;w<4;w++) mm=fmaxf(mm,red[w]); red[32]=mm; }
  __syncthreads();
  m = red[32];
  float s=0.f;
  for (int j=threadIdx.x;j<NN;j+=256) s += __expf(a[j]-m);
#pragma unroll
  for (int off=32; off; off>>=1) s += __shfl_down(s, off);
  if (lane==0) red[wid]=s;
  __syncthreads();
  if (threadIdx.x==0){ float ss=0; for(int w=0;w<4;w++) ss+=red[w]; red[33]=ss; }
  __syncthreads();
  float inv = 1.f/red[33];
  for (int j=threadIdx.x;j<NN;j+=256) {
    float val = __expf(a[j]-m)*inv;
    if (j==i) val = 1.f;
    sup_out[e*250000 + i*NN + j] = val;
  }
}

// ST[e][w][v] transposed bf16 + SB[e][v][w] cast bf16 (both 512x512 zero-padded)
__global__ __launch_bounds__(256) void k_tposeS(const float* __restrict__ sup,
    short* __restrict__ ST, short* __restrict__ SB) {
  __shared__ float ts[64][68];
  int e = blockIdx.z;
  int v0 = blockIdx.x*64, w0 = blockIdx.y*64;
  int tid = threadIdx.x;
  int vv = tid>>2, wc = (tid&3)*16;
  bool vok = (v0+vv) < 500;
#pragma unroll
  for (int c=0;c<4;c++){
    f32x4 val = {0,0,0,0};
    int wg = w0 + wc + c*4;
    if (vok && wg < 500) val = *(const f32x4*)(sup + e*250000 + (size_t)(v0+vv)*500 + wg);
    *(f32x4*)&ts[vv][wc + c*4] = val;
    int2 pv; pv.x = pk2(val.x, val.y); pv.y = pk2(val.z, val.w);
    *(int2*)(SB + (size_t)e*(512*512) + (size_t)(v0+vv)*VS + wg) = pv;
  }
  __syncthreads();
  int w = tid>>2, vc = (tid&3)*16;
  unsigned short u[16];
#pragma unroll
  for (int j=0;j<16;j++) u[j] = f2bf(ts[vc+j][w]);
  int4 o0, o1;
  o0.x = u[0]|(u[1]<<16);  o0.y = u[2]|(u[3]<<16);
  o0.z = u[4]|(u[5]<<16);  o0.w = u[6]|(u[7]<<16);
  o1.x = u[8]|(u[9]<<16);  o1.y = u[10]|(u[11]<<16);
  o1.z = u[12]|(u[13]<<16); o1.w = u[14]|(u[15]<<16);
  short* op = ST + (size_t)e*(512*512) + (size_t)(w0+w)*VS + v0 + vc;
  *(int4*)(op) = o0;
  *(int4*)(op+8) = o1;
}

// ST2[e] = (S@S)^T stored [w][u]
__global__ __launch_bounds__(256) void k_ssq(const short* __restrict__ SB,
    const short* __restrict__ ST, short* __restrict__ ST2) {
  __shared__ __align__(16) short As[64*72];
  __shared__ __align__(16) short Bs[64*72];
  int e = blockIdx.z;
  int u0 = blockIdx.x*64, w0 = blockIdx.y*64;
  const short* Ab = SB + (size_t)e*(512*512);
  const short* Bb = ST + (size_t)e*(512*512);
  int tid = threadIdx.x;
  int row = tid>>2, col = (tid&3)*16;
  const short* ap = Ab + (size_t)(u0+row)*VS + col;
  const short* bp = Bb + (size_t)(w0+row)*VS + col;
  f32x4 ra0 = *(const f32x4*)(ap);
  f32x4 ra1 = *(const f32x4*)(ap+8);
  f32x4 rb0 = *(const f32x4*)(bp);
  f32x4 rb1 = *(const f32x4*)(bp+8);
  int wid = tid>>6, lane = tid&63;
  int wr = wid>>1, wc = wid&1;
  int lm = lane&15, lk = (lane>>4)*8;
  f32x4 acc[2][2] = {};
  short* aw = As + row*72 + col;
  short* bw = Bs + row*72 + col;
  for (int kk=0; kk<8; kk++) {
    __syncthreads();
    *(f32x4*)(aw) = ra0; *(f32x4*)(aw+8) = ra1;
    *(f32x4*)(bw) = rb0; *(f32x4*)(bw+8) = rb1;
    __syncthreads();
    if (kk < 7) {
      const short* ap2 = ap + (kk+1)*64;
      const short* bp2 = bp + (kk+1)*64;
      ra0 = *(const f32x4*)(ap2); ra1 = *(const f32x4*)(ap2+8);
      rb0 = *(const f32x4*)(bp2); rb1 = *(const f32x4*)(bp2+8);
    }
#pragma unroll
    for (int ks=0; ks<2; ks++) {
      bf16x8 af0 = *(const bf16x8*)(As + (wr*32 + lm)*72 + ks*32 + lk);
      bf16x8 af1 = *(const bf16x8*)(As + (wr*32 + 16 + lm)*72 + ks*32 + lk);
      bf16x8 bq0 = *(const bf16x8*)(Bs + (wc*32 + lm)*72 + ks*32 + lk);
      bf16x8 bq1 = *(const bf16x8*)(Bs + (wc*32 + 16 + lm)*72 + ks*32 + lk);
      acc[0][0] = __builtin_amdgcn_mfma_f32_16x16x32_bf16(af0, bq0, acc[0][0], 0,0,0);
      acc[0][1] = __builtin_amdgcn_mfma_f32_16x16x32_bf16(af0, bq1, acc[0][1], 0,0,0);
      acc[1][0] = __builtin_amdgcn_mfma_f32_16x16x32_bf16(af1, bq0, acc[1][0], 0,0,0);
      acc[1][1] = __builtin_amdgcn_mfma_f32_16x16x32_bf16(af1, bq1, acc[1][1], 0,0,0);
    }
  }
#pragma unroll
  for (int fm=0; fm<2; fm++) {
    int u4 = u0 + wr*32 + fm*16 + (lane>>4)*4;
#pragma unroll
    for (int fn=0; fn<2; fn++) {
      int w = w0 + wc*32 + fn*16 + lm;
      f32x4 v4 = acc[fm][fn];
      int2 pv; pv.x = pk2(v4.x, v4.y); pv.y = pk2(v4.z, v4.w);
      *(int2*)(ST2 + (size_t)e*(512*512) + (size_t)w*VS + u4) = pv;
    }
  }
}

// GT[b][q][v] bf16 from Gbf[b*NN+v][q] bf16
__global__ __launch_bounds__(256) void k_tposeGb(const short* __restrict__ Gbf,
    short* __restrict__ GT, int qmax) {
  __shared__ __align__(16) short ts[64][72];
  int b = blockIdx.z;
  int v0 = blockIdx.x*64, q0 = blockIdx.y*64;
  int tid = threadIdx.x;
  int vv = tid>>2, qc = (tid&3)*16;
  bool ok = ((v0+vv) < 500) && ((q0+qc) < qmax);
  int4 z4 = {0,0,0,0};
  int4 i0 = z4, i1 = z4;
  if (ok){
    const short* gp = Gbf + (size_t)(b*NN + v0+vv)*QS + q0 + qc;
    i0 = *(const int4*)(gp);
    i1 = *(const int4*)(gp+8);
  }
  *(int4*)&ts[vv][qc] = i0;
  *(int4*)&ts[vv][qc+8] = i1;
  __syncthreads();
  int q = tid>>2, vc = (tid&3)*16;
  if (q0 + q < qmax) {
    unsigned short u[16];
#pragma unroll
    for (int j=0;j<16;j++) u[j] = (unsigned short)ts[vc+j][q];
    int4 o0, o1;
    o0.x = u[0]|(u[1]<<16);  o0.y = u[2]|(u[3]<<16);
    o0.z = u[4]|(u[5]<<16);  o0.w = u[6]|(u[7]<<16);
    o1.x = u[8]|(u[9]<<16);  o1.y = u[10]|(u[11]<<16);
    o1.z = u[12]|(u[13]<<16); o1.w = u[14]|(u[15]<<16);
    short* op = GT + ((size_t)b*QS + q0+q)*VS + v0 + vc;
    *(int4*)(op) = o0;
    *(int4*)(op+8) = o1;
  }
}

// Merged MFMA diffusion: blockIdx.z = b*4 + (e*2+hop); OUT bf16
__global__ __launch_bounds__(256) void k_hop(const short* __restrict__ ST,
    const short* __restrict__ ST2, const short* __restrict__ GT,
    short* __restrict__ Dout, int qmax) {
  __shared__ __align__(16) short As[64*72];
  __shared__ __align__(16) short Bs[64*72];
  int sel = blockIdx.z & 3, b = blockIdx.z >> 2;
  int e = sel >> 1, hop = sel & 1;
  int w0 = blockIdx.x*64, q0 = blockIdx.y*64;
  const short* Ab = (hop ? ST2 : ST) + (size_t)e*(512*512);
  const short* Bb = GT + (size_t)b*(QS*VS);
  int tid = threadIdx.x;
  int row = tid>>2, col = (tid&3)*16;
  const short* ap = Ab + (size_t)(w0+row)*VS + col;
  const short* bp = Bb + (size_t)(q0+row)*VS + col;
  bool bok = (q0+row) < qmax;
  f32x4 zero4 = {0,0,0,0};
  f32x4 ra0 = *(const f32x4*)(ap);
  f32x4 ra1 = *(const f32x4*)(ap+8);
  f32x4 rb0 = bok ? *(const f32x4*)(bp) : zero4;
  f32x4 rb1 = bok ? *(const f32x4*)(bp+8) : zero4;
  int wid = tid>>6, lane = tid&63;
  int wr = wid>>1, wc = wid&1;
  int lm = lane&15, lk = (lane>>4)*8;
  f32x4 acc[2][2] = {};
  short* aw = As + row*72 + col;
  short* bw = Bs + row*72 + col;
  for (int kk=0; kk<8; kk++) {
    __syncthreads();
    *(f32x4*)(aw) = ra0; *(f32x4*)(aw+8) = ra1;
    *(f32x4*)(bw) = rb0; *(f32x4*)(bw+8) = rb1;
    __syncthreads();
    if (kk < 7) {
      const short* ap2 = ap + (kk+1)*64;
      const short* bp2 = bp + (kk+1)*64;
      ra0 = *(const f32x4*)(ap2); ra1 = *(const f32x4*)(ap2+8);
      rb0 = bok ? *(const f32x4*)(bp2) : zero4;
      rb1 = bok ? *(const f32x4*)(bp2+8) : zero4;
    }
#pragma unroll
    for (int ks=0; ks<2; ks++) {
      bf16x8 af0 = *(const bf16x8*)(As + (wr*32 + lm)*72 + ks*32 + lk);
      bf16x8 af1 = *(const bf16x8*)(As + (wr*32 + 16 + lm)*72 + ks*32 + lk);
      bf16x8 bq0 = *(const bf16x8*)(Bs + (wc*32 + lm)*72 + ks*32 + lk);
      bf16x8 bq1 = *(const bf16x8*)(Bs + (wc*32 + 16 + lm)*72 + ks*32 + lk);
      acc[0][0] = __builtin_amdgcn_mfma_f32_16x16x32_bf16(af0, bq0, acc[0][0], 0,0,0);
      acc[0][1] = __builtin_amdgcn_mfma_f32_16x16x32_bf16(af0, bq1, acc[0][1], 0,0,0);
      acc[1][0] = __builtin_amdgcn_mfma_f32_16x16x32_bf16(af1, bq0, acc[1][0], 0,0,0);
      acc[1][1] = __builtin_amdgcn_mfma_f32_16x16x32_bf16(af1, bq1, acc[1][1], 0,0,0);
    }
  }
  short* Ob = Dout + (size_t)sel*DSZ + (size_t)b*(NN*QS);
#pragma unroll
  for (int fm=0; fm<2; fm++) {
    int wb4 = w0 + wr*32 + fm*16 + (lane>>4)*4;
    if (wb4 >= 500) continue;
#pragma unroll
    for (int fn=0; fn<2; fn++) {
      int q = q0 + wc*32 + fn*16 + lm;
      if (q < qmax) {
        f32x4 v4 = acc[fm][fn];
        short* op = Ob + (size_t)wb4*QS + q;
        op[0*QS] = (short)f2bf(v4.x);
        op[1*QS] = (short)f2bf(v4.y);
        op[2*QS] = (short)f2bf(v4.z);
        op[3*QS] = (short)f2bf(v4.w);
      }
    }
  }
}

// ================= input projection / enter conv =================

__global__ void k_proj(const float* __restrict__ inputs, const float* __restrict__ factor,
                       float* __restrict__ proj) {
  int bt = blockIdx.x;
  __shared__ float xin[NN*2];
  for (int idx=threadIdx.x; idx<NN*2; idx+=64) xin[idx] = inputs[bt*NN*2 + idx];
  __syncthreads();
  int u = threadIdx.x>>1, f = threadIdx.x&1;
  float acc=0.f;
  for (int n=0;n<NN;n++) acc += xin[n*2+f]*factor[n*UU+u];
  proj[bt*64 + u*2+f] = acc;
}

__global__ __launch_bounds__(256) void k_enter(const float* __restrict__ inputs,
    const float* __restrict__ factor, const float* __restrict__ proj,
    const float* __restrict__ ew, const float* __restrict__ eb, float* __restrict__ X) {
  int idx = blockIdx.x*256+threadIdx.x;
  if (idx >= BB*NN*TX) return;
  int t = idx % TX; int n = (idx/TX)%NN; int b = idx/(TX*NN);
  float x4[4]={0.f,0.f,0.f,0.f};
  if (t>0) {
    int tt=t-1;
    float s0=0.f,s1=0.f;
    const float* pr = proj + (b*TT+tt)*64;
    const float* fr = factor + n*UU;
#pragma unroll
    for(int u=0;u<UU;u++){ s0 += pr[u*2]*fr[u]; s1 += pr[u*2+1]*fr[u]; }
    float i0 = inputs[((b*TT+tt)*NN+n)*2];
    float i1 = inputs[((b*TT+tt)*NN+n)*2+1];
    x4[0]=s0; x4[1]=s1; x4[2]=i0-s0; x4[3]=i1-s1;
  }
  float* xp = X + ((size_t)(b*NN+n)*TX + t)*CC;
#pragma unroll
  for(int o=0;o<CC;o++){
    xp[o] = eb[o] + ew[o*4]*x4[0] + ew[o*4+1]*x4[1] + ew[o*4+2]*x4[2] + ew[o*4+3]*x4[3];
  }
}

// ================= MFMA gated temporal conv =================

__global__ __launch_bounds__(256) void k_gated3(const float* __restrict__ X,
    short* __restrict__ Gbf, short* __restrict__ Glb,
    const float* __restrict__ fw, const float* __restrict__ fb,
    const float* __restrict__ gw, const float* __restrict__ gb,
    const float* __restrict__ stat, int use_stat, int d, int t_out, int lidx) {
  __shared__ __align__(16) short As[64*72];
  __shared__ __align__(16) short Wb[64*72];
  __shared__ float scs[32], shs[32];
  int tid = threadIdx.x;
  if (tid < 32) {
    scs[tid] = use_stat ? stat[tid] : 1.0f;
    shs[tid] = use_stat ? stat[32 + tid] : 0.0f;
  }
  for (int i = tid; i < 2048; i += 256) {
    int o = i >> 6, k = i & 63;
    Wb[o*72 + k]      = (short)f2bf(fw[i]);
    Wb[(32+o)*72 + k] = (short)f2bf(gw[i]);
  }
  __syncthreads();
  int m0 = blockIdx.x * 64;
  {
    int mm = tid & 63;
    int kb = (tid >> 6) * 16;
    int c0 = kb >> 1;
    int m = m0 + mm;
    int bn = m / t_out, t = m - bn * t_out;
    const float* xr = X + (size_t)bn * (TX * CC);
    float4 a0 = *(const float4*)(xr + t * 32 + c0);
    float4 a1 = *(const float4*)(xr + t * 32 + c0 + 4);
    float4 b0 = *(const float4*)(xr + (t + d) * 32 + c0);
    float4 b1 = *(const float4*)(xr + (t + d) * 32 + c0 + 4);
    float va[8] = {a0.x,a0.y,a0.z,a0.w,a1.x,a1.y,a1.z,a1.w};
    float vb[8] = {b0.x,b0.y,b0.z,b0.w,b1.x,b1.y,b1.z,b1.w};
    int iv[8];
#pragma unroll
    for (int j = 0; j < 8; j++) {
      float sc = scs[c0+j], sh = shs[c0+j];
      iv[j] = pk2(va[j]*sc + sh, vb[j]*sc + sh);
    }
    int4 w0 = {iv[0],iv[1],iv[2],iv[3]};
    int4 w1 = {iv[4],iv[5],iv[6],iv[7]};
    *(int4*)(As + mm*72 + kb) = w0;
    *(int4*)(As + mm*72 + kb + 8) = w1;
  }
  __syncthreads();
  int wid = tid>>6, lane = tid&63;
  int lm = lane&15, g = lane>>4, lk8 = g*8;
  f32x4 acc[4] = {};
#pragma unroll
  for (int kk=0; kk<2; kk++){
    bf16x8 af = *(const bf16x8*)(As + (wid*16+lm)*72 + kk*32 + lk8);
#pragma unroll
    for (int fn=0; fn<4; fn++){
      bf16x8 bq = *(const bf16x8*)(Wb + (fn*16+lm)*72 + kk*32 + lk8);
      acc[fn] = __builtin_amdgcn_mfma_f32_16x16x32_bf16(af, bq, acc[fn], 0,0,0);
    }
  }
#pragma unroll
  for (int fn=0; fn<2; fn++){
    int o = fn*16 + lm;
    float fbv = fb[o], gbv = gb[o];
#pragma unroll
    for (int r=0; r<4; r++){
      int m = m0 + wid*16 + g*4 + r;
      int bn = m / t_out, t = m - bn*t_out;
      float f = acc[fn][r] + fbv;
      float gg = acc[fn+2][r] + gbv;
      float th = 2.f/(1.f+__expf(-2.f*f)) - 1.f;
      float sg = 1.f/(1.f+__expf(-gg));
      unsigned short ov = f2bf(th*sg);
      Gbf[(size_t)bn*QS + t*32 + o] = (short)ov;
      if (t == t_out-1) Glb[(size_t)bn*256 + lidx*32 + o] = (short)ov;
    }
  }
}

// ======= MFMA graph-conv 1x1 + residual + BN partials =======

template<int TOUT>
__global__ __launch_bounds__(64) void k_gc3(const short* __restrict__ Gbf,
    const short* __restrict__ Dbf, const float* __restrict__ Xc, float* __restrict__ Xn,
    const float* __restrict__ gcw, const float* __restrict__ gcb,
    const float* __restrict__ stat, int use_stat, float* __restrict__ part, int d) {
  int tid = threadIdx.x;
  int lm = tid&15, g = tid>>4, lk8 = g*8;
  bf16x8 wf[5][2];
#pragma unroll
  for (int ks=0;ks<5;ks++)
#pragma unroll
    for (int nh=0;nh<2;nh++){
      const float* wp = gcw + (nh*16+lm)*160 + ks*32 + lk8;
      wf[ks][nh] = pack8(*(const f32x4*)wp, *(const f32x4*)(wp+4));
    }
  float scn0 = use_stat ? stat[lm]    : 1.f;
  float scn1 = use_stat ? stat[16+lm] : 1.f;
  float shn0 = use_stat ? stat[32+lm] : 0.f;
  float shn1 = use_stat ? stat[48+lm] : 0.f;
  float gb0 = gcb[lm], gb1 = gcb[16+lm];
  int m0 = blockIdx.x*64;
  float ss0=0.f, sq0=0.f, ss1=0.f, sq1=0.f;
#pragma unroll
  for (int mg=0; mg<4; mg++){
    int m = m0 + mg*16 + lm;
    int bn = m / TOUT; int t = m - bn*TOUT;
    size_t off = (size_t)bn*(TG*CC) + t*32 + lk8;
    f32x4 acc0={0,0,0,0}, acc1={0,0,0,0};
    {
      bf16x8 af = *(const bf16x8*)(Gbf + off);
      acc0 = __builtin_amdgcn_mfma_f32_16x16x32_bf16(af, wf[0][0], acc0, 0,0,0);
      acc1 = __builtin_amdgcn_mfma_f32_16x16x32_bf16(af, wf[0][1], acc1, 0,0,0);
    }
#pragma unroll
    for (int ks=1;ks<5;ks++){
      bf16x8 af = *(const bf16x8*)(Dbf + (size_t)(ks-1)*DSZ + off);
      acc0 = __builtin_amdgcn_mfma_f32_16x16x32_bf16(af, wf[ks][0], acc0, 0,0,0);
      acc1 = __builtin_amdgcn_mfma_f32_16x16x32_bf16(af, wf[ks][1], acc1, 0,0,0);
    }
#pragma unroll
    for (int r=0;r<4;r++){
      int mr = m0 + mg*16 + g*4 + r;
      int bnr = mr / TOUT; int tr = mr - bnr*TOUT;
      size_t xoff = (size_t)bnr*(TX*CC);
      float r0 = Xc[xoff + (tr+d)*32 + lm];
      float r1 = Xc[xoff + (tr+d)*32 + 16 + lm];
      float v0 = acc0[r] + gb0 + r0*scn0 + shn0;
      float v1 = acc1[r] + gb1 + r1*scn1 + shn1;
      Xn[xoff + tr*32 + lm] = v0;
      Xn[xoff + tr*32 + 16 + lm] = v1;
      ss0+=v0; sq0+=v0*v0; ss1+=v1; sq1+=v1*v1;
    }
  }
#pragma unroll
  for (int off=16; off<64; off<<=1){
    ss0+=__shfl_xor(ss0,off); sq0+=__shfl_xor(sq0,off);
    ss1+=__shfl_xor(ss1,off); sq1+=__shfl_xor(sq1,off);
  }
  if (tid<16){
    float* pp = part + (size_t)blockIdx.x*64;
    pp[tid]=ss0; pp[16+tid]=ss1; pp[32+tid]=sq0; pp[48+tid]=sq1;
  }
}

// 2-stage BN-stat reduction
__global__ __launch_bounds__(64) void k_stat2a(const float* __restrict__ part, int nblk,
    float* __restrict__ part2) {
  int t = threadIdx.x;
  float s = 0.f;
  for (int i = blockIdx.x; i < nblk; i += 64) s += part[(size_t)i*64 + t];
  part2[blockIdx.x*64 + t] = s;
}

__global__ __launch_bounds__(64) void k_stat2b(const float* __restrict__ part2,
    const float* __restrict__ g, const float* __restrict__ b,
    float* __restrict__ statout, float cntinv) {
  int t = threadIdx.x;
  float s = 0.f;
#pragma unroll 8
  for (int i = 0; i < 64; i++) s += part2[i*64 + t];
  __shared__ float red[64];
  red[t] = s;
  __syncthreads();
  if (t < 32){
    float sum = red[t], sq = red[32+t];
    float m = sum*cntinv, var = sq*cntinv - m*m;
    float sc = rsqrtf(var + BN_EPS)*g[t];
    statout[t] = sc;
    statout[32+t] = b[t] - m*sc;
  }
}

// ================= output head =================

__global__ void k_wstack2(const float* __restrict__ skp_w, const float* __restrict__ skp_b,
                          const float* __restrict__ o1w,
                          short* __restrict__ Wstb, short* __restrict__ o1wb,
                          float* __restrict__ bsum) {
  int bid = blockIdx.x;
  int idx = bid*256 + threadIdx.x;
  if (bid < 256){
    int kk = idx >> 8, o = idx & 255;
    Wstb[o*256 + kk] = (short)f2bf(skp_w[(kk>>5)*8192 + o*32 + (kk&31)]);
    if (idx < 256){
      float s=0.f;
      for (int l=0;l<8;l++) s += skp_b[l*256+idx];
      bsum[idx]=s;
    }
  } else {
    int j = idx - 65536;
    o1wb[j] = (short)f2bf(o1w[j]);
  }
}

// C[m][n] = relu(sum_k A[m][k]*B[n][k] + bias[n]) -> bf16 out
__global__ __launch_bounds__(256) void k_mm(const short* __restrict__ A,
    const short* __restrict__ B, const float* __restrict__ bias,
    short* __restrict__ out, int ldout, int K) {
  __shared__ __align__(16) short As[64*72];
  __shared__ __align__(16) short Bs[64*72];
  int m0 = blockIdx.x*64, n0 = blockIdx.y*64;
  int tid = threadIdx.x;
  int row = tid>>2, col = (tid&3)*16;
  const short* ap = A + (size_t)(m0+row)*K + col;
  const short* bp = B + (size_t)(n0+row)*K + col;
  f32x4 ra0 = *(const f32x4*)(ap);
  f32x4 ra1 = *(const f32x4*)(ap+8);
  f32x4 rb0 = *(const f32x4*)(bp);
  f32x4 rb1 = *(const f32x4*)(bp+8);
  int wid = tid>>6, lane = tid&63;
  int wr = wid>>1, wc = wid&1;
  int lm = lane&15, lk = (lane>>4)*8;
  f32x4 acc[2][2] = {};
  short* aw = As + row*72 + col;
  short* bw = Bs + row*72 + col;
  int nk = K>>6;
  for (int kk=0; kk<nk; kk++) {
    __syncthreads();
    *(f32x4*)(aw) = ra0; *(f32x4*)(aw+8) = ra1;
    *(f32x4*)(bw) = rb0; *(f32x4*)(bw+8) = rb1;
    __syncthreads();
    if (kk < nk-1) {
      const short* ap2 = ap + (kk+1)*64;
      const short* bp2 = bp + (kk+1)*64;
      ra0 = *(const f32x4*)(ap2); ra1 = *(const f32x4*)(ap2+8);
      rb0 = *(const f32x4*)(bp2); rb1 = *(const f32x4*)(bp2+8);
    }
#pragma unroll
    for (int ks=0; ks<2; ks++) {
      bf16x8 af0 = *(const bf16x8*)(As + (wr*32 + lm)*72 + ks*32 + lk);
      bf16x8 af1 = *(const bf16x8*)(As + (wr*32 + 16 + lm)*72 + ks*32 + lk);
      bf16x8 bq0 = *(const bf16x8*)(Bs + (wc*32 + lm)*72 + ks*32 + lk);
      bf16x8 bq1 = *(const bf16x8*)(Bs + (wc*32 + 16 + lm)*72 + ks*32 + lk);
      acc[0][0] = __builtin_amdgcn_mfma_f32_16x16x32_bf16(af0, bq0, acc[0][0], 0,0,0);
      acc[0][1] = __builtin_amdgcn_mfma_f32_16x16x32_bf16(af0, bq1, acc[0][1], 0,0,0);
      acc[1][0] = __builtin_amdgcn_mfma_f32_16x16x32_bf16(af1, bq0, acc[1][0], 0,0,0);
      acc[1][1] = __builtin_amdgcn_mfma_f32_16x16x32_bf16(af1, bq1, acc[1][1], 0,0,0);
    }
  }
#pragma unroll
  for (int fm=0; fm<2; fm++) {
    int mb = m0 + wr*32 + fm*16 + (lane>>4)*4;
#pragma unroll
    for (int fn=0; fn<2; fn++) {
      int n = n0 + wc*32 + fn*16 + lm;
      float bv = bias[n];
      f32x4 v4 = acc[fm][fn];
#pragma unroll
      for (int r=0;r<4;r++)
        out[(size_t)(mb+r)*ldout + n] = (short)f2bf(fmaxf(v4[r]+bv, 0.f));
    }
  }
}

__global__ __launch_bounds__(256) void k_head2c(const short* __restrict__ Y1b,
    const float* __restrict__ o2w, const float* __restrict__ o2b, float* __restrict__ y) {
  int tid = threadIdx.x;
  int ml = tid>>2, kc = tid&3;
  int m = blockIdx.x*64 + ml;
  float accs[NPREDC] = {};
  for (int e=kc*128; e<kc*128+128; e+=8){
    bf16x8 yv = *(const bf16x8*)(Y1b + (size_t)m*NENDC + e);
    float yf[8];
#pragma unroll
    for (int j=0;j<8;j++) yf[j] = bf2f(yv[j]);
#pragma unroll
    for (int p=0;p<NPREDC;p++){
      const float* wp = o2w + p*NENDC + e;
      float a = 0.f;
#pragma unroll
      for (int j=0;j<8;j++) a += wp[j]*yf[j];
      accs[p] += a;
    }
  }
#pragma unroll
  for (int off=1; off<4; off<<=1)
#pragma unroll
    for (int p=0;p<NPREDC;p++) accs[p] += __shfl_xor(accs[p], off);
  if (kc==0){
    int b=m/NN, n=m%NN;
#pragma unroll
    for (int p=0;p<NPREDC;p++) y[(b*NPREDC+p)*NN+n] = accs[p] + o2b[p];
  }
}

// ================= host =================

extern "C" void kernel_launch(void* const* d_in, const int* in_sizes, int n_in,
                              void* d_out, int out_size, void* d_ws, size_t ws_size,
                              hipStream_t stream) {
  const float* inputs  = (const float*)d_in[0];
  const float* factor  = (const float*)d_in[1];
  const float* map_w   = (const float*)d_in[2];
  const float* map_b   = (const float*)d_in[3];
  const float* a1w     = (const float*)d_in[4];
  const float* a1b     = (const float*)d_in[5];
  const float* a2w     = (const float*)d_in[6];
  const float* a2b     = (const float*)d_in[7];
  const float* a3w     = (const float*)d_in[8];
  const float* a3b     = (const float*)d_in[9];
  const float* enter_w = (const float*)d_in[10];
  const float* enter_b = (const float*)d_in[11];
  const float* filt_w  = (const float*)d_in[12];
  const float* filt_b  = (const float*)d_in[13];
  const float* gate_w  = (const float*)d_in[14];
  const float* gate_b  = (const float*)d_in[15];
  const float* skp_w   = (const float*)d_in[16];
  const float* skp_b   = (const float*)d_in[17];
  const float* gc_w    = (const float*)d_in[18];
  const float* gc_b    = (const float*)d_in[19];
  const float* bn_g    = (const float*)d_in[20];
  const float* bn_b    = (const float*)d_in[21];
  const float* o1w     = (const float*)d_in[22];
  const float* o1b     = (const float*)d_in[23];
  const float* o2w     = (const float*)d_in[24];
  const float* o2b     = (const float*)d_in[25];
  (void)in_sizes; (void)n_in; (void)out_size; (void)ws_size;

  float* ws = (float*)d_ws;
  float* v      = ws + OFF_V;
  float* adj    = ws + OFF_ADJ;
  float* part2  = ws + OFF_ADJ;      // reuse (adj dead after k_tposeS)
  float* asrc   = ws + OFF_ASRC;
  float* adst   = ws + OFF_ADST;
  float* proj   = ws + OFF_PROJ;
  float* statb  = ws + OFF_STAT;
  float* part   = ws + OFF_PART;
  float* bsum   = ws + OFF_BSUM;
  float* X      = ws + OFF_X;
  float* Xn     = ws + OFF_XN;
  short* Dbf    = (short*)(ws + OFF_D);
  short* Gbf    = (short*)(ws + OFF_GBF);
  short* Glb    = (short*)(ws + OFF_GLB);
  short* GT     = (short*)(ws + OFF_GT);
  short* ST     = (short*)(ws + OFF_ST);
  short* SB     = (short*)(ws + OFF_SB);
  short* ST2    = (short*)(ws + OFF_ST2);
  short* Wstb   = (short*)(ws + OFF_WSTB);
  short* o1wb   = (short*)(ws + OFF_O1WB);
  short* skvb   = (short*)(ws + OFF_SKV);
  short* Y1b    = (short*)(ws + OFF_Y1B);

  float* y_out   = (float*)d_out;
  float* sup_out = y_out + BB*NPREDC*NN;

  // adaptive supports
  k_v<<<NN, 32, 0, stream>>>(factor, map_w, map_b, v);
  k_asrc2<<<NN, 64, 0, stream>>>(v, a1w, a1b, asrc, adst);
  {
    dim3 gp(NN, 2);
    k_pair3<<<gp, 256, 0, stream>>>(asrc, adst, a2w, a2b, a3w, a3b, adj);
  }
  k_softmax<<<2*NN, 256, 0, stream>>>(adj, sup_out);
  {
    dim3 gt(8, 8, 2);
    k_tposeS<<<gt, 256, 0, stream>>>(sup_out, ST, SB);
    k_ssq<<<gt, 256, 0, stream>>>(SB, ST, ST2);
  }

  // input split + enter
  k_proj<<<BB*TT, 64, 0, stream>>>(inputs, factor, proj);
  k_enter<<<(BB*NN*TX+255)/256, 256, 0, stream>>>(inputs, factor, proj, enter_w, enter_b, X);

  // head weight prep (independent)
  k_wstack2<<<768, 256, 0, stream>>>(skp_w, skp_b, o1w, Wstb, o1wb, bsum);

  float* Xc = X; float* Xo = Xn;
  int t = TX;
  static const int dil[8]={1,2,1,2,1,2,1,2};
  for (int l=0;l<7;l++){
    int d=dil[l], t_out=t-d;
    const float* st = statb + (l>0 ? (l-1)*64 : 0);
    k_gated3<<<250*t_out,256,0,stream>>>(Xc, Gbf, Glb, filt_w + l*2048, filt_b + l*32,
                                         gate_w + l*2048, gate_b + l*32, st, l>0, d, t_out, l);
    int qmax = t_out*CC;
    int qt = (qmax+63)/64;
    dim3 gtp(8, qt, 32);
    k_tposeGb<<<gtp,256,0,stream>>>(Gbf, GT, qmax);
    dim3 ghp(8, qt, 128);
    k_hop<<<ghp,256,0,stream>>>(ST, ST2, GT, Dbf, qmax);
    int nblk = 250*t_out;
    const float* gcwl = gc_w + l*5120;
    const float* gcbl = gc_b + l*32;
    switch (t_out){
      case 12: k_gc3<12><<<nblk,64,0,stream>>>(Gbf,Dbf,Xc,Xo,gcwl,gcbl,st,l>0,part,d); break;
      case 10: k_gc3<10><<<nblk,64,0,stream>>>(Gbf,Dbf,Xc,Xo,gcwl,gcbl,st,l>0,part,d); break;
      case  9: k_gc3< 9><<<nblk,64,0,stream>>>(Gbf,Dbf,Xc,Xo,gcwl,gcbl,st,l>0,part,d); break;
      case  7: k_gc3< 7><<<nblk,64,0,stream>>>(Gbf,Dbf,Xc,Xo,gcwl,gcbl,st,l>0,part,d); break;
      case  6: k_gc3< 6><<<nblk,64,0,stream>>>(Gbf,Dbf,Xc,Xo,gcwl,gcbl,st,l>0,part,d); break;
      case  4: k_gc3< 4><<<nblk,64,0,stream>>>(Gbf,Dbf,Xc,Xo,gcwl,gcbl,st,l>0,part,d); break;
      default: k_gc3< 3><<<nblk,64,0,stream>>>(Gbf,Dbf,Xc,Xo,gcwl,gcbl,st,l>0,part,d); break;
    }
    k_stat2a<<<64,64,0,stream>>>(part, nblk, part2);
    k_stat2b<<<1,64,0,stream>>>(part2, bn_g + l*32, bn_b + l*32,
                                statb + l*64, 1.f/(16000.f*(float)t_out));
    float* tmp=Xc; Xc=Xo; Xo=tmp;
    t = t_out;
  }
  // layer 8: only gated conv feeds skip
  k_gated3<<<250*1,256,0,stream>>>(Xc, Gbf, Glb, filt_w + 7*2048, filt_b + 7*32,
                                   gate_w + 7*2048, gate_b + 7*32, statb + 6*64, 1, 2, 1, 7);

  // head: skip GEMM -> head1 -> head2
  {
    dim3 gs(BNN/64, NSKIPC/64);
    k_mm<<<gs,256,0,stream>>>(Glb, Wstb, bsum, skvb, NSKIPC, 256);
    dim3 gh(BNN/64, NENDC/64);
    k_mm<<<gh,256,0,stream>>>(skvb, o1wb, o1b, Y1b, NENDC, 256);
    k_head2c<<<BNN/64,256,0,stream>>>(Y1b, o2w, o2b, y_out);
  }
}

// Round 8
// 771.424 us; speedup vs baseline: 10.7313x; 1.0270x over previous
//
#include <hip/hip_runtime.h>
#include <math.h>

// ---- static config ----
#define BB 32
#define TT 12
#define NN 500
#define UU 32
#define CC 32
#define NSKIPC 256
#define NENDC 512
#define NPREDC 12
#define TX 13
#define TG 12
#define QS 384
#define VS 512
#define BNN (BB*NN)
#define DSZ (BNN*TG*CC)
#define BN_EPS 1e-5f

// ---- workspace offsets (floats) ----
#define OFF_V      0u
#define OFF_ADJ    16000u        // adj 500000; tail reused as part2 (4096) after supports
#define OFF_ASRC   516000u
#define OFF_ADST   548000u
#define OFF_PROJ   580000u
#define OFF_STAT   582048u
#define OFF_PART   582560u       // 3000*64 = 192000
#define OFF_BSUM   774560u
#define OFF_X      774816u
#define OFF_XN     7430816u
#define OFF_D      14086816u     // shorts 4*6144000 = 24576000 (12288000 floats)
#define OFF_GBF    38662816u     // shorts 6144000 (G bf16 [16000][384])
#define OFF_GLB    41734816u     // shorts 4096000 (Glast bf16 [16000][256])
#define OFF_GT     43782816u     // shorts 6291456
#define OFF_ST     46928544u     // shorts 524288
#define OFF_SB     47190688u
#define OFF_ST2    47452832u
#define OFF_WSTB   47714976u     // shorts 65536
#define OFF_O1WB   47747744u     // shorts 131072
#define OFF_SKV    47813280u     // shorts 4096000 (skipv bf16)
#define OFF_Y1B    49861280u     // shorts 8192000 (Y1 bf16) -> ends 53957280

typedef __attribute__((ext_vector_type(8))) short bf16x8;
typedef __attribute__((ext_vector_type(4))) float f32x4;

__device__ inline unsigned short f2bf(float f) {
  union { float f; unsigned u; } x; x.f = f;
  unsigned r = x.u + 0x7FFFu + ((x.u >> 16) & 1u);
  return (unsigned short)(r >> 16);
}
__device__ inline float bf2f(short s) {
  union { float f; unsigned u; } x;
  x.u = ((unsigned)(unsigned short)s) << 16;
  return x.f;
}
__device__ inline int pk2(float a, float b) {
  return (int)((unsigned)f2bf(a) | ((unsigned)f2bf(b) << 16));
}
__device__ inline bf16x8 pack8(f32x4 a, f32x4 b) {
  union { int i[4]; bf16x8 v; } u;
  u.i[0]=pk2(a.x,a.y); u.i[1]=pk2(a.z,a.w);
  u.i[2]=pk2(b.x,b.y); u.i[3]=pk2(b.z,b.w);
  return u.v;
}
__device__ inline f32x4 reluadd(f32x4 a, f32x4 b) {
  f32x4 r;
  r.x=fmaxf(a.x+b.x,0.f); r.y=fmaxf(a.y+b.y,0.f);
  r.z=fmaxf(a.z+b.z,0.f); r.w=fmaxf(a.w+b.w,0.f);
  return r;
}

// ================= adaptive supports =================

__global__ void k_v(const float* __restrict__ factor, const float* __restrict__ map_w,
                    const float* __restrict__ map_b, float* __restrict__ v) {
  int n = blockIdx.x; int d = threadIdx.x;
  __shared__ float fr[UU];
  fr[d] = factor[n*UU + d];
  __syncthreads();
  float acc = map_b[d];
#pragma unroll
  for (int u=0;u<UU;u++) acc += fr[u]*map_w[u*32+d];
  v[n*32+d] = fmaxf(acc, 0.f);
}

__global__ void k_asrc2(const float* __restrict__ v, const float* __restrict__ a1w,
                        const float* __restrict__ a1b,
                        float* __restrict__ asrc, float* __restrict__ adst) {
  int n = blockIdx.x; int o = threadIdx.x; // 64 threads
  __shared__ float vn[32];
  if (o < 32) vn[o] = v[n*32+o];
  __syncthreads();
  float s = 0.f, dst = a1b[o];
#pragma unroll
  for (int u=0;u<32;u++){ s += vn[u]*a1w[u*64+o]; dst += vn[u]*a1w[(32+u)*64+o]; }
  asrc[n*64+o] = s;
  adst[n*64+o] = dst;
}

__global__ __launch_bounds__(256) void k_pair3(const float* __restrict__ asrc,
    const float* __restrict__ adst, const float* __restrict__ a2w,
    const float* __restrict__ a2b, const float* __restrict__ a3w,
    const float* __restrict__ a3b, float* __restrict__ adj) {
  int i = blockIdx.x;
  int tid = threadIdx.x;
  int wid = tid>>6, lane = tid&63;
  int lm = lane&15, g = lane>>4, lk8 = g*8;
  int jb = blockIdx.y*256 + wid*64;
  bf16x8 wf[2][2];
#pragma unroll
  for (int ks=0;ks<2;ks++)
#pragma unroll
    for (int nh=0;nh<2;nh++){
      int n = nh*16+lm;
      f32x4 lo, hi;
      lo.x=a2w[(ks*32+lk8+0)*32+n]; lo.y=a2w[(ks*32+lk8+1)*32+n];
      lo.z=a2w[(ks*32+lk8+2)*32+n]; lo.w=a2w[(ks*32+lk8+3)*32+n];
      hi.x=a2w[(ks*32+lk8+4)*32+n]; hi.y=a2w[(ks*32+lk8+5)*32+n];
      hi.z=a2w[(ks*32+lk8+6)*32+n]; hi.w=a2w[(ks*32+lk8+7)*32+n];
      wf[ks][nh] = pack8(lo, hi);
    }
  float b20 = a2b[lm], b21 = a2b[16+lm];
  float w3e0n0 = a3w[lm*2],      w3e1n0 = a3w[lm*2+1];
  float w3e0n1 = a3w[(16+lm)*2], w3e1n1 = a3w[(16+lm)*2+1];
  float b30 = a3b[0], b31 = a3b[1];
  const float* dp = adst + i*64;
  f32x4 d00 = *(const f32x4*)(dp + lk8);
  f32x4 d01 = *(const f32x4*)(dp + lk8 + 4);
  f32x4 d10 = *(const f32x4*)(dp + 32 + lk8);
  f32x4 d11 = *(const f32x4*)(dp + 32 + lk8 + 4);
#pragma unroll
  for (int mg=0; mg<4; mg++){
    int j = jb + mg*16 + lm;
    int jc = j < 500 ? j : 0;
    const float* ap = asrc + jc*64;
    f32x4 s00=*(const f32x4*)(ap+lk8),    s01=*(const f32x4*)(ap+lk8+4);
    f32x4 s10=*(const f32x4*)(ap+32+lk8), s11=*(const f32x4*)(ap+32+lk8+4);
    bf16x8 a0 = pack8(reluadd(s00,d00), reluadd(s01,d01));
    bf16x8 a1 = pack8(reluadd(s10,d10), reluadd(s11,d11));
    f32x4 acc0 = {b20,b20,b20,b20};
    f32x4 acc1 = {b21,b21,b21,b21};
    acc0 = __builtin_amdgcn_mfma_f32_16x16x32_bf16(a0, wf[0][0], acc0, 0,0,0);
    acc0 = __builtin_amdgcn_mfma_f32_16x16x32_bf16(a1, wf[1][0], acc0, 0,0,0);
    acc1 = __builtin_amdgcn_mfma_f32_16x16x32_bf16(a0, wf[0][1], acc1, 0,0,0);
    acc1 = __builtin_amdgcn_mfma_f32_16x16x32_bf16(a1, wf[1][1], acc1, 0,0,0);
    float e0[4], e1[4];
#pragma unroll
    for (int r=0;r<4;r++){
      float h2a = fmaxf(acc0[r],0.f), h2b = fmaxf(acc1[r],0.f);
      e0[r] = h2a*w3e0n0 + h2b*w3e0n1;
      e1[r] = h2a*w3e1n0 + h2b*w3e1n1;
    }
#pragma unroll
    for (int off=1; off<16; off<<=1){
#pragma unroll
      for (int r=0;r<4;r++){ e0[r]+=__shfl_xor(e0[r],off); e1[r]+=__shfl_xor(e1[r],off); }
    }
    if (lm==0){
      int j4 = jb + mg*16 + g*4;
      if (j4 < 500){
        f32x4 v0={e0[0]+b30,e0[1]+b30,e0[2]+b30,e0[3]+b30};
        f32x4 v1={e1[0]+b31,e1[1]+b31,e1[2]+b31,e1[3]+b31};
        *(f32x4*)(adj + i*500 + j4) = v0;
        *(f32x4*)(adj + 250000 + i*500 + j4) = v1;
      }
    }
  }
}

__global__ __launch_bounds__(256) void k_softmax(const float* __restrict__ adj,
    float* __restrict__ sup_out) {
  int row = blockIdx.x;
  int e = row/NN, i = row%NN;
  const float* a = adj + e*250000 + i*NN;
  __shared__ float red[64];
  float m = -1e30f;
  for (int j=threadIdx.x;j<NN;j+=256) m = fmaxf(m, a[j]);
#pragma unroll
  for (int off=32; off; off>>=1) m = fmaxf(m, __shfl_down(m, off));
  int lane = threadIdx.x & 63, wid = threadIdx.x >> 6;
  if (lane==0) red[wid]=m;
  __syncthreads();
  if (threadIdx.x==0){ float mm=red[0]; for(int w=1;w<4;w++) mm=fmaxf(mm,red[w]); red[32]=mm; }
  __syncthreads();
  m = red[32];
  float s=0.f;
  for (int j=threadIdx.x;j<NN;j+=256) s += __expf(a[j]-m);
#pragma unroll
  for (int off=32; off; off>>=1) s += __shfl_down(s, off);
  if (lane==0) red[wid]=s;
  __syncthreads();
  if (threadIdx.x==0){ float ss=0; for(int w=0;w<4;w++) ss+=red[w]; red[33]=ss; }
  __syncthreads();
  float inv = 1.f/red[33];
  for (int j=threadIdx.x;j<NN;j+=256) {
    float val = __expf(a[j]-m)*inv;
    if (j==i) val = 1.f;
    sup_out[e*250000 + i*NN + j] = val;
  }
}

// ST[e][w][v] transposed bf16 + SB[e][v][w] cast bf16 (both 512x512 zero-padded)
__global__ __launch_bounds__(256) void k_tposeS(const float* __restrict__ sup,
    short* __restrict__ ST, short* __restrict__ SB) {
  __shared__ float ts[64][68];
  int e = blockIdx.z;
  int v0 = blockIdx.x*64, w0 = blockIdx.y*64;
  int tid = threadIdx.x;
  int vv = tid>>2, wc = (tid&3)*16;
  bool vok = (v0+vv) < 500;
#pragma unroll
  for (int c=0;c<4;c++){
    f32x4 val = {0,0,0,0};
    int wg = w0 + wc + c*4;
    if (vok && wg < 500) val = *(const f32x4*)(sup + e*250000 + (size_t)(v0+vv)*500 + wg);
    *(f32x4*)&ts[vv][wc + c*4] = val;
    int2 pv; pv.x = pk2(val.x, val.y); pv.y = pk2(val.z, val.w);
    *(int2*)(SB + (size_t)e*(512*512) + (size_t)(v0+vv)*VS + wg) = pv;
  }
  __syncthreads();
  int w = tid>>2, vc = (tid&3)*16;
  unsigned short u[16];
#pragma unroll
  for (int j=0;j<16;j++) u[j] = f2bf(ts[vc+j][w]);
  int4 o0, o1;
  o0.x = u[0]|(u[1]<<16);  o0.y = u[2]|(u[3]<<16);
  o0.z = u[4]|(u[5]<<16);  o0.w = u[6]|(u[7]<<16);
  o1.x = u[8]|(u[9]<<16);  o1.y = u[10]|(u[11]<<16);
  o1.z = u[12]|(u[13]<<16); o1.w = u[14]|(u[15]<<16);
  short* op = ST + (size_t)e*(512*512) + (size_t)(w0+w)*VS + v0 + vc;
  *(int4*)(op) = o0;
  *(int4*)(op+8) = o1;
}

// ST2[e] = (S@S)^T stored [w][u]
__global__ __launch_bounds__(256) void k_ssq(const short* __restrict__ SB,
    const short* __restrict__ ST, short* __restrict__ ST2) {
  __shared__ __align__(16) short As[64*72];
  __shared__ __align__(16) short Bs[64*72];
  int e = blockIdx.z;
  int u0 = blockIdx.x*64, w0 = blockIdx.y*64;
  const short* Ab = SB + (size_t)e*(512*512);
  const short* Bb = ST + (size_t)e*(512*512);
  int tid = threadIdx.x;
  int row = tid>>2, col = (tid&3)*16;
  const short* ap = Ab + (size_t)(u0+row)*VS + col;
  const short* bp = Bb + (size_t)(w0+row)*VS + col;
  f32x4 ra0 = *(const f32x4*)(ap);
  f32x4 ra1 = *(const f32x4*)(ap+8);
  f32x4 rb0 = *(const f32x4*)(bp);
  f32x4 rb1 = *(const f32x4*)(bp+8);
  int wid = tid>>6, lane = tid&63;
  int wr = wid>>1, wc = wid&1;
  int lm = lane&15, lk = (lane>>4)*8;
  f32x4 acc[2][2] = {};
  short* aw = As + row*72 + col;
  short* bw = Bs + row*72 + col;
  for (int kk=0; kk<8; kk++) {
    __syncthreads();
    *(f32x4*)(aw) = ra0; *(f32x4*)(aw+8) = ra1;
    *(f32x4*)(bw) = rb0; *(f32x4*)(bw+8) = rb1;
    __syncthreads();
    if (kk < 7) {
      const short* ap2 = ap + (kk+1)*64;
      const short* bp2 = bp + (kk+1)*64;
      ra0 = *(const f32x4*)(ap2); ra1 = *(const f32x4*)(ap2+8);
      rb0 = *(const f32x4*)(bp2); rb1 = *(const f32x4*)(bp2+8);
    }
#pragma unroll
    for (int ks=0; ks<2; ks++) {
      bf16x8 af0 = *(const bf16x8*)(As + (wr*32 + lm)*72 + ks*32 + lk);
      bf16x8 af1 = *(const bf16x8*)(As + (wr*32 + 16 + lm)*72 + ks*32 + lk);
      bf16x8 bq0 = *(const bf16x8*)(Bs + (wc*32 + lm)*72 + ks*32 + lk);
      bf16x8 bq1 = *(const bf16x8*)(Bs + (wc*32 + 16 + lm)*72 + ks*32 + lk);
      acc[0][0] = __builtin_amdgcn_mfma_f32_16x16x32_bf16(af0, bq0, acc[0][0], 0,0,0);
      acc[0][1] = __builtin_amdgcn_mfma_f32_16x16x32_bf16(af0, bq1, acc[0][1], 0,0,0);
      acc[1][0] = __builtin_amdgcn_mfma_f32_16x16x32_bf16(af1, bq0, acc[1][0], 0,0,0);
      acc[1][1] = __builtin_amdgcn_mfma_f32_16x16x32_bf16(af1, bq1, acc[1][1], 0,0,0);
    }
  }
#pragma unroll
  for (int fm=0; fm<2; fm++) {
    int u4 = u0 + wr*32 + fm*16 + (lane>>4)*4;
#pragma unroll
    for (int fn=0; fn<2; fn++) {
      int w = w0 + wc*32 + fn*16 + lm;
      f32x4 v4 = acc[fm][fn];
      int2 pv; pv.x = pk2(v4.x, v4.y); pv.y = pk2(v4.z, v4.w);
      *(int2*)(ST2 + (size_t)e*(512*512) + (size_t)w*VS + u4) = pv;
    }
  }
}

// GT[b][q][v] bf16 from Gbf[b*NN+v][q] bf16
__global__ __launch_bounds__(256) void k_tposeGb(const short* __restrict__ Gbf,
    short* __restrict__ GT, int qmax) {
  __shared__ __align__(16) short ts[64][72];
  int b = blockIdx.z;
  int v0 = blockIdx.x*64, q0 = blockIdx.y*64;
  int tid = threadIdx.x;
  int vv = tid>>2, qc = (tid&3)*16;
  bool ok = ((v0+vv) < 500) && ((q0+qc) < qmax);
  int4 z4 = {0,0,0,0};
  int4 i0 = z4, i1 = z4;
  if (ok){
    const short* gp = Gbf + (size_t)(b*NN + v0+vv)*QS + q0 + qc;
    i0 = *(const int4*)(gp);
    i1 = *(const int4*)(gp+8);
  }
  *(int4*)&ts[vv][qc] = i0;
  *(int4*)&ts[vv][qc+8] = i1;
  __syncthreads();
  int q = tid>>2, vc = (tid&3)*16;
  if (q0 + q < qmax) {
    unsigned short u[16];
#pragma unroll
    for (int j=0;j<16;j++) u[j] = (unsigned short)ts[vc+j][q];
    int4 o0, o1;
    o0.x = u[0]|(u[1]<<16);  o0.y = u[2]|(u[3]<<16);
    o0.z = u[4]|(u[5]<<16);  o0.w = u[6]|(u[7]<<16);
    o1.x = u[8]|(u[9]<<16);  o1.y = u[10]|(u[11]<<16);
    o1.z = u[12]|(u[13]<<16); o1.w = u[14]|(u[15]<<16);
    short* op = GT + ((size_t)b*QS + q0+q)*VS + v0 + vc;
    *(int4*)(op) = o0;
    *(int4*)(op+8) = o1;
  }
}

// Merged MFMA diffusion, 128x128 tile: blockIdx.z = b*4 + sel; OUT bf16
__global__ __launch_bounds__(256) void k_hop2(const short* __restrict__ ST,
    const short* __restrict__ ST2, const short* __restrict__ GT,
    short* __restrict__ Dout, int qmax) {
  __shared__ __align__(16) short As[128*72];
  __shared__ __align__(16) short Bs[128*72];
  int sel = blockIdx.z & 3, b = blockIdx.z >> 2;
  int e = sel >> 1, hop = sel & 1;
  int w0 = blockIdx.x*128, q0 = blockIdx.y*128;
  const short* Ab = (hop ? ST2 : ST) + (size_t)e*(512*512) + (size_t)w0*VS;
  const short* Bb = GT + (size_t)b*(QS*VS) + (size_t)q0*VS;
  int tid = threadIdx.x;
  int row = tid>>2, col = (tid&3)*16;
  const short* ap0 = Ab + (size_t)row*VS + col;
  const short* ap1 = ap0 + (size_t)64*VS;
  const short* bp0 = Bb + (size_t)row*VS + col;
  const short* bp1 = bp0 + (size_t)64*VS;
  f32x4 a00=*(const f32x4*)ap0, a01=*(const f32x4*)(ap0+8);
  f32x4 a10=*(const f32x4*)ap1, a11=*(const f32x4*)(ap1+8);
  f32x4 b00=*(const f32x4*)bp0, b01=*(const f32x4*)(bp0+8);
  f32x4 b10=*(const f32x4*)bp1, b11=*(const f32x4*)(bp1+8);
  int wid = tid>>6, lane = tid&63;
  int wr = wid>>1, wc = wid&1;
  int lm = lane&15, lk = (lane>>4)*8;
  f32x4 acc[4][4] = {};
  short* aw0 = As + row*72 + col; short* aw1 = aw0 + 64*72;
  short* bw0 = Bs + row*72 + col; short* bw1 = bw0 + 64*72;
  for (int kk=0; kk<8; kk++) {
    __syncthreads();
    *(f32x4*)(aw0) = a00; *(f32x4*)(aw0+8) = a01;
    *(f32x4*)(aw1) = a10; *(f32x4*)(aw1+8) = a11;
    *(f32x4*)(bw0) = b00; *(f32x4*)(bw0+8) = b01;
    *(f32x4*)(bw1) = b10; *(f32x4*)(bw1+8) = b11;
    __syncthreads();
    if (kk < 7) {
      int o = (kk+1)*64;
      a00=*(const f32x4*)(ap0+o); a01=*(const f32x4*)(ap0+o+8);
      a10=*(const f32x4*)(ap1+o); a11=*(const f32x4*)(ap1+o+8);
      b00=*(const f32x4*)(bp0+o); b01=*(const f32x4*)(bp0+o+8);
      b10=*(const f32x4*)(bp1+o); b11=*(const f32x4*)(bp1+o+8);
    }
#pragma unroll
    for (int ks=0; ks<2; ks++) {
      bf16x8 af[4], bq[4];
#pragma unroll
      for (int fm=0;fm<4;fm++) af[fm] = *(const bf16x8*)(As + (wr*64+fm*16+lm)*72 + ks*32 + lk);
#pragma unroll
      for (int fn=0;fn<4;fn++) bq[fn] = *(const bf16x8*)(Bs + (wc*64+fn*16+lm)*72 + ks*32 + lk);
#pragma unroll
      for (int fm=0;fm<4;fm++)
#pragma unroll
        for (int fn=0;fn<4;fn++)
          acc[fm][fn] = __builtin_amdgcn_mfma_f32_16x16x32_bf16(af[fm], bq[fn], acc[fm][fn], 0,0,0);
    }
  }
  short* Ob = Dout + (size_t)sel*DSZ + (size_t)b*(NN*QS);
#pragma unroll
  for (int fm=0; fm<4; fm++) {
    int wb4 = w0 + wr*64 + fm*16 + (lane>>4)*4;
    if (wb4 >= 500) continue;
#pragma unroll
    for (int fn=0; fn<4; fn++) {
      int q = q0 + wc*64 + fn*16 + lm;
      if (q < qmax) {
        f32x4 v4 = acc[fm][fn];
        short* op = Ob + (size_t)wb4*QS + q;
        op[0*QS] = (short)f2bf(v4.x);
        op[1*QS] = (short)f2bf(v4.y);
        op[2*QS] = (short)f2bf(v4.z);
        op[3*QS] = (short)f2bf(v4.w);
      }
    }
  }
}

// ================= input projection / enter conv =================

__global__ void k_proj(const float* __restrict__ inputs, const float* __restrict__ factor,
                       float* __restrict__ proj) {
  int bt = blockIdx.x;
  __shared__ float xin[NN*2];
  for (int idx=threadIdx.x; idx<NN*2; idx+=64) xin[idx] = inputs[bt*NN*2 + idx];
  __syncthreads();
  int u = threadIdx.x>>1, f = threadIdx.x&1;
  float acc=0.f;
  for (int n=0;n<NN;n++) acc += xin[n*2+f]*factor[n*UU+u];
  proj[bt*64 + u*2+f] = acc;
}

__global__ __launch_bounds__(256) void k_enter(const float* __restrict__ inputs,
    const float* __restrict__ factor, const float* __restrict__ proj,
    const float* __restrict__ ew, const float* __restrict__ eb, float* __restrict__ X) {
  int idx = blockIdx.x*256+threadIdx.x;
  if (idx >= BB*NN*TX) return;
  int t = idx % TX; int n = (idx/TX)%NN; int b = idx/(TX*NN);
  float x4[4]={0.f,0.f,0.f,0.f};
  if (t>0) {
    int tt=t-1;
    float s0=0.f,s1=0.f;
    const float* pr = proj + (b*TT+tt)*64;
    const float* fr = factor + n*UU;
#pragma unroll
    for(int u=0;u<UU;u++){ s0 += pr[u*2]*fr[u]; s1 += pr[u*2+1]*fr[u]; }
    float i0 = inputs[((b*TT+tt)*NN+n)*2];
    float i1 = inputs[((b*TT+tt)*NN+n)*2+1];
    x4[0]=s0; x4[1]=s1; x4[2]=i0-s0; x4[3]=i1-s1;
  }
  float* xp = X + ((size_t)(b*NN+n)*TX + t)*CC;
#pragma unroll
  for(int o=0;o<CC;o++){
    xp[o] = eb[o] + ew[o*4]*x4[0] + ew[o*4+1]*x4[1] + ew[o*4+2]*x4[2] + ew[o*4+3]*x4[3];
  }
}

// ================= MFMA gated temporal conv =================

__global__ __launch_bounds__(256) void k_gated3(const float* __restrict__ X,
    short* __restrict__ Gbf, short* __restrict__ Glb,
    const float* __restrict__ fw, const float* __restrict__ fb,
    const float* __restrict__ gw, const float* __restrict__ gb,
    const float* __restrict__ stat, int use_stat, int d, int t_out, int lidx) {
  __shared__ __align__(16) short As[64*72];
  __shared__ __align__(16) short Wb[64*72];
  __shared__ float scs[32], shs[32];
  int tid = threadIdx.x;
  if (tid < 32) {
    scs[tid] = use_stat ? stat[tid] : 1.0f;
    shs[tid] = use_stat ? stat[32 + tid] : 0.0f;
  }
  for (int i = tid; i < 2048; i += 256) {
    int o = i >> 6, k = i & 63;
    Wb[o*72 + k]      = (short)f2bf(fw[i]);
    Wb[(32+o)*72 + k] = (short)f2bf(gw[i]);
  }
  __syncthreads();
  int m0 = blockIdx.x * 64;
  {
    int mm = tid & 63;
    int kb = (tid >> 6) * 16;
    int c0 = kb >> 1;
    int m = m0 + mm;
    int bn = m / t_out, t = m - bn * t_out;
    const float* xr = X + (size_t)bn * (TX * CC);
    float4 a0 = *(const float4*)(xr + t * 32 + c0);
    float4 a1 = *(const float4*)(xr + t * 32 + c0 + 4);
    float4 b0 = *(const float4*)(xr + (t + d) * 32 + c0);
    float4 b1 = *(const float4*)(xr + (t + d) * 32 + c0 + 4);
    float va[8] = {a0.x,a0.y,a0.z,a0.w,a1.x,a1.y,a1.z,a1.w};
    float vb[8] = {b0.x,b0.y,b0.z,b0.w,b1.x,b1.y,b1.z,b1.w};
    int iv[8];
#pragma unroll
    for (int j = 0; j < 8; j++) {
      float sc = scs[c0+j], sh = shs[c0+j];
      iv[j] = pk2(va[j]*sc + sh, vb[j]*sc + sh);
    }
    int4 w0 = {iv[0],iv[1],iv[2],iv[3]};
    int4 w1 = {iv[4],iv[5],iv[6],iv[7]};
    *(int4*)(As + mm*72 + kb) = w0;
    *(int4*)(As + mm*72 + kb + 8) = w1;
  }
  __syncthreads();
  int wid = tid>>6, lane = tid&63;
  int lm = lane&15, g = lane>>4, lk8 = g*8;
  f32x4 acc[4] = {};
#pragma unroll
  for (int kk=0; kk<2; kk++){
    bf16x8 af = *(const bf16x8*)(As + (wid*16+lm)*72 + kk*32 + lk8);
#pragma unroll
    for (int fn=0; fn<4; fn++){
      bf16x8 bq = *(const bf16x8*)(Wb + (fn*16+lm)*72 + kk*32 + lk8);
      acc[fn] = __builtin_amdgcn_mfma_f32_16x16x32_bf16(af, bq, acc[fn], 0,0,0);
    }
  }
#pragma unroll
  for (int fn=0; fn<2; fn++){
    int o = fn*16 + lm;
    float fbv = fb[o], gbv = gb[o];
#pragma unroll
    for (int r=0; r<4; r++){
      int m = m0 + wid*16 + g*4 + r;
      int bn = m / t_out, t = m - bn*t_out;
      float f = acc[fn][r] + fbv;
      float gg = acc[fn+2][r] + gbv;
      float th = 2.f/(1.f+__expf(-2.f*f)) - 1.f;
      float sg = 1.f/(1.f+__expf(-gg));
      unsigned short ov = f2bf(th*sg);
      Gbf[(size_t)bn*QS + t*32 + o] = (short)ov;
      if (t == t_out-1) Glb[(size_t)bn*256 + lidx*32 + o] = (short)ov;
    }
  }
}

// ======= MFMA graph-conv 1x1 + residual + BN partials (256 thr, 4 waves) =======

template<int TOUT>
__global__ __launch_bounds__(256) void k_gc3(const short* __restrict__ Gbf,
    const short* __restrict__ Dbf, const float* __restrict__ Xc, float* __restrict__ Xn,
    const float* __restrict__ gcw, const float* __restrict__ gcb,
    const float* __restrict__ stat, int use_stat, float* __restrict__ part, int d) {
  int tid = threadIdx.x;
  int wid = tid>>6, lane = tid&63;
  int lm = lane&15, g = lane>>4, lk8 = g*8;
  int m0 = blockIdx.x*256 + wid*64;
  const int M = 16000*TOUT;
  float* pp = part + ((size_t)blockIdx.x*4 + wid)*64;
  if (m0 >= M){
    if (lane < 16){ pp[lane]=0.f; pp[16+lane]=0.f; pp[32+lane]=0.f; pp[48+lane]=0.f; }
    return;
  }
  bf16x8 wf[5][2];
#pragma unroll
  for (int ks=0;ks<5;ks++)
#pragma unroll
    for (int nh=0;nh<2;nh++){
      const float* wp = gcw + (nh*16+lm)*160 + ks*32 + lk8;
      wf[ks][nh] = pack8(*(const f32x4*)wp, *(const f32x4*)(wp+4));
    }
  float scn0 = use_stat ? stat[lm]    : 1.f;
  float scn1 = use_stat ? stat[16+lm] : 1.f;
  float shn0 = use_stat ? stat[32+lm] : 0.f;
  float shn1 = use_stat ? stat[48+lm] : 0.f;
  float gb0 = gcb[lm], gb1 = gcb[16+lm];
  float ss0=0.f, sq0=0.f, ss1=0.f, sq1=0.f;
#pragma unroll
  for (int mg=0; mg<4; mg++){
    int m = m0 + mg*16 + lm;
    int bn = m / TOUT; int t = m - bn*TOUT;
    size_t off = (size_t)bn*(TG*CC) + t*32 + lk8;
    f32x4 acc0={0,0,0,0}, acc1={0,0,0,0};
    {
      bf16x8 af = *(const bf16x8*)(Gbf + off);
      acc0 = __builtin_amdgcn_mfma_f32_16x16x32_bf16(af, wf[0][0], acc0, 0,0,0);
      acc1 = __builtin_amdgcn_mfma_f32_16x16x32_bf16(af, wf[0][1], acc1, 0,0,0);
    }
#pragma unroll
    for (int ks=1;ks<5;ks++){
      bf16x8 af = *(const bf16x8*)(Dbf + (size_t)(ks-1)*DSZ + off);
      acc0 = __builtin_amdgcn_mfma_f32_16x16x32_bf16(af, wf[ks][0], acc0, 0,0,0);
      acc1 = __builtin_amdgcn_mfma_f32_16x16x32_bf16(af, wf[ks][1], acc1, 0,0,0);
    }
#pragma unroll
    for (int r=0;r<4;r++){
      int mr = m0 + mg*16 + g*4 + r;
      int bnr = mr / TOUT; int tr = mr - bnr*TOUT;
      size_t xoff = (size_t)bnr*(TX*CC);
      float r0 = Xc[xoff + (tr+d)*32 + lm];
      float r1 = Xc[xoff + (tr+d)*32 + 16 + lm];
      float v0 = acc0[r] + gb0 + r0*scn0 + shn0;
      float v1 = acc1[r] + gb1 + r1*scn1 + shn1;
      Xn[xoff + tr*32 + lm] = v0;
      Xn[xoff + tr*32 + 16 + lm] = v1;
      ss0+=v0; sq0+=v0*v0; ss1+=v1; sq1+=v1*v1;
    }
  }
#pragma unroll
  for (int off=16; off<64; off<<=1){
    ss0+=__shfl_xor(ss0,off); sq0+=__shfl_xor(sq0,off);
    ss1+=__shfl_xor(ss1,off); sq1+=__shfl_xor(sq1,off);
  }
  if (lane<16){
    pp[lane]=ss0; pp[16+lane]=ss1; pp[32+lane]=sq0; pp[48+lane]=sq1;
  }
}

// 2-stage BN-stat reduction
__global__ __launch_bounds__(64) void k_stat2a(const float* __restrict__ part, int nblk,
    float* __restrict__ part2) {
  int t = threadIdx.x;
  float s = 0.f;
  for (int i = blockIdx.x; i < nblk; i += 64) s += part[(size_t)i*64 + t];
  part2[blockIdx.x*64 + t] = s;
}

__global__ __launch_bounds__(64) void k_stat2b(const float* __restrict__ part2,
    const float* __restrict__ g, const float* __restrict__ b,
    float* __restrict__ statout, float cntinv) {
  int t = threadIdx.x;
  float s = 0.f;
#pragma unroll 8
  for (int i = 0; i < 64; i++) s += part2[i*64 + t];
  __shared__ float red[64];
  red[t] = s;
  __syncthreads();
  if (t < 32){
    float sum = red[t], sq = red[32+t];
    float m = sum*cntinv, var = sq*cntinv - m*m;
    float sc = rsqrtf(var + BN_EPS)*g[t];
    statout[t] = sc;
    statout[32+t] = b[t] - m*sc;
  }
}

// ================= output head =================

__global__ void k_wstack2(const float* __restrict__ skp_w, const float* __restrict__ skp_b,
                          const float* __restrict__ o1w,
                          short* __restrict__ Wstb, short* __restrict__ o1wb,
                          float* __restrict__ bsum) {
  int bid = blockIdx.x;
  int idx = bid*256 + threadIdx.x;
  if (bid < 256){
    int kk = idx >> 8, o = idx & 255;
    Wstb[o*256 + kk] = (short)f2bf(skp_w[(kk>>5)*8192 + o*32 + (kk&31)]);
    if (idx < 256){
      float s=0.f;
      for (int l=0;l<8;l++) s += skp_b[l*256+idx];
      bsum[idx]=s;
    }
  } else {
    int j = idx - 65536;
    o1wb[j] = (short)f2bf(o1w[j]);
  }
}

// C[m][n] = relu(sum_k A[m][k]*B[n][k] + bias[n]) -> bf16 out
__global__ __launch_bounds__(256) void k_mm(const short* __restrict__ A,
    const short* __restrict__ B, const float* __restrict__ bias,
    short* __restrict__ out, int ldout, int K) {
  __shared__ __align__(16) short As[64*72];
  __shared__ __align__(16) short Bs[64*72];
  int m0 = blockIdx.x*64, n0 = blockIdx.y*64;
  int tid = threadIdx.x;
  int row = tid>>2, col = (tid&3)*16;
  const short* ap = A + (size_t)(m0+row)*K + col;
  const short* bp = B + (size_t)(n0+row)*K + col;
  f32x4 ra0 = *(const f32x4*)(ap);
  f32x4 ra1 = *(const f32x4*)(ap+8);
  f32x4 rb0 = *(const f32x4*)(bp);
  f32x4 rb1 = *(const f32x4*)(bp+8);
  int wid = tid>>6, lane = tid&63;
  int wr = wid>>1, wc = wid&1;
  int lm = lane&15, lk = (lane>>4)*8;
  f32x4 acc[2][2] = {};
  short* aw = As + row*72 + col;
  short* bw = Bs + row*72 + col;
  int nk = K>>6;
  for (int kk=0; kk<nk; kk++) {
    __syncthreads();
    *(f32x4*)(aw) = ra0; *(f32x4*)(aw+8) = ra1;
    *(f32x4*)(bw) = rb0; *(f32x4*)(bw+8) = rb1;
    __syncthreads();
    if (kk < nk-1) {
      const short* ap2 = ap + (kk+1)*64;
      const short* bp2 = bp + (kk+1)*64;
      ra0 = *(const f32x4*)(ap2); ra1 = *(const f32x4*)(ap2+8);
      rb0 = *(const f32x4*)(bp2); rb1 = *(const f32x4*)(bp2+8);
    }
#pragma unroll
    for (int ks=0; ks<2; ks++) {
      bf16x8 af0 = *(const bf16x8*)(As + (wr*32 + lm)*72 + ks*32 + lk);
      bf16x8 af1 = *(const bf16x8*)(As + (wr*32 + 16 + lm)*72 + ks*32 + lk);
      bf16x8 bq0 = *(const bf16x8*)(Bs + (wc*32 + lm)*72 + ks*32 + lk);
      bf16x8 bq1 = *(const bf16x8*)(Bs + (wc*32 + 16 + lm)*72 + ks*32 + lk);
      acc[0][0] = __builtin_amdgcn_mfma_f32_16x16x32_bf16(af0, bq0, acc[0][0], 0,0,0);
      acc[0][1] = __builtin_amdgcn_mfma_f32_16x16x32_bf16(af0, bq1, acc[0][1], 0,0,0);
      acc[1][0] = __builtin_amdgcn_mfma_f32_16x16x32_bf16(af1, bq0, acc[1][0], 0,0,0);
      acc[1][1] = __builtin_amdgcn_mfma_f32_16x16x32_bf16(af1, bq1, acc[1][1], 0,0,0);
    }
  }
#pragma unroll
  for (int fm=0; fm<2; fm++) {
    int mb = m0 + wr*32 + fm*16 + (lane>>4)*4;
#pragma unroll
    for (int fn=0; fn<2; fn++) {
      int n = n0 + wc*32 + fn*16 + lm;
      float bv = bias[n];
      f32x4 v4 = acc[fm][fn];
#pragma unroll
      for (int r=0;r<4;r++)
        out[(size_t)(mb+r)*ldout + n] = (short)f2bf(fmaxf(v4[r]+bv, 0.f));
    }
  }
}

__global__ __launch_bounds__(256) void k_head2c(const short* __restrict__ Y1b,
    const float* __restrict__ o2w, const float* __restrict__ o2b, float* __restrict__ y) {
  int tid = threadIdx.x;
  int ml = tid>>2, kc = tid&3;
  int m = blockIdx.x*64 + ml;
  float accs[NPREDC] = {};
  for (int e=kc*128; e<kc*128+128; e+=8){
    bf16x8 yv = *(const bf16x8*)(Y1b + (size_t)m*NENDC + e);
    float yf[8];
#pragma unroll
    for (int j=0;j<8;j++) yf[j] = bf2f(yv[j]);
#pragma unroll
    for (int p=0;p<NPREDC;p++){
      const float* wp = o2w + p*NENDC + e;
      float a = 0.f;
#pragma unroll
      for (int j=0;j<8;j++) a += wp[j]*yf[j];
      accs[p] += a;
    }
  }
#pragma unroll
  for (int off=1; off<4; off<<=1)
#pragma unroll
    for (int p=0;p<NPREDC;p++) accs[p] += __shfl_xor(accs[p], off);
  if (kc==0){
    int b=m/NN, n=m%NN;
#pragma unroll
    for (int p=0;p<NPREDC;p++) y[(b*NPREDC+p)*NN+n] = accs[p] + o2b[p];
  }
}

// ================= host =================

extern "C" void kernel_launch(void* const* d_in, const int* in_sizes, int n_in,
                              void* d_out, int out_size, void* d_ws, size_t ws_size,
                              hipStream_t stream) {
  const float* inputs  = (const float*)d_in[0];
  const float* factor  = (const float*)d_in[1];
  const float* map_w   = (const float*)d_in[2];
  const float* map_b   = (const float*)d_in[3];
  const float* a1w     = (const float*)d_in[4];
  const float* a1b     = (const float*)d_in[5];
  const float* a2w     = (const float*)d_in[6];
  const float* a2b     = (const float*)d_in[7];
  const float* a3w     = (const float*)d_in[8];
  const float* a3b     = (const float*)d_in[9];
  const float* enter_w = (const float*)d_in[10];
  const float* enter_b = (const float*)d_in[11];
  const float* filt_w  = (const float*)d_in[12];
  const float* filt_b  = (const float*)d_in[13];
  const float* gate_w  = (const float*)d_in[14];
  const float* gate_b  = (const float*)d_in[15];
  const float* skp_w   = (const float*)d_in[16];
  const float* skp_b   = (const float*)d_in[17];
  const float* gc_w    = (const float*)d_in[18];
  const float* gc_b    = (const float*)d_in[19];
  const float* bn_g    = (const float*)d_in[20];
  const float* bn_b    = (const float*)d_in[21];
  const float* o1w     = (const float*)d_in[22];
  const float* o1b     = (const float*)d_in[23];
  const float* o2w     = (const float*)d_in[24];
  const float* o2b     = (const float*)d_in[25];
  (void)in_sizes; (void)n_in; (void)out_size; (void)ws_size;

  float* ws = (float*)d_ws;
  float* v      = ws + OFF_V;
  float* adj    = ws + OFF_ADJ;
  float* part2  = ws + OFF_ADJ;      // reuse (adj dead after k_tposeS)
  float* asrc   = ws + OFF_ASRC;
  float* adst   = ws + OFF_ADST;
  float* proj   = ws + OFF_PROJ;
  float* statb  = ws + OFF_STAT;
  float* part   = ws + OFF_PART;
  float* bsum   = ws + OFF_BSUM;
  float* X      = ws + OFF_X;
  float* Xn     = ws + OFF_XN;
  short* Dbf    = (short*)(ws + OFF_D);
  short* Gbf    = (short*)(ws + OFF_GBF);
  short* Glb    = (short*)(ws + OFF_GLB);
  short* GT     = (short*)(ws + OFF_GT);
  short* ST     = (short*)(ws + OFF_ST);
  short* SB     = (short*)(ws + OFF_SB);
  short* ST2    = (short*)(ws + OFF_ST2);
  short* Wstb   = (short*)(ws + OFF_WSTB);
  short* o1wb   = (short*)(ws + OFF_O1WB);
  short* skvb   = (short*)(ws + OFF_SKV);
  short* Y1b    = (short*)(ws + OFF_Y1B);

  float* y_out   = (float*)d_out;
  float* sup_out = y_out + BB*NPREDC*NN;

  // adaptive supports
  k_v<<<NN, 32, 0, stream>>>(factor, map_w, map_b, v);
  k_asrc2<<<NN, 64, 0, stream>>>(v, a1w, a1b, asrc, adst);
  {
    dim3 gp(NN, 2);
    k_pair3<<<gp, 256, 0, stream>>>(asrc, adst, a2w, a2b, a3w, a3b, adj);
  }
  k_softmax<<<2*NN, 256, 0, stream>>>(adj, sup_out);
  {
    dim3 gt(8, 8, 2);
    k_tposeS<<<gt, 256, 0, stream>>>(sup_out, ST, SB);
    k_ssq<<<gt, 256, 0, stream>>>(SB, ST, ST2);
  }

  // input split + enter
  k_proj<<<BB*TT, 64, 0, stream>>>(inputs, factor, proj);
  k_enter<<<(BB*NN*TX+255)/256, 256, 0, stream>>>(inputs, factor, proj, enter_w, enter_b, X);

  // head weight prep (independent)
  k_wstack2<<<768, 256, 0, stream>>>(skp_w, skp_b, o1w, Wstb, o1wb, bsum);

  float* Xc = X; float* Xo = Xn;
  int t = TX;
  static const int dil[8]={1,2,1,2,1,2,1,2};
  for (int l=0;l<7;l++){
    int d=dil[l], t_out=t-d;
    const float* st = statb + (l>0 ? (l-1)*64 : 0);
    k_gated3<<<250*t_out,256,0,stream>>>(Xc, Gbf, Glb, filt_w + l*2048, filt_b + l*32,
                                         gate_w + l*2048, gate_b + l*32, st, l>0, d, t_out, l);
    int qmax = t_out*CC;
    int qt64 = (qmax+63)/64;
    dim3 gtp(8, qt64, 32);
    k_tposeGb<<<gtp,256,0,stream>>>(Gbf, GT, qmax);
    int qt128 = (qmax+127)/128;
    dim3 ghp(4, qt128, 128);
    k_hop2<<<ghp,256,0,stream>>>(ST, ST2, GT, Dbf, qmax);
    int nb = (16000*t_out + 255)/256;
    const float* gcwl = gc_w + l*5120;
    const float* gcbl = gc_b + l*32;
    switch (t_out){
      case 12: k_gc3<12><<<nb,256,0,stream>>>(Gbf,Dbf,Xc,Xo,gcwl,gcbl,st,l>0,part,d); break;
      case 10: k_gc3<10><<<nb,256,0,stream>>>(Gbf,Dbf,Xc,Xo,gcwl,gcbl,st,l>0,part,d); break;
      case  9: k_gc3< 9><<<nb,256,0,stream>>>(Gbf,Dbf,Xc,Xo,gcwl,gcbl,st,l>0,part,d); break;
      case  7: k_gc3< 7><<<nb,256,0,stream>>>(Gbf,Dbf,Xc,Xo,gcwl,gcbl,st,l>0,part,d); break;
      case  6: k_gc3< 6><<<nb,256,0,stream>>>(Gbf,Dbf,Xc,Xo,gcwl,gcbl,st,l>0,part,d); break;
      case  4: k_gc3< 4><<<nb,256,0,stream>>>(Gbf,Dbf,Xc,Xo,gcwl,gcbl,st,l>0,part,d); break;
      default: k_gc3< 3><<<nb,256,0,stream>>>(Gbf,Dbf,Xc,Xo,gcwl,gcbl,st,l>0,part,d); break;
    }
    k_stat2a<<<64,64,0,stream>>>(part, nb*4, part2);
    k_stat2b<<<1,64,0,stream>>>(part2, bn_g + l*32, bn_b + l*32,
                                statb + l*64, 1.f/(16000.f*(float)t_out));
    float* tmp=Xc; Xc=Xo; Xo=tmp;
    t = t_out;
  }
  // layer 8: only gated conv feeds skip
  k_gated3<<<250*1,256,0,stream>>>(Xc, Gbf, Glb, filt_w + 7*2048, filt_b + 7*32,
                                   gate_w + 7*2048, gate_b + 7*32, statb + 6*64, 1, 2, 1, 7);

  // head: skip GEMM -> head1 -> head2
  {
    dim3 gs(BNN/64, NSKIPC/64);
    k_mm<<<gs,256,0,stream>>>(Glb, Wstb, bsum, skvb, NSKIPC, 256);
    dim3 gh(BNN/64, NENDC/64);
    k_mm<<<gh,256,0,stream>>>(skvb, o1wb, o1b, Y1b, NENDC, 256);
    k_head2c<<<BNN/64,256,0,stream>>>(Y1b, o2w, o2b, y_out);
  }
}

// Round 9
// 728.660 us; speedup vs baseline: 11.3611x; 1.0587x over previous
//
#include <hip/hip_runtime.h>
#include <math.h>

// ---- static config ----
#define BB 32
#define TT 12
#define NN 500
#define UU 32
#define CC 32
#define NSKIPC 256
#define NENDC 512
#define NPREDC 12
#define TX 13
#define TG 12
#define QS 384
#define VS 512
#define BNN (BB*NN)
#define DSZ (BNN*TG*CC)
#define BN_EPS 1e-5f

// ---- workspace offsets (floats) ----
#define OFF_V      0u
#define OFF_ADJ    16000u        // adj 500000; tail reused as part2 (4096) after supports
#define OFF_ASRC   516000u
#define OFF_ADST   548000u
#define OFF_PROJ   580000u
#define OFF_STAT   582048u
#define OFF_PART   582560u       // 3000*64 = 192000
#define OFF_BSUM   774560u
#define OFF_X      774816u
#define OFF_XN     7430816u
#define OFF_D      14086816u     // shorts 4*6144000 = 24576000 (12288000 floats)
#define OFF_GBF    38662816u     // shorts 6144000 (G bf16 [16000][384])
#define OFF_GLB    41734816u     // shorts 4096000 (Glast bf16 [16000][256])
#define OFF_GT     43782816u     // shorts 6291456
#define OFF_ST     46928544u     // shorts 524288
#define OFF_SB     47190688u
#define OFF_ST2    47452832u
#define OFF_WSTB   47714976u     // shorts 65536
#define OFF_O1WB   47747744u     // shorts 131072
#define OFF_SKV    47813280u     // shorts 4096000 (skipv bf16)
#define OFF_Y1B    49861280u     // shorts 8192000 (Y1 bf16) -> ends 53957280

typedef __attribute__((ext_vector_type(8))) short bf16x8;
typedef __attribute__((ext_vector_type(4))) float f32x4;

__device__ inline unsigned short f2bf(float f) {
  union { float f; unsigned u; } x; x.f = f;
  unsigned r = x.u + 0x7FFFu + ((x.u >> 16) & 1u);
  return (unsigned short)(r >> 16);
}
__device__ inline float bf2f(short s) {
  union { float f; unsigned u; } x;
  x.u = ((unsigned)(unsigned short)s) << 16;
  return x.f;
}
__device__ inline int pk2(float a, float b) {
  return (int)((unsigned)f2bf(a) | ((unsigned)f2bf(b) << 16));
}
__device__ inline bf16x8 pack8(f32x4 a, f32x4 b) {
  union { int i[4]; bf16x8 v; } u;
  u.i[0]=pk2(a.x,a.y); u.i[1]=pk2(a.z,a.w);
  u.i[2]=pk2(b.x,b.y); u.i[3]=pk2(b.z,b.w);
  return u.v;
}
__device__ inline f32x4 reluadd(f32x4 a, f32x4 b) {
  f32x4 r;
  r.x=fmaxf(a.x+b.x,0.f); r.y=fmaxf(a.y+b.y,0.f);
  r.z=fmaxf(a.z+b.z,0.f); r.w=fmaxf(a.w+b.w,0.f);
  return r;
}

// ================= adaptive supports =================

__global__ void k_v(const float* __restrict__ factor, const float* __restrict__ map_w,
                    const float* __restrict__ map_b, float* __restrict__ v) {
  int n = blockIdx.x; int d = threadIdx.x;
  __shared__ float fr[UU];
  fr[d] = factor[n*UU + d];
  __syncthreads();
  float acc = map_b[d];
#pragma unroll
  for (int u=0;u<UU;u++) acc += fr[u]*map_w[u*32+d];
  v[n*32+d] = fmaxf(acc, 0.f);
}

__global__ void k_asrc2(const float* __restrict__ v, const float* __restrict__ a1w,
                        const float* __restrict__ a1b,
                        float* __restrict__ asrc, float* __restrict__ adst) {
  int n = blockIdx.x; int o = threadIdx.x; // 64 threads
  __shared__ float vn[32];
  if (o < 32) vn[o] = v[n*32+o];
  __syncthreads();
  float s = 0.f, dst = a1b[o];
#pragma unroll
  for (int u=0;u<32;u++){ s += vn[u]*a1w[u*64+o]; dst += vn[u]*a1w[(32+u)*64+o]; }
  asrc[n*64+o] = s;
  adst[n*64+o] = dst;
}

__global__ __launch_bounds__(256) void k_pair3(const float* __restrict__ asrc,
    const float* __restrict__ adst, const float* __restrict__ a2w,
    const float* __restrict__ a2b, const float* __restrict__ a3w,
    const float* __restrict__ a3b, float* __restrict__ adj) {
  int i = blockIdx.x;
  int tid = threadIdx.x;
  int wid = tid>>6, lane = tid&63;
  int lm = lane&15, g = lane>>4, lk8 = g*8;
  int jb = blockIdx.y*256 + wid*64;
  bf16x8 wf[2][2];
#pragma unroll
  for (int ks=0;ks<2;ks++)
#pragma unroll
    for (int nh=0;nh<2;nh++){
      int n = nh*16+lm;
      f32x4 lo, hi;
      lo.x=a2w[(ks*32+lk8+0)*32+n]; lo.y=a2w[(ks*32+lk8+1)*32+n];
      lo.z=a2w[(ks*32+lk8+2)*32+n]; lo.w=a2w[(ks*32+lk8+3)*32+n];
      hi.x=a2w[(ks*32+lk8+4)*32+n]; hi.y=a2w[(ks*32+lk8+5)*32+n];
      hi.z=a2w[(ks*32+lk8+6)*32+n]; hi.w=a2w[(ks*32+lk8+7)*32+n];
      wf[ks][nh] = pack8(lo, hi);
    }
  float b20 = a2b[lm], b21 = a2b[16+lm];
  float w3e0n0 = a3w[lm*2],      w3e1n0 = a3w[lm*2+1];
  float w3e0n1 = a3w[(16+lm)*2], w3e1n1 = a3w[(16+lm)*2+1];
  float b30 = a3b[0], b31 = a3b[1];
  const float* dp = adst + i*64;
  f32x4 d00 = *(const f32x4*)(dp + lk8);
  f32x4 d01 = *(const f32x4*)(dp + lk8 + 4);
  f32x4 d10 = *(const f32x4*)(dp + 32 + lk8);
  f32x4 d11 = *(const f32x4*)(dp + 32 + lk8 + 4);
#pragma unroll
  for (int mg=0; mg<4; mg++){
    int j = jb + mg*16 + lm;
    int jc = j < 500 ? j : 0;
    const float* ap = asrc + jc*64;
    f32x4 s00=*(const f32x4*)(ap+lk8),    s01=*(const f32x4*)(ap+lk8+4);
    f32x4 s10=*(const f32x4*)(ap+32+lk8), s11=*(const f32x4*)(ap+32+lk8+4);
    bf16x8 a0 = pack8(reluadd(s00,d00), reluadd(s01,d01));
    bf16x8 a1 = pack8(reluadd(s10,d10), reluadd(s11,d11));
    f32x4 acc0 = {b20,b20,b20,b20};
    f32x4 acc1 = {b21,b21,b21,b21};
    acc0 = __builtin_amdgcn_mfma_f32_16x16x32_bf16(a0, wf[0][0], acc0, 0,0,0);
    acc0 = __builtin_amdgcn_mfma_f32_16x16x32_bf16(a1, wf[1][0], acc0, 0,0,0);
    acc1 = __builtin_amdgcn_mfma_f32_16x16x32_bf16(a0, wf[0][1], acc1, 0,0,0);
    acc1 = __builtin_amdgcn_mfma_f32_16x16x32_bf16(a1, wf[1][1], acc1, 0,0,0);
    float e0[4], e1[4];
#pragma unroll
    for (int r=0;r<4;r++){
      float h2a = fmaxf(acc0[r],0.f), h2b = fmaxf(acc1[r],0.f);
      e0[r] = h2a*w3e0n0 + h2b*w3e0n1;
      e1[r] = h2a*w3e1n0 + h2b*w3e1n1;
    }
#pragma unroll
    for (int off=1; off<16; off<<=1){
#pragma unroll
      for (int r=0;r<4;r++){ e0[r]+=__shfl_xor(e0[r],off); e1[r]+=__shfl_xor(e1[r],off); }
    }
    if (lm==0){
      int j4 = jb + mg*16 + g*4;
      if (j4 < 500){
        f32x4 v0={e0[0]+b30,e0[1]+b30,e0[2]+b30,e0[3]+b30};
        f32x4 v1={e1[0]+b31,e1[1]+b31,e1[2]+b31,e1[3]+b31};
        *(f32x4*)(adj + i*500 + j4) = v0;
        *(f32x4*)(adj + 250000 + i*500 + j4) = v1;
      }
    }
  }
}

__global__ __launch_bounds__(256) void k_softmax(const float* __restrict__ adj,
    float* __restrict__ sup_out) {
  int row = blockIdx.x;
  int e = row/NN, i = row%NN;
  const float* a = adj + e*250000 + i*NN;
  __shared__ float red[64];
  float m = -1e30f;
  for (int j=threadIdx.x;j<NN;j+=256) m = fmaxf(m, a[j]);
#pragma unroll
  for (int off=32; off; off>>=1) m = fmaxf(m, __shfl_down(m, off));
  int lane = threadIdx.x & 63, wid = threadIdx.x >> 6;
  if (lane==0) red[wid]=m;
  __syncthreads();
  if (threadIdx.x==0){ float mm=red[0]; for(int w=1;w<4;w++) mm=fmaxf(mm,red[w]); red[32]=mm; }
  __syncthreads();
  m = red[32];
  float s=0.f;
  for (int j=threadIdx.x;j<NN;j+=256) s += __expf(a[j]-m);
#pragma unroll
  for (int off=32; off; off>>=1) s += __shfl_down(s, off);
  if (lane==0) red[wid]=s;
  __syncthreads();
  if (threadIdx.x==0){ float ss=0; for(int w=0;w<4;w++) ss+=red[w]; red[33]=ss; }
  __syncthreads();
  float inv = 1.f/red[33];
  for (int j=threadIdx.x;j<NN;j+=256) {
    float val = __expf(a[j]-m)*inv;
    if (j==i) val = 1.f;
    sup_out[e*250000 + i*NN + j] = val;
  }
}

// ST[e][w][v] transposed bf16 + SB[e][v][w] cast bf16 (both 512x512 zero-padded)
__global__ __launch_bounds__(256) void k_tposeS(const float* __restrict__ sup,
    short* __restrict__ ST, short* __restrict__ SB) {
  __shared__ float ts[64][68];
  int e = blockIdx.z;
  int v0 = blockIdx.x*64, w0 = blockIdx.y*64;
  int tid = threadIdx.x;
  int vv = tid>>2, wc = (tid&3)*16;
  bool vok = (v0+vv) < 500;
#pragma unroll
  for (int c=0;c<4;c++){
    f32x4 val = {0,0,0,0};
    int wg = w0 + wc + c*4;
    if (vok && wg < 500) val = *(const f32x4*)(sup + e*250000 + (size_t)(v0+vv)*500 + wg);
    *(f32x4*)&ts[vv][wc + c*4] = val;
    int2 pv; pv.x = pk2(val.x, val.y); pv.y = pk2(val.z, val.w);
    *(int2*)(SB + (size_t)e*(512*512) + (size_t)(v0+vv)*VS + wg) = pv;
  }
  __syncthreads();
  int w = tid>>2, vc = (tid&3)*16;
  unsigned short u[16];
#pragma unroll
  for (int j=0;j<16;j++) u[j] = f2bf(ts[vc+j][w]);
  int4 o0, o1;
  o0.x = u[0]|(u[1]<<16);  o0.y = u[2]|(u[3]<<16);
  o0.z = u[4]|(u[5]<<16);  o0.w = u[6]|(u[7]<<16);
  o1.x = u[8]|(u[9]<<16);  o1.y = u[10]|(u[11]<<16);
  o1.z = u[12]|(u[13]<<16); o1.w = u[14]|(u[15]<<16);
  short* op = ST + (size_t)e*(512*512) + (size_t)(w0+w)*VS + v0 + vc;
  *(int4*)(op) = o0;
  *(int4*)(op+8) = o1;
}

// ST2[e] = (S@S)^T stored [w][u]
__global__ __launch_bounds__(256) void k_ssq(const short* __restrict__ SB,
    const short* __restrict__ ST, short* __restrict__ ST2) {
  __shared__ __align__(16) short As[64*72];
  __shared__ __align__(16) short Bs[64*72];
  int e = blockIdx.z;
  int u0 = blockIdx.x*64, w0 = blockIdx.y*64;
  const short* Ab = SB + (size_t)e*(512*512);
  const short* Bb = ST + (size_t)e*(512*512);
  int tid = threadIdx.x;
  int row = tid>>2, col = (tid&3)*16;
  const short* ap = Ab + (size_t)(u0+row)*VS + col;
  const short* bp = Bb + (size_t)(w0+row)*VS + col;
  f32x4 ra0 = *(const f32x4*)(ap);
  f32x4 ra1 = *(const f32x4*)(ap+8);
  f32x4 rb0 = *(const f32x4*)(bp);
  f32x4 rb1 = *(const f32x4*)(bp+8);
  int wid = tid>>6, lane = tid&63;
  int wr = wid>>1, wc = wid&1;
  int lm = lane&15, lk = (lane>>4)*8;
  f32x4 acc[2][2] = {};
  short* aw = As + row*72 + col;
  short* bw = Bs + row*72 + col;
  for (int kk=0; kk<8; kk++) {
    __syncthreads();
    *(f32x4*)(aw) = ra0; *(f32x4*)(aw+8) = ra1;
    *(f32x4*)(bw) = rb0; *(f32x4*)(bw+8) = rb1;
    __syncthreads();
    if (kk < 7) {
      const short* ap2 = ap + (kk+1)*64;
      const short* bp2 = bp + (kk+1)*64;
      ra0 = *(const f32x4*)(ap2); ra1 = *(const f32x4*)(ap2+8);
      rb0 = *(const f32x4*)(bp2); rb1 = *(const f32x4*)(bp2+8);
    }
#pragma unroll
    for (int ks=0; ks<2; ks++) {
      bf16x8 af0 = *(const bf16x8*)(As + (wr*32 + lm)*72 + ks*32 + lk);
      bf16x8 af1 = *(const bf16x8*)(As + (wr*32 + 16 + lm)*72 + ks*32 + lk);
      bf16x8 bq0 = *(const bf16x8*)(Bs + (wc*32 + lm)*72 + ks*32 + lk);
      bf16x8 bq1 = *(const bf16x8*)(Bs + (wc*32 + 16 + lm)*72 + ks*32 + lk);
      acc[0][0] = __builtin_amdgcn_mfma_f32_16x16x32_bf16(af0, bq0, acc[0][0], 0,0,0);
      acc[0][1] = __builtin_amdgcn_mfma_f32_16x16x32_bf16(af0, bq1, acc[0][1], 0,0,0);
      acc[1][0] = __builtin_amdgcn_mfma_f32_16x16x32_bf16(af1, bq0, acc[1][0], 0,0,0);
      acc[1][1] = __builtin_amdgcn_mfma_f32_16x16x32_bf16(af1, bq1, acc[1][1], 0,0,0);
    }
  }
#pragma unroll
  for (int fm=0; fm<2; fm++) {
    int u4 = u0 + wr*32 + fm*16 + (lane>>4)*4;
#pragma unroll
    for (int fn=0; fn<2; fn++) {
      int w = w0 + wc*32 + fn*16 + lm;
      f32x4 v4 = acc[fm][fn];
      int2 pv; pv.x = pk2(v4.x, v4.y); pv.y = pk2(v4.z, v4.w);
      *(int2*)(ST2 + (size_t)e*(512*512) + (size_t)w*VS + u4) = pv;
    }
  }
}

// GT[b][q][v] bf16 from Gbf[b*NN+v][q] bf16
__global__ __launch_bounds__(256) void k_tposeGb(const short* __restrict__ Gbf,
    short* __restrict__ GT, int qmax) {
  __shared__ __align__(16) short ts[64][72];
  int b = blockIdx.z;
  int v0 = blockIdx.x*64, q0 = blockIdx.y*64;
  int tid = threadIdx.x;
  int vv = tid>>2, qc = (tid&3)*16;
  bool ok = ((v0+vv) < 500) && ((q0+qc) < qmax);
  int4 z4 = {0,0,0,0};
  int4 i0 = z4, i1 = z4;
  if (ok){
    const short* gp = Gbf + (size_t)(b*NN + v0+vv)*QS + q0 + qc;
    i0 = *(const int4*)(gp);
    i1 = *(const int4*)(gp+8);
  }
  *(int4*)&ts[vv][qc] = i0;
  *(int4*)&ts[vv][qc+8] = i1;
  __syncthreads();
  int q = tid>>2, vc = (tid&3)*16;
  if (q0 + q < qmax) {
    unsigned short u[16];
#pragma unroll
    for (int j=0;j<16;j++) u[j] = (unsigned short)ts[vc+j][q];
    int4 o0, o1;
    o0.x = u[0]|(u[1]<<16);  o0.y = u[2]|(u[3]<<16);
    o0.z = u[4]|(u[5]<<16);  o0.w = u[6]|(u[7]<<16);
    o1.x = u[8]|(u[9]<<16);  o1.y = u[10]|(u[11]<<16);
    o1.z = u[12]|(u[13]<<16); o1.w = u[14]|(u[15]<<16);
    short* op = GT + ((size_t)b*QS + q0+q)*VS + v0 + vc;
    *(int4*)(op) = o0;
    *(int4*)(op+8) = o1;
  }
}

// Merged MFMA diffusion, 128x128 tile, XCD-chunked swizzle, LDS-packed stores.
// Flat grid nwg = 512*qt; work w ordered b-major: w = ((b*4+sel)*qt + y)*4 + x
__global__ __launch_bounds__(256) void k_hop2(const short* __restrict__ ST,
    const short* __restrict__ ST2, const short* __restrict__ GT,
    short* __restrict__ Dout, int qmax, int qt) {
  __shared__ __align__(16) short LB[2*128*72];
  short* As = LB;
  short* Bs = LB + 128*72;
  int nwg = gridDim.x;
  int w = (blockIdx.x & 7) * (nwg >> 3) + (blockIdx.x >> 3);
  int x = w & 3; w >>= 2;
  int y = w % qt; w /= qt;
  int sel = w & 3; int b = w >> 2;
  int e = sel >> 1, hop = sel & 1;
  int w0 = x*128, q0 = y*128;
  const short* Ab = (hop ? ST2 : ST) + (size_t)e*(512*512) + (size_t)w0*VS;
  const short* Bb = GT + (size_t)b*(QS*VS) + (size_t)q0*VS;
  int tid = threadIdx.x;
  int row = tid>>2, col = (tid&3)*16;
  const short* ap0 = Ab + (size_t)row*VS + col;
  const short* ap1 = ap0 + (size_t)64*VS;
  const short* bp0 = Bb + (size_t)row*VS + col;
  const short* bp1 = bp0 + (size_t)64*VS;
  f32x4 a00=*(const f32x4*)ap0, a01=*(const f32x4*)(ap0+8);
  f32x4 a10=*(const f32x4*)ap1, a11=*(const f32x4*)(ap1+8);
  f32x4 b00=*(const f32x4*)bp0, b01=*(const f32x4*)(bp0+8);
  f32x4 b10=*(const f32x4*)bp1, b11=*(const f32x4*)(bp1+8);
  int wid = tid>>6, lane = tid&63;
  int wr = wid>>1, wc = wid&1;
  int lm = lane&15, lk = (lane>>4)*8;
  f32x4 acc[4][4] = {};
  short* aw0 = As + row*72 + col; short* aw1 = aw0 + 64*72;
  short* bw0 = Bs + row*72 + col; short* bw1 = bw0 + 64*72;
  for (int kk=0; kk<8; kk++) {
    __syncthreads();
    *(f32x4*)(aw0) = a00; *(f32x4*)(aw0+8) = a01;
    *(f32x4*)(aw1) = a10; *(f32x4*)(aw1+8) = a11;
    *(f32x4*)(bw0) = b00; *(f32x4*)(bw0+8) = b01;
    *(f32x4*)(bw1) = b10; *(f32x4*)(bw1+8) = b11;
    __syncthreads();
    if (kk < 7) {
      int o = (kk+1)*64;
      a00=*(const f32x4*)(ap0+o); a01=*(const f32x4*)(ap0+o+8);
      a10=*(const f32x4*)(ap1+o); a11=*(const f32x4*)(ap1+o+8);
      b00=*(const f32x4*)(bp0+o); b01=*(const f32x4*)(bp0+o+8);
      b10=*(const f32x4*)(bp1+o); b11=*(const f32x4*)(bp1+o+8);
    }
#pragma unroll
    for (int ks=0; ks<2; ks++) {
      bf16x8 af[4], bq[4];
#pragma unroll
      for (int fm=0;fm<4;fm++) af[fm] = *(const bf16x8*)(As + (wr*64+fm*16+lm)*72 + ks*32 + lk);
#pragma unroll
      for (int fn=0;fn<4;fn++) bq[fn] = *(const bf16x8*)(Bs + (wc*64+fn*16+lm)*72 + ks*32 + lk);
#pragma unroll
      for (int fm=0;fm<4;fm++)
#pragma unroll
        for (int fn=0;fn<4;fn++)
          acc[fm][fn] = __builtin_amdgcn_mfma_f32_16x16x32_bf16(af[fm], bq[fn], acc[fm][fn], 0,0,0);
    }
  }
  // epilogue: acc -> LDS [128][136] bf16 -> coalesced int4 stores
  __syncthreads();
#pragma unroll
  for (int fm=0; fm<4; fm++){
    int rr = wr*64 + fm*16 + (lane>>4)*4;
#pragma unroll
    for (int fn=0; fn<4; fn++){
      int cc = wc*64 + fn*16 + lm;
      f32x4 v4 = acc[fm][fn];
      LB[(rr+0)*136 + cc] = (short)f2bf(v4.x);
      LB[(rr+1)*136 + cc] = (short)f2bf(v4.y);
      LB[(rr+2)*136 + cc] = (short)f2bf(v4.z);
      LB[(rr+3)*136 + cc] = (short)f2bf(v4.w);
    }
  }
  __syncthreads();
  short* Ob = Dout + (size_t)sel*DSZ + (size_t)b*(NN*QS);
#pragma unroll
  for (int pass=0; pass<8; pass++){
    int rr = pass*16 + (tid>>4);
    int cc = (tid&15)*8;
    int wg = w0 + rr, qg = q0 + cc;
    if (wg < 500 && qg < qmax){
      int4 vv = *(const int4*)(LB + rr*136 + cc);
      *(int4*)(Ob + (size_t)wg*QS + qg) = vv;
    }
  }
}

// ================= input projection / enter conv =================

__global__ void k_proj(const float* __restrict__ inputs, const float* __restrict__ factor,
                       float* __restrict__ proj) {
  int bt = blockIdx.x;
  __shared__ float xin[NN*2];
  for (int idx=threadIdx.x; idx<NN*2; idx+=64) xin[idx] = inputs[bt*NN*2 + idx];
  __syncthreads();
  int u = threadIdx.x>>1, f = threadIdx.x&1;
  float acc=0.f;
  for (int n=0;n<NN;n++) acc += xin[n*2+f]*factor[n*UU+u];
  proj[bt*64 + u*2+f] = acc;
}

__global__ __launch_bounds__(256) void k_enter(const float* __restrict__ inputs,
    const float* __restrict__ factor, const float* __restrict__ proj,
    const float* __restrict__ ew, const float* __restrict__ eb, float* __restrict__ X) {
  int idx = blockIdx.x*256+threadIdx.x;
  if (idx >= BB*NN*TX) return;
  int t = idx % TX; int n = (idx/TX)%NN; int b = idx/(TX*NN);
  float x4[4]={0.f,0.f,0.f,0.f};
  if (t>0) {
    int tt=t-1;
    float s0=0.f,s1=0.f;
    const float* pr = proj + (b*TT+tt)*64;
    const float* fr = factor + n*UU;
#pragma unroll
    for(int u=0;u<UU;u++){ s0 += pr[u*2]*fr[u]; s1 += pr[u*2+1]*fr[u]; }
    float i0 = inputs[((b*TT+tt)*NN+n)*2];
    float i1 = inputs[((b*TT+tt)*NN+n)*2+1];
    x4[0]=s0; x4[1]=s1; x4[2]=i0-s0; x4[3]=i1-s1;
  }
  float* xp = X + ((size_t)(b*NN+n)*TX + t)*CC;
#pragma unroll
  for(int o=0;o<CC;o++){
    xp[o] = eb[o] + ew[o*4]*x4[0] + ew[o*4+1]*x4[1] + ew[o*4+2]*x4[2] + ew[o*4+3]*x4[3];
  }
}

// ================= MFMA gated temporal conv =================

__global__ __launch_bounds__(256) void k_gated3(const float* __restrict__ X,
    short* __restrict__ Gbf, short* __restrict__ Glb,
    const float* __restrict__ fw, const float* __restrict__ fb,
    const float* __restrict__ gw, const float* __restrict__ gb,
    const float* __restrict__ stat, int use_stat, int d, int t_out, int lidx) {
  __shared__ __align__(16) short As[64*72];
  __shared__ __align__(16) short Wb[64*72];
  __shared__ float scs[32], shs[32];
  int tid = threadIdx.x;
  if (tid < 32) {
    scs[tid] = use_stat ? stat[tid] : 1.0f;
    shs[tid] = use_stat ? stat[32 + tid] : 0.0f;
  }
  for (int i = tid; i < 2048; i += 256) {
    int o = i >> 6, k = i & 63;
    Wb[o*72 + k]      = (short)f2bf(fw[i]);
    Wb[(32+o)*72 + k] = (short)f2bf(gw[i]);
  }
  __syncthreads();
  int m0 = blockIdx.x * 64;
  {
    int mm = tid & 63;
    int kb = (tid >> 6) * 16;
    int c0 = kb >> 1;
    int m = m0 + mm;
    int bn = m / t_out, t = m - bn * t_out;
    const float* xr = X + (size_t)bn * (TX * CC);
    float4 a0 = *(const float4*)(xr + t * 32 + c0);
    float4 a1 = *(const float4*)(xr + t * 32 + c0 + 4);
    float4 b0 = *(const float4*)(xr + (t + d) * 32 + c0);
    float4 b1 = *(const float4*)(xr + (t + d) * 32 + c0 + 4);
    float va[8] = {a0.x,a0.y,a0.z,a0.w,a1.x,a1.y,a1.z,a1.w};
    float vb[8] = {b0.x,b0.y,b0.z,b0.w,b1.x,b1.y,b1.z,b1.w};
    int iv[8];
#pragma unroll
    for (int j = 0; j < 8; j++) {
      float sc = scs[c0+j], sh = shs[c0+j];
      iv[j] = pk2(va[j]*sc + sh, vb[j]*sc + sh);
    }
    int4 w0 = {iv[0],iv[1],iv[2],iv[3]};
    int4 w1 = {iv[4],iv[5],iv[6],iv[7]};
    *(int4*)(As + mm*72 + kb) = w0;
    *(int4*)(As + mm*72 + kb + 8) = w1;
  }
  __syncthreads();
  int wid = tid>>6, lane = tid&63;
  int lm = lane&15, g = lane>>4, lk8 = g*8;
  f32x4 acc[4] = {};
#pragma unroll
  for (int kk=0; kk<2; kk++){
    bf16x8 af = *(const bf16x8*)(As + (wid*16+lm)*72 + kk*32 + lk8);
#pragma unroll
    for (int fn=0; fn<4; fn++){
      bf16x8 bq = *(const bf16x8*)(Wb + (fn*16+lm)*72 + kk*32 + lk8);
      acc[fn] = __builtin_amdgcn_mfma_f32_16x16x32_bf16(af, bq, acc[fn], 0,0,0);
    }
  }
#pragma unroll
  for (int fn=0; fn<2; fn++){
    int o = fn*16 + lm;
    float fbv = fb[o], gbv = gb[o];
#pragma unroll
    for (int r=0; r<4; r++){
      int m = m0 + wid*16 + g*4 + r;
      int bn = m / t_out, t = m - bn*t_out;
      float f = acc[fn][r] + fbv;
      float gg = acc[fn+2][r] + gbv;
      float th = 2.f/(1.f+__expf(-2.f*f)) - 1.f;
      float sg = 1.f/(1.f+__expf(-gg));
      unsigned short ov = f2bf(th*sg);
      Gbf[(size_t)bn*QS + t*32 + o] = (short)ov;
      if (t == t_out-1) Glb[(size_t)bn*256 + lidx*32 + o] = (short)ov;
    }
  }
}

// ======= MFMA graph-conv 1x1 + residual + BN partials (256 thr, 4 waves) =======

template<int TOUT>
__global__ __launch_bounds__(256) void k_gc3(const short* __restrict__ Gbf,
    const short* __restrict__ Dbf, const float* __restrict__ Xc, float* __restrict__ Xn,
    const float* __restrict__ gcw, const float* __restrict__ gcb,
    const float* __restrict__ stat, int use_stat, float* __restrict__ part, int d) {
  int tid = threadIdx.x;
  int wid = tid>>6, lane = tid&63;
  int lm = lane&15, g = lane>>4, lk8 = g*8;
  int m0 = blockIdx.x*256 + wid*64;
  const int M = 16000*TOUT;
  float* pp = part + ((size_t)blockIdx.x*4 + wid)*64;
  if (m0 >= M){
    if (lane < 16){ pp[lane]=0.f; pp[16+lane]=0.f; pp[32+lane]=0.f; pp[48+lane]=0.f; }
    return;
  }
  bf16x8 wf[5][2];
#pragma unroll
  for (int ks=0;ks<5;ks++)
#pragma unroll
    for (int nh=0;nh<2;nh++){
      const float* wp = gcw + (nh*16+lm)*160 + ks*32 + lk8;
      wf[ks][nh] = pack8(*(const f32x4*)wp, *(const f32x4*)(wp+4));
    }
  float scn0 = use_stat ? stat[lm]    : 1.f;
  float scn1 = use_stat ? stat[16+lm] : 1.f;
  float shn0 = use_stat ? stat[32+lm] : 0.f;
  float shn1 = use_stat ? stat[48+lm] : 0.f;
  float gb0 = gcb[lm], gb1 = gcb[16+lm];
  float ss0=0.f, sq0=0.f, ss1=0.f, sq1=0.f;
#pragma unroll
  for (int mg=0; mg<4; mg++){
    int m = m0 + mg*16 + lm;
    int bn = m / TOUT; int t = m - bn*TOUT;
    size_t off = (size_t)bn*(TG*CC) + t*32 + lk8;
    f32x4 acc0={0,0,0,0}, acc1={0,0,0,0};
    {
      bf16x8 af = *(const bf16x8*)(Gbf + off);
      acc0 = __builtin_amdgcn_mfma_f32_16x16x32_bf16(af, wf[0][0], acc0, 0,0,0);
      acc1 = __builtin_amdgcn_mfma_f32_16x16x32_bf16(af, wf[0][1], acc1, 0,0,0);
    }
#pragma unroll
    for (int ks=1;ks<5;ks++){
      bf16x8 af = *(const bf16x8*)(Dbf + (size_t)(ks-1)*DSZ + off);
      acc0 = __builtin_amdgcn_mfma_f32_16x16x32_bf16(af, wf[ks][0], acc0, 0,0,0);
      acc1 = __builtin_amdgcn_mfma_f32_16x16x32_bf16(af, wf[ks][1], acc1, 0,0,0);
    }
#pragma unroll
    for (int r=0;r<4;r++){
      int mr = m0 + mg*16 + g*4 + r;
      int bnr = mr / TOUT; int tr = mr - bnr*TOUT;
      size_t xoff = (size_t)bnr*(TX*CC);
      float r0 = Xc[xoff + (tr+d)*32 + lm];
      float r1 = Xc[xoff + (tr+d)*32 + 16 + lm];
      float v0 = acc0[r] + gb0 + r0*scn0 + shn0;
      float v1 = acc1[r] + gb1 + r1*scn1 + shn1;
      Xn[xoff + tr*32 + lm] = v0;
      Xn[xoff + tr*32 + 16 + lm] = v1;
      ss0+=v0; sq0+=v0*v0; ss1+=v1; sq1+=v1*v1;
    }
  }
#pragma unroll
  for (int off=16; off<64; off<<=1){
    ss0+=__shfl_xor(ss0,off); sq0+=__shfl_xor(sq0,off);
    ss1+=__shfl_xor(ss1,off); sq1+=__shfl_xor(sq1,off);
  }
  if (lane<16){
    pp[lane]=ss0; pp[16+lane]=ss1; pp[32+lane]=sq0; pp[48+lane]=sq1;
  }
}

// 2-stage BN-stat reduction
__global__ __launch_bounds__(64) void k_stat2a(const float* __restrict__ part, int nblk,
    float* __restrict__ part2) {
  int t = threadIdx.x;
  float s = 0.f;
  for (int i = blockIdx.x; i < nblk; i += 64) s += part[(size_t)i*64 + t];
  part2[blockIdx.x*64 + t] = s;
}

__global__ __launch_bounds__(64) void k_stat2b(const float* __restrict__ part2,
    const float* __restrict__ g, const float* __restrict__ b,
    float* __restrict__ statout, float cntinv) {
  int t = threadIdx.x;
  float s = 0.f;
#pragma unroll 8
  for (int i = 0; i < 64; i++) s += part2[i*64 + t];
  __shared__ float red[64];
  red[t] = s;
  __syncthreads();
  if (t < 32){
    float sum = red[t], sq = red[32+t];
    float m = sum*cntinv, var = sq*cntinv - m*m;
    float sc = rsqrtf(var + BN_EPS)*g[t];
    statout[t] = sc;
    statout[32+t] = b[t] - m*sc;
  }
}

// ================= output head =================

__global__ void k_wstack2(const float* __restrict__ skp_w, const float* __restrict__ skp_b,
                          const float* __restrict__ o1w,
                          short* __restrict__ Wstb, short* __restrict__ o1wb,
                          float* __restrict__ bsum) {
  int bid = blockIdx.x;
  int idx = bid*256 + threadIdx.x;
  if (bid < 256){
    int kk = idx >> 8, o = idx & 255;
    Wstb[o*256 + kk] = (short)f2bf(skp_w[(kk>>5)*8192 + o*32 + (kk&31)]);
    if (idx < 256){
      float s=0.f;
      for (int l=0;l<8;l++) s += skp_b[l*256+idx];
      bsum[idx]=s;
    }
  } else {
    int j = idx - 65536;
    o1wb[j] = (short)f2bf(o1w[j]);
  }
}

// C[m][n] = relu(sum_k A[m][k]*B[n][k] + bias[n]) -> bf16 out
__global__ __launch_bounds__(256) void k_mm(const short* __restrict__ A,
    const short* __restrict__ B, const float* __restrict__ bias,
    short* __restrict__ out, int ldout, int K) {
  __shared__ __align__(16) short As[64*72];
  __shared__ __align__(16) short Bs[64*72];
  int m0 = blockIdx.x*64, n0 = blockIdx.y*64;
  int tid = threadIdx.x;
  int row = tid>>2, col = (tid&3)*16;
  const short* ap = A + (size_t)(m0+row)*K + col;
  const short* bp = B + (size_t)(n0+row)*K + col;
  f32x4 ra0 = *(const f32x4*)(ap);
  f32x4 ra1 = *(const f32x4*)(ap+8);
  f32x4 rb0 = *(const f32x4*)(bp);
  f32x4 rb1 = *(const f32x4*)(bp+8);
  int wid = tid>>6, lane = tid&63;
  int wr = wid>>1, wc = wid&1;
  int lm = lane&15, lk = (lane>>4)*8;
  f32x4 acc[2][2] = {};
  short* aw = As + row*72 + col;
  short* bw = Bs + row*72 + col;
  int nk = K>>6;
  for (int kk=0; kk<nk; kk++) {
    __syncthreads();
    *(f32x4*)(aw) = ra0; *(f32x4*)(aw+8) = ra1;
    *(f32x4*)(bw) = rb0; *(f32x4*)(bw+8) = rb1;
    __syncthreads();
    if (kk < nk-1) {
      const short* ap2 = ap + (kk+1)*64;
      const short* bp2 = bp + (kk+1)*64;
      ra0 = *(const f32x4*)(ap2); ra1 = *(const f32x4*)(ap2+8);
      rb0 = *(const f32x4*)(bp2); rb1 = *(const f32x4*)(bp2+8);
    }
#pragma unroll
    for (int ks=0; ks<2; ks++) {
      bf16x8 af0 = *(const bf16x8*)(As + (wr*32 + lm)*72 + ks*32 + lk);
      bf16x8 af1 = *(const bf16x8*)(As + (wr*32 + 16 + lm)*72 + ks*32 + lk);
      bf16x8 bq0 = *(const bf16x8*)(Bs + (wc*32 + lm)*72 + ks*32 + lk);
      bf16x8 bq1 = *(const bf16x8*)(Bs + (wc*32 + 16 + lm)*72 + ks*32 + lk);
      acc[0][0] = __builtin_amdgcn_mfma_f32_16x16x32_bf16(af0, bq0, acc[0][0], 0,0,0);
      acc[0][1] = __builtin_amdgcn_mfma_f32_16x16x32_bf16(af0, bq1, acc[0][1], 0,0,0);
      acc[1][0] = __builtin_amdgcn_mfma_f32_16x16x32_bf16(af1, bq0, acc[1][0], 0,0,0);
      acc[1][1] = __builtin_amdgcn_mfma_f32_16x16x32_bf16(af1, bq1, acc[1][1], 0,0,0);
    }
  }
#pragma unroll
  for (int fm=0; fm<2; fm++) {
    int mb = m0 + wr*32 + fm*16 + (lane>>4)*4;
#pragma unroll
    for (int fn=0; fn<2; fn++) {
      int n = n0 + wc*32 + fn*16 + lm;
      float bv = bias[n];
      f32x4 v4 = acc[fm][fn];
#pragma unroll
      for (int r=0;r<4;r++)
        out[(size_t)(mb+r)*ldout + n] = (short)f2bf(fmaxf(v4[r]+bv, 0.f));
    }
  }
}

// head2 as MFMA skinny GEMM: y[m][p] = Y1b[m][512] . o2w[p][512] + o2b, p<12 (N=16 padded)
__global__ __launch_bounds__(256) void k_head2m(const short* __restrict__ Y1b,
    const float* __restrict__ o2w, const float* __restrict__ o2b, float* __restrict__ y) {
  int tid = threadIdx.x;
  int wid = tid>>6, lane = tid&63;
  int lm = lane&15, g = lane>>4, lk8 = g*8;
  int m0 = blockIdx.x*64 + wid*16;
  bf16x8 wf[16];
#pragma unroll
  for (int ks=0; ks<16; ks++){
    f32x4 lo={0,0,0,0}, hi={0,0,0,0};
    if (lm < NPREDC){
      const float* wp = o2w + lm*NENDC + ks*32 + lk8;
      lo = *(const f32x4*)wp; hi = *(const f32x4*)(wp+4);
    }
    wf[ks] = pack8(lo, hi);
  }
  f32x4 acc = {0,0,0,0};
  const short* ar = Y1b + (size_t)(m0+lm)*NENDC;
#pragma unroll
  for (int ks=0; ks<16; ks++){
    bf16x8 af = *(const bf16x8*)(ar + ks*32 + lk8);
    acc = __builtin_amdgcn_mfma_f32_16x16x32_bf16(af, wf[ks], acc, 0,0,0);
  }
  int p = lm;
  if (p < NPREDC){
    float bv = o2b[p];
#pragma unroll
    for (int r=0;r<4;r++){
      int m = m0 + g*4 + r;
      int bb = m/NN, n = m - bb*NN;
      y[(bb*NPREDC+p)*NN + n] = acc[r] + bv;
    }
  }
}

// ================= host =================

extern "C" void kernel_launch(void* const* d_in, const int* in_sizes, int n_in,
                              void* d_out, int out_size, void* d_ws, size_t ws_size,
                              hipStream_t stream) {
  const float* inputs  = (const float*)d_in[0];
  const float* factor  = (const float*)d_in[1];
  const float* map_w   = (const float*)d_in[2];
  const float* map_b   = (const float*)d_in[3];
  const float* a1w     = (const float*)d_in[4];
  const float* a1b     = (const float*)d_in[5];
  const float* a2w     = (const float*)d_in[6];
  const float* a2b     = (const float*)d_in[7];
  const float* a3w     = (const float*)d_in[8];
  const float* a3b     = (const float*)d_in[9];
  const float* enter_w = (const float*)d_in[10];
  const float* enter_b = (const float*)d_in[11];
  const float* filt_w  = (const float*)d_in[12];
  const float* filt_b  = (const float*)d_in[13];
  const float* gate_w  = (const float*)d_in[14];
  const float* gate_b  = (const float*)d_in[15];
  const float* skp_w   = (const float*)d_in[16];
  const float* skp_b   = (const float*)d_in[17];
  const float* gc_w    = (const float*)d_in[18];
  const float* gc_b    = (const float*)d_in[19];
  const float* bn_g    = (const float*)d_in[20];
  const float* bn_b    = (const float*)d_in[21];
  const float* o1w     = (const float*)d_in[22];
  const float* o1b     = (const float*)d_in[23];
  const float* o2w     = (const float*)d_in[24];
  const float* o2b     = (const float*)d_in[25];
  (void)in_sizes; (void)n_in; (void)out_size; (void)ws_size;

  float* ws = (float*)d_ws;
  float* v      = ws + OFF_V;
  float* adj    = ws + OFF_ADJ;
  float* part2  = ws + OFF_ADJ;      // reuse (adj dead after k_tposeS)
  float* asrc   = ws + OFF_ASRC;
  float* adst   = ws + OFF_ADST;
  float* proj   = ws + OFF_PROJ;
  float* statb  = ws + OFF_STAT;
  float* part   = ws + OFF_PART;
  float* bsum   = ws + OFF_BSUM;
  float* X      = ws + OFF_X;
  float* Xn     = ws + OFF_XN;
  short* Dbf    = (short*)(ws + OFF_D);
  short* Gbf    = (short*)(ws + OFF_GBF);
  short* Glb    = (short*)(ws + OFF_GLB);
  short* GT     = (short*)(ws + OFF_GT);
  short* ST     = (short*)(ws + OFF_ST);
  short* SB     = (short*)(ws + OFF_SB);
  short* ST2    = (short*)(ws + OFF_ST2);
  short* Wstb   = (short*)(ws + OFF_WSTB);
  short* o1wb   = (short*)(ws + OFF_O1WB);
  short* skvb   = (short*)(ws + OFF_SKV);
  short* Y1b    = (short*)(ws + OFF_Y1B);

  float* y_out   = (float*)d_out;
  float* sup_out = y_out + BB*NPREDC*NN;

  // adaptive supports
  k_v<<<NN, 32, 0, stream>>>(factor, map_w, map_b, v);
  k_asrc2<<<NN, 64, 0, stream>>>(v, a1w, a1b, asrc, adst);
  {
    dim3 gp(NN, 2);
    k_pair3<<<gp, 256, 0, stream>>>(asrc, adst, a2w, a2b, a3w, a3b, adj);
  }
  k_softmax<<<2*NN, 256, 0, stream>>>(adj, sup_out);
  {
    dim3 gt(8, 8, 2);
    k_tposeS<<<gt, 256, 0, stream>>>(sup_out, ST, SB);
    k_ssq<<<gt, 256, 0, stream>>>(SB, ST, ST2);
  }

  // input split + enter
  k_proj<<<BB*TT, 64, 0, stream>>>(inputs, factor, proj);
  k_enter<<<(BB*NN*TX+255)/256, 256, 0, stream>>>(inputs, factor, proj, enter_w, enter_b, X);

  // head weight prep (independent)
  k_wstack2<<<768, 256, 0, stream>>>(skp_w, skp_b, o1w, Wstb, o1wb, bsum);

  float* Xc = X; float* Xo = Xn;
  int t = TX;
  static const int dil[8]={1,2,1,2,1,2,1,2};
  for (int l=0;l<7;l++){
    int d=dil[l], t_out=t-d;
    const float* st = statb + (l>0 ? (l-1)*64 : 0);
    k_gated3<<<250*t_out,256,0,stream>>>(Xc, Gbf, Glb, filt_w + l*2048, filt_b + l*32,
                                         gate_w + l*2048, gate_b + l*32, st, l>0, d, t_out, l);
    int qmax = t_out*CC;
    int qt64 = (qmax+63)/64;
    dim3 gtp(8, qt64, 32);
    k_tposeGb<<<gtp,256,0,stream>>>(Gbf, GT, qmax);
    int qt128 = (qmax+127)/128;
    k_hop2<<<512*qt128,256,0,stream>>>(ST, ST2, GT, Dbf, qmax, qt128);
    int nb = (16000*t_out + 255)/256;
    const float* gcwl = gc_w + l*5120;
    const float* gcbl = gc_b + l*32;
    switch (t_out){
      case 12: k_gc3<12><<<nb,256,0,stream>>>(Gbf,Dbf,Xc,Xo,gcwl,gcbl,st,l>0,part,d); break;
      case 10: k_gc3<10><<<nb,256,0,stream>>>(Gbf,Dbf,Xc,Xo,gcwl,gcbl,st,l>0,part,d); break;
      case  9: k_gc3< 9><<<nb,256,0,stream>>>(Gbf,Dbf,Xc,Xo,gcwl,gcbl,st,l>0,part,d); break;
      case  7: k_gc3< 7><<<nb,256,0,stream>>>(Gbf,Dbf,Xc,Xo,gcwl,gcbl,st,l>0,part,d); break;
      case  6: k_gc3< 6><<<nb,256,0,stream>>>(Gbf,Dbf,Xc,Xo,gcwl,gcbl,st,l>0,part,d); break;
      case  4: k_gc3< 4><<<nb,256,0,stream>>>(Gbf,Dbf,Xc,Xo,gcwl,gcbl,st,l>0,part,d); break;
      default: k_gc3< 3><<<nb,256,0,stream>>>(Gbf,Dbf,Xc,Xo,gcwl,gcbl,st,l>0,part,d); break;
    }
    k_stat2a<<<64,64,0,stream>>>(part, nb*4, part2);
    k_stat2b<<<1,64,0,stream>>>(part2, bn_g + l*32, bn_b + l*32,
                                statb + l*64, 1.f/(16000.f*(float)t_out));
    float* tmp=Xc; Xc=Xo; Xo=tmp;
    t = t_out;
  }
  // layer 8: only gated conv feeds skip
  k_gated3<<<250*1,256,0,stream>>>(Xc, Gbf, Glb, filt_w + 7*2048, filt_b + 7*32,
                                   gate_w + 7*2048, gate_b + 7*32, statb + 6*64, 1, 2, 1, 7);

  // head: skip GEMM -> head1 -> head2
  {
    dim3 gs(BNN/64, NSKIPC/64);
    k_mm<<<gs,256,0,stream>>>(Glb, Wstb, bsum, skvb, NSKIPC, 256);
    dim3 gh(BNN/64, NENDC/64);
    k_mm<<<gh,256,0,stream>>>(skvb, o1wb, o1b, Y1b, NENDC, 256);
    k_head2m<<<BNN/64,256,0,stream>>>(Y1b, o2w, o2b, y_out);
  }
}

// Round 11
// 725.006 us; speedup vs baseline: 11.4184x; 1.0050x over previous
//
#include <hip/hip_runtime.h>
#include <math.h>

// ---- static config ----
#define BB 32
#define TT 12
#define NN 500
#define UU 32
#define CC 32
#define NSKIPC 256
#define NENDC 512
#define NPREDC 12
#define TX 13
#define TG 12
#define QS 384
#define VS 512
#define BNN (BB*NN)
#define DSZ (BNN*TG*CC)
#define BN_EPS 1e-5f

// ---- workspace offsets (floats) ----
#define OFF_V      0u
#define OFF_ADJ    16000u        // adj 500000; tail reused as part2 (4096) after supports
#define OFF_ASRC   516000u
#define OFF_ADST   548000u
#define OFF_PROJ   580000u
#define OFF_STAT   582048u
#define OFF_PART   582560u       // 3000*64 = 192000
#define OFF_BSUM   774560u
#define OFF_X      774816u
#define OFF_XN     7430816u
#define OFF_D      14086816u     // (now unused diffusion scratch)
#define OFF_GBF    38662816u     // shorts 6144000 (G bf16 [16000][384])
#define OFF_GLB    41734816u     // shorts 4096000 (Glast bf16 [16000][256])
#define OFF_GT     43782816u     // shorts 6291456
#define OFF_ST     46928544u     // shorts 524288
#define OFF_SB     47190688u
#define OFF_ST2    47452832u
#define OFF_WSTB   47714976u     // shorts 65536
#define OFF_O1WB   47747744u     // shorts 131072
#define OFF_SKV    47813280u     // shorts 4096000 (skipv bf16)
#define OFF_Y1B    49861280u     // shorts 8192000 (Y1 bf16) -> ends 53957280

typedef __attribute__((ext_vector_type(8))) short bf16x8;
typedef __attribute__((ext_vector_type(4))) float f32x4;

__device__ inline unsigned short f2bf(float f) {
  union { float f; unsigned u; } x; x.f = f;
  unsigned r = x.u + 0x7FFFu + ((x.u >> 16) & 1u);
  return (unsigned short)(r >> 16);
}
__device__ inline float bf2f(short s) {
  union { float f; unsigned u; } x;
  x.u = ((unsigned)(unsigned short)s) << 16;
  return x.f;
}
__device__ inline int pk2(float a, float b) {
  return (int)((unsigned)f2bf(a) | ((unsigned)f2bf(b) << 16));
}
__device__ inline bf16x8 pack8(f32x4 a, f32x4 b) {
  union { int i[4]; bf16x8 v; } u;
  u.i[0]=pk2(a.x,a.y); u.i[1]=pk2(a.z,a.w);
  u.i[2]=pk2(b.x,b.y); u.i[3]=pk2(b.z,b.w);
  return u.v;
}
__device__ inline f32x4 reluadd(f32x4 a, f32x4 b) {
  f32x4 r;
  r.x=fmaxf(a.x+b.x,0.f); r.y=fmaxf(a.y+b.y,0.f);
  r.z=fmaxf(a.z+b.z,0.f); r.w=fmaxf(a.w+b.w,0.f);
  return r;
}

// ================= adaptive supports =================

__global__ void k_v(const float* __restrict__ factor, const float* __restrict__ map_w,
                    const float* __restrict__ map_b, float* __restrict__ v) {
  int n = blockIdx.x; int d = threadIdx.x;
  __shared__ float fr[UU];
  fr[d] = factor[n*UU + d];
  __syncthreads();
  float acc = map_b[d];
#pragma unroll
  for (int u=0;u<UU;u++) acc += fr[u]*map_w[u*32+d];
  v[n*32+d] = fmaxf(acc, 0.f);
}

__global__ void k_asrc2(const float* __restrict__ v, const float* __restrict__ a1w,
                        const float* __restrict__ a1b,
                        float* __restrict__ asrc, float* __restrict__ adst) {
  int n = blockIdx.x; int o = threadIdx.x; // 64 threads
  __shared__ float vn[32];
  if (o < 32) vn[o] = v[n*32+o];
  __syncthreads();
  float s = 0.f, dst = a1b[o];
#pragma unroll
  for (int u=0;u<32;u++){ s += vn[u]*a1w[u*64+o]; dst += vn[u]*a1w[(32+u)*64+o]; }
  asrc[n*64+o] = s;
  adst[n*64+o] = dst;
}

__global__ __launch_bounds__(256) void k_pair3(const float* __restrict__ asrc,
    const float* __restrict__ adst, const float* __restrict__ a2w,
    const float* __restrict__ a2b, const float* __restrict__ a3w,
    const float* __restrict__ a3b, float* __restrict__ adj) {
  int i = blockIdx.x;
  int tid = threadIdx.x;
  int wid = tid>>6, lane = tid&63;
  int lm = lane&15, g = lane>>4, lk8 = g*8;
  int jb = blockIdx.y*256 + wid*64;
  bf16x8 wf[2][2];
#pragma unroll
  for (int ks=0;ks<2;ks++)
#pragma unroll
    for (int nh=0;nh<2;nh++){
      int n = nh*16+lm;
      f32x4 lo, hi;
      lo.x=a2w[(ks*32+lk8+0)*32+n]; lo.y=a2w[(ks*32+lk8+1)*32+n];
      lo.z=a2w[(ks*32+lk8+2)*32+n]; lo.w=a2w[(ks*32+lk8+3)*32+n];
      hi.x=a2w[(ks*32+lk8+4)*32+n]; hi.y=a2w[(ks*32+lk8+5)*32+n];
      hi.z=a2w[(ks*32+lk8+6)*32+n]; hi.w=a2w[(ks*32+lk8+7)*32+n];
      wf[ks][nh] = pack8(lo, hi);
    }
  float b20 = a2b[lm], b21 = a2b[16+lm];
  float w3e0n0 = a3w[lm*2],      w3e1n0 = a3w[lm*2+1];
  float w3e0n1 = a3w[(16+lm)*2], w3e1n1 = a3w[(16+lm)*2+1];
  float b30 = a3b[0], b31 = a3b[1];
  const float* dp = adst + i*64;
  f32x4 d00 = *(const f32x4*)(dp + lk8);
  f32x4 d01 = *(const f32x4*)(dp + lk8 + 4);
  f32x4 d10 = *(const f32x4*)(dp + 32 + lk8);
  f32x4 d11 = *(const f32x4*)(dp + 32 + lk8 + 4);
#pragma unroll
  for (int mg=0; mg<4; mg++){
    int j = jb + mg*16 + lm;
    int jc = j < 500 ? j : 0;
    const float* ap = asrc + jc*64;
    f32x4 s00=*(const f32x4*)(ap+lk8),    s01=*(const f32x4*)(ap+lk8+4);
    f32x4 s10=*(const f32x4*)(ap+32+lk8), s11=*(const f32x4*)(ap+32+lk8+4);
    bf16x8 a0 = pack8(reluadd(s00,d00), reluadd(s01,d01));
    bf16x8 a1 = pack8(reluadd(s10,d10), reluadd(s11,d11));
    f32x4 acc0 = {b20,b20,b20,b20};
    f32x4 acc1 = {b21,b21,b21,b21};
    acc0 = __builtin_amdgcn_mfma_f32_16x16x32_bf16(a0, wf[0][0], acc0, 0,0,0);
    acc0 = __builtin_amdgcn_mfma_f32_16x16x32_bf16(a1, wf[1][0], acc0, 0,0,0);
    acc1 = __builtin_amdgcn_mfma_f32_16x16x32_bf16(a0, wf[0][1], acc1, 0,0,0);
    acc1 = __builtin_amdgcn_mfma_f32_16x16x32_bf16(a1, wf[1][1], acc1, 0,0,0);
    float e0[4], e1[4];
#pragma unroll
    for (int r=0;r<4;r++){
      float h2a = fmaxf(acc0[r],0.f), h2b = fmaxf(acc1[r],0.f);
      e0[r] = h2a*w3e0n0 + h2b*w3e0n1;
      e1[r] = h2a*w3e1n0 + h2b*w3e1n1;
    }
#pragma unroll
    for (int off=1; off<16; off<<=1){
#pragma unroll
      for (int r=0;r<4;r++){ e0[r]+=__shfl_xor(e0[r],off); e1[r]+=__shfl_xor(e1[r],off); }
    }
    if (lm==0){
      int j4 = jb + mg*16 + g*4;
      if (j4 < 500){
        f32x4 v0={e0[0]+b30,e0[1]+b30,e0[2]+b30,e0[3]+b30};
        f32x4 v1={e1[0]+b31,e1[1]+b31,e1[2]+b31,e1[3]+b31};
        *(f32x4*)(adj + i*500 + j4) = v0;
        *(f32x4*)(adj + 250000 + i*500 + j4) = v1;
      }
    }
  }
}

__global__ __launch_bounds__(256) void k_softmax(const float* __restrict__ adj,
    float* __restrict__ sup_out) {
  int row = blockIdx.x;
  int e = row/NN, i = row%NN;
  const float* a = adj + e*250000 + i*NN;
  __shared__ float red[64];
  float m = -1e30f;
  for (int j=threadIdx.x;j<NN;j+=256) m = fmaxf(m, a[j]);
#pragma unroll
  for (int off=32; off; off>>=1) m = fmaxf(m, __shfl_down(m, off));
  int lane = threadIdx.x & 63, wid = threadIdx.x >> 6;
  if (lane==0) red[wid]=m;
  __syncthreads();
  if (threadIdx.x==0){ float mm=red[0]; for(int w=1;w<4;w++) mm=fmaxf(mm,red[w]); red[32]=mm; }
  __syncthreads();
  m = red[32];
  float s=0.f;
  for (int j=threadIdx.x;j<NN;j+=256) s += __expf(a[j]-m);
#pragma unroll
  for (int off=32; off; off>>=1) s += __shfl_down(s, off);
  if (lane==0) red[wid]=s;
  __syncthreads();
  if (threadIdx.x==0){ float ss=0; for(int w=0;w<4;w++) ss+=red[w]; red[33]=ss; }
  __syncthreads();
  float inv = 1.f/red[33];
  for (int j=threadIdx.x;j<NN;j+=256) {
    float val = __expf(a[j]-m)*inv;
    if (j==i) val = 1.f;
    sup_out[e*250000 + i*NN + j] = val;
  }
}

// ST[e][w][v] transposed bf16 + SB[e][v][w] cast bf16 (both 512x512 zero-padded)
__global__ __launch_bounds__(256) void k_tposeS(const float* __restrict__ sup,
    short* __restrict__ ST, short* __restrict__ SB) {
  __shared__ float ts[64][68];
  int e = blockIdx.z;
  int v0 = blockIdx.x*64, w0 = blockIdx.y*64;
  int tid = threadIdx.x;
  int vv = tid>>2, wc = (tid&3)*16;
  bool vok = (v0+vv) < 500;
#pragma unroll
  for (int c=0;c<4;c++){
    f32x4 val = {0,0,0,0};
    int wg = w0 + wc + c*4;
    if (vok && wg < 500) val = *(const f32x4*)(sup + e*250000 + (size_t)(v0+vv)*500 + wg);
    *(f32x4*)&ts[vv][wc + c*4] = val;
    int2 pv; pv.x = pk2(val.x, val.y); pv.y = pk2(val.z, val.w);
    *(int2*)(SB + (size_t)e*(512*512) + (size_t)(v0+vv)*VS + wg) = pv;
  }
  __syncthreads();
  int w = tid>>2, vc = (tid&3)*16;
  unsigned short u[16];
#pragma unroll
  for (int j=0;j<16;j++) u[j] = f2bf(ts[vc+j][w]);
  int4 o0, o1;
  o0.x = u[0]|(u[1]<<16);  o0.y = u[2]|(u[3]<<16);
  o0.z = u[4]|(u[5]<<16);  o0.w = u[6]|(u[7]<<16);
  o1.x = u[8]|(u[9]<<16);  o1.y = u[10]|(u[11]<<16);
  o1.z = u[12]|(u[13]<<16); o1.w = u[14]|(u[15]<<16);
  short* op = ST + (size_t)e*(512*512) + (size_t)(w0+w)*VS + v0 + vc;
  *(int4*)(op) = o0;
  *(int4*)(op+8) = o1;
}

// ST2[e] = (S@S)^T stored [w][u]
__global__ __launch_bounds__(256) void k_ssq(const short* __restrict__ SB,
    const short* __restrict__ ST, short* __restrict__ ST2) {
  __shared__ __align__(16) short As[64*72];
  __shared__ __align__(16) short Bs[64*72];
  int e = blockIdx.z;
  int u0 = blockIdx.x*64, w0 = blockIdx.y*64;
  const short* Ab = SB + (size_t)e*(512*512);
  const short* Bb = ST + (size_t)e*(512*512);
  int tid = threadIdx.x;
  int row = tid>>2, col = (tid&3)*16;
  const short* ap = Ab + (size_t)(u0+row)*VS + col;
  const short* bp = Bb + (size_t)(w0+row)*VS + col;
  f32x4 ra0 = *(const f32x4*)(ap);
  f32x4 ra1 = *(const f32x4*)(ap+8);
  f32x4 rb0 = *(const f32x4*)(bp);
  f32x4 rb1 = *(const f32x4*)(bp+8);
  int wid = tid>>6, lane = tid&63;
  int wr = wid>>1, wc = wid&1;
  int lm = lane&15, lk = (lane>>4)*8;
  f32x4 acc[2][2] = {};
  short* aw = As + row*72 + col;
  short* bw = Bs + row*72 + col;
  for (int kk=0; kk<8; kk++) {
    __syncthreads();
    *(f32x4*)(aw) = ra0; *(f32x4*)(aw+8) = ra1;
    *(f32x4*)(bw) = rb0; *(f32x4*)(bw+8) = rb1;
    __syncthreads();
    if (kk < 7) {
      const short* ap2 = ap + (kk+1)*64;
      const short* bp2 = bp + (kk+1)*64;
      ra0 = *(const f32x4*)(ap2); ra1 = *(const f32x4*)(ap2+8);
      rb0 = *(const f32x4*)(bp2); rb1 = *(const f32x4*)(bp2+8);
    }
#pragma unroll
    for (int ks=0; ks<2; ks++) {
      bf16x8 af0 = *(const bf16x8*)(As + (wr*32 + lm)*72 + ks*32 + lk);
      bf16x8 af1 = *(const bf16x8*)(As + (wr*32 + 16 + lm)*72 + ks*32 + lk);
      bf16x8 bq0 = *(const bf16x8*)(Bs + (wc*32 + lm)*72 + ks*32 + lk);
      bf16x8 bq1 = *(const bf16x8*)(Bs + (wc*32 + 16 + lm)*72 + ks*32 + lk);
      acc[0][0] = __builtin_amdgcn_mfma_f32_16x16x32_bf16(af0, bq0, acc[0][0], 0,0,0);
      acc[0][1] = __builtin_amdgcn_mfma_f32_16x16x32_bf16(af0, bq1, acc[0][1], 0,0,0);
      acc[1][0] = __builtin_amdgcn_mfma_f32_16x16x32_bf16(af1, bq0, acc[1][0], 0,0,0);
      acc[1][1] = __builtin_amdgcn_mfma_f32_16x16x32_bf16(af1, bq1, acc[1][1], 0,0,0);
    }
  }
#pragma unroll
  for (int fm=0; fm<2; fm++) {
    int u4 = u0 + wr*32 + fm*16 + (lane>>4)*4;
#pragma unroll
    for (int fn=0; fn<2; fn++) {
      int w = w0 + wc*32 + fn*16 + lm;
      f32x4 v4 = acc[fm][fn];
      int2 pv; pv.x = pk2(v4.x, v4.y); pv.y = pk2(v4.z, v4.w);
      *(int2*)(ST2 + (size_t)e*(512*512) + (size_t)w*VS + u4) = pv;
    }
  }
}

// GT[b][q][v] bf16 from Gbf[b*NN+v][q] bf16
__global__ __launch_bounds__(256) void k_tposeGb(const short* __restrict__ Gbf,
    short* __restrict__ GT, int qmax) {
  __shared__ __align__(16) short ts[64][72];
  int b = blockIdx.z;
  int v0 = blockIdx.x*64, q0 = blockIdx.y*64;
  int tid = threadIdx.x;
  int vv = tid>>2, qc = (tid&3)*16;
  bool ok = ((v0+vv) < 500) && ((q0+qc) < qmax);
  int4 z4 = {0,0,0,0};
  int4 i0 = z4, i1 = z4;
  if (ok){
    const short* gp = Gbf + (size_t)(b*NN + v0+vv)*QS + q0 + qc;
    i0 = *(const int4*)(gp);
    i1 = *(const int4*)(gp+8);
  }
  *(int4*)&ts[vv][qc] = i0;
  *(int4*)&ts[vv][qc+8] = i1;
  __syncthreads();
  int q = tid>>2, vc = (tid&3)*16;
  if (q0 + q < qmax) {
    unsigned short u[16];
#pragma unroll
    for (int j=0;j<16;j++) u[j] = (unsigned short)ts[vc+j][q];
    int4 o0, o1;
    o0.x = u[0]|(u[1]<<16);  o0.y = u[2]|(u[3]<<16);
    o0.z = u[4]|(u[5]<<16);  o0.w = u[6]|(u[7]<<16);
    o1.x = u[8]|(u[9]<<16);  o1.y = u[10]|(u[11]<<16);
    o1.z = u[12]|(u[13]<<16); o1.w = u[14]|(u[15]<<16);
    short* op = GT + ((size_t)b*QS + q0+q)*VS + v0 + vc;
    *(int4*)(op) = o0;
    *(int4*)(op+8) = o1;
  }
}

// ===== fused diffusion(4 sel) + graph-conv mix + residual + BN partials =====
// tile: 128 w-rows x 64 q-cols; grid nwg = 4 * qt * 32 (x, y, b) with XCD swizzle.
__global__ __launch_bounds__(256) void k_fuse(const short* __restrict__ ST,
    const short* __restrict__ ST2, const short* __restrict__ GT,
    const short* __restrict__ Gbf, const float* __restrict__ Xc,
    float* __restrict__ Xn, const float* __restrict__ gcw,
    const float* __restrict__ gcb, const float* __restrict__ stat, int use_stat,
    float* __restrict__ part, int d, int qt, int qmax) {
  __shared__ __align__(16) short SH[3*128*72];   // As0 | As1 | Bs ; mixb aliases As0
  __shared__ __align__(16) short gws[5*32*32];
  __shared__ float red[4][64];
  short* As0 = SH;
  short* As1 = SH + 128*72;
  short* Bs  = SH + 2*128*72;
  short* mixb = SH;                               // 128 rows x 72
  int nwg = gridDim.x;
  int v = (blockIdx.x & 7)*(nwg>>3) + (blockIdx.x>>3);
  int x = v & 3; v >>= 2;
  int y = v % qt; int b = v / qt;
  int w0 = x*128, q0 = y*64;
  int tid = threadIdx.x, wid = tid>>6, lane = tid&63;
  int lm = lane&15, g = lane>>4, lk8 = g*8;
  // stage gcw -> gws[src][c'][c] bf16
  for (int i = tid; i < 5120; i += 256){
    int src = i >> 10, rem = i & 1023;
    int cp = rem >> 5, c = rem & 31;
    gws[i] = (short)f2bf(gcw[cp*160 + src*32 + c]);
  }
  f32x4 outa[2][2][2] = {};   // [mf][t][nf]

#define MIX_STEP(SRC) do { \
  _Pragma("unroll") \
  for (int mf=0; mf<2; mf++) \
    _Pragma("unroll") \
    for (int t=0; t<2; t++) { \
      bf16x8 af = *(const bf16x8*)(mixb + (wid*32+mf*16+lm)*72 + t*32 + lk8); \
      _Pragma("unroll") \
      for (int nf=0; nf<2; nf++) { \
        bf16x8 bq = *(const bf16x8*)(gws + (SRC)*1024 + (nf*16+lm)*32 + lk8); \
        outa[mf][t][nf] = __builtin_amdgcn_mfma_f32_16x16x32_bf16(af, bq, outa[mf][t][nf], 0,0,0); \
      } \
    } \
} while(0)

  // ---- G term (src 0): load G tile 128x64 into mixb ----
  {
#pragma unroll
    for (int p=0;p<4;p++){
      int rr = (tid>>3) + p*32, cc = (tid&7)*8;
      int4 z = {0,0,0,0};
      if (w0+rr < 500 && q0+cc < qmax)
        z = *(const int4*)(Gbf + (size_t)(b*NN + w0+rr)*QS + q0 + cc);
      *(int4*)(mixb + rr*72 + cc) = z;
    }
    __syncthreads();
    MIX_STEP(0);
    __syncthreads();
  }

  // ---- diffusion pairs ----
  int arow = tid>>2, acol = (tid&3)*16;   // A: rows arow, arow+64; 16-short seg
#pragma unroll
  for (int e=0; e<2; e++){
    const short* A0b = ST  + (size_t)e*(512*512) + (size_t)w0*VS;
    const short* A1b = ST2 + (size_t)e*(512*512) + (size_t)w0*VS;
    const short* Bb  = GT + (size_t)b*(QS*VS) + (size_t)q0*VS;
    f32x4 acc0[2][4] = {}, acc1[2][4] = {};
    for (int kk=0; kk<8; kk++){
      const short* a0 = A0b + (size_t)arow*VS + kk*64 + acol;
      const short* a1 = A1b + (size_t)arow*VS + kk*64 + acol;
      const short* bp = Bb + (size_t)arow*VS + kk*64 + acol;
      int4 r00 = *(const int4*)a0;
      int4 r01 = *(const int4*)(a0+8);
      int4 r02 = *(const int4*)(a0 + (size_t)64*VS);
      int4 r03 = *(const int4*)(a0 + (size_t)64*VS + 8);
      int4 r10 = *(const int4*)a1;
      int4 r11 = *(const int4*)(a1+8);
      int4 r12 = *(const int4*)(a1 + (size_t)64*VS);
      int4 r13 = *(const int4*)(a1 + (size_t)64*VS + 8);
      int4 rb0 = *(const int4*)bp;
      int4 rb1 = *(const int4*)(bp+8);
      __syncthreads();
      *(int4*)(As0 + arow*72 + acol) = r00;
      *(int4*)(As0 + arow*72 + acol + 8) = r01;
      *(int4*)(As0 + (arow+64)*72 + acol) = r02;
      *(int4*)(As0 + (arow+64)*72 + acol + 8) = r03;
      *(int4*)(As1 + arow*72 + acol) = r10;
      *(int4*)(As1 + arow*72 + acol + 8) = r11;
      *(int4*)(As1 + (arow+64)*72 + acol) = r12;
      *(int4*)(As1 + (arow+64)*72 + acol + 8) = r13;
      *(int4*)(Bs + arow*72 + acol) = rb0;
      *(int4*)(Bs + arow*72 + acol + 8) = rb1;
      __syncthreads();
#pragma unroll
      for (int ks=0; ks<2; ks++){
        bf16x8 bq[4];
#pragma unroll
        for (int nf=0; nf<4; nf++) bq[nf] = *(const bf16x8*)(Bs + (nf*16+lm)*72 + ks*32 + lk8);
#pragma unroll
        for (int mf=0; mf<2; mf++){
          bf16x8 af0 = *(const bf16x8*)(As0 + (wid*32+mf*16+lm)*72 + ks*32 + lk8);
          bf16x8 af1 = *(const bf16x8*)(As1 + (wid*32+mf*16+lm)*72 + ks*32 + lk8);
#pragma unroll
          for (int nf=0; nf<4; nf++){
            acc0[mf][nf] = __builtin_amdgcn_mfma_f32_16x16x32_bf16(af0, bq[nf], acc0[mf][nf], 0,0,0);
            acc1[mf][nf] = __builtin_amdgcn_mfma_f32_16x16x32_bf16(af1, bq[nf], acc1[mf][nf], 0,0,0);
          }
        }
      }
    }
    // mix acc0 (src 1+2e)
    __syncthreads();
#pragma unroll
    for (int mf=0; mf<2; mf++)
#pragma unroll
      for (int nf=0; nf<4; nf++){
        f32x4 vv = acc0[mf][nf];
        int rbase = (wid*32+mf*16+g*4)*72 + nf*16+lm;
        mixb[rbase]       = (short)f2bf(vv.x);
        mixb[rbase+72]    = (short)f2bf(vv.y);
        mixb[rbase+144]   = (short)f2bf(vv.z);
        mixb[rbase+216]   = (short)f2bf(vv.w);
      }
    __syncthreads();
    MIX_STEP(1+e*2);
    __syncthreads();
    // mix acc1 (src 2+2e)
#pragma unroll
    for (int mf=0; mf<2; mf++)
#pragma unroll
      for (int nf=0; nf<4; nf++){
        f32x4 vv = acc1[mf][nf];
        int rbase = (wid*32+mf*16+g*4)*72 + nf*16+lm;
        mixb[rbase]       = (short)f2bf(vv.x);
        mixb[rbase+72]    = (short)f2bf(vv.y);
        mixb[rbase+144]   = (short)f2bf(vv.z);
        mixb[rbase+216]   = (short)f2bf(vv.w);
      }
    __syncthreads();
    MIX_STEP(2+e*2);
    __syncthreads();
  }
#undef MIX_STEP

  // ---- epilogue: bias + residual + BN + store ----
  float scn0 = use_stat ? stat[lm]    : 1.f;
  float scn1 = use_stat ? stat[16+lm] : 1.f;
  float shn0 = use_stat ? stat[32+lm] : 0.f;
  float shn1 = use_stat ? stat[48+lm] : 0.f;
  float gb0 = gcb[lm], gb1 = gcb[16+lm];
  float ss0=0.f, ss1=0.f, sq0=0.f, sq1=0.f;
  int tbase = q0>>5;
#pragma unroll
  for (int mf=0; mf<2; mf++)
#pragma unroll
    for (int t=0; t<2; t++){
      if (q0 + t*32 >= qmax) continue;
      int tg = tbase + t;
#pragma unroll
      for (int r=0; r<4; r++){
        int w = w0 + wid*32 + mf*16 + g*4 + r;
        if (w >= 500) continue;
        size_t xoff = (size_t)(b*NN + w)*(TX*CC);
        float v0 = outa[mf][t][0][r] + gb0 + Xc[xoff + (tg+d)*32 + lm]*scn0 + shn0;
        float v1 = outa[mf][t][1][r] + gb1 + Xc[xoff + (tg+d)*32 + 16+lm]*scn1 + shn1;
        Xn[xoff + tg*32 + lm] = v0;
        Xn[xoff + tg*32 + 16+lm] = v1;
        ss0+=v0; sq0+=v0*v0; ss1+=v1; sq1+=v1*v1;
      }
    }
#pragma unroll
  for (int off=16; off<64; off<<=1){
    ss0+=__shfl_xor(ss0,off); sq0+=__shfl_xor(sq0,off);
    ss1+=__shfl_xor(ss1,off); sq1+=__shfl_xor(sq1,off);
  }
  if (lane<16){
    red[wid][lm]=ss0; red[wid][16+lm]=ss1; red[wid][32+lm]=sq0; red[wid][48+lm]=sq1;
  }
  __syncthreads();
  if (tid<64){
    part[(size_t)blockIdx.x*64 + tid] = red[0][tid]+red[1][tid]+red[2][tid]+red[3][tid];
  }
}

// ================= input projection / enter conv =================

__global__ void k_proj(const float* __restrict__ inputs, const float* __restrict__ factor,
                       float* __restrict__ proj) {
  int bt = blockIdx.x;
  __shared__ float xin[NN*2];
  for (int idx=threadIdx.x; idx<NN*2; idx+=64) xin[idx] = inputs[bt*NN*2 + idx];
  __syncthreads();
  int u = threadIdx.x>>1, f = threadIdx.x&1;
  float acc=0.f;
  for (int n=0;n<NN;n++) acc += xin[n*2+f]*factor[n*UU+u];
  proj[bt*64 + u*2+f] = acc;
}

__global__ __launch_bounds__(256) void k_enter(const float* __restrict__ inputs,
    const float* __restrict__ factor, const float* __restrict__ proj,
    const float* __restrict__ ew, const float* __restrict__ eb, float* __restrict__ X) {
  int idx = blockIdx.x*256+threadIdx.x;
  if (idx >= BB*NN*TX) return;
  int t = idx % TX; int n = (idx/TX)%NN; int b = idx/(TX*NN);
  float x4[4]={0.f,0.f,0.f,0.f};
  if (t>0) {
    int tt=t-1;
    float s0=0.f,s1=0.f;
    const float* pr = proj + (b*TT+tt)*64;
    const float* fr = factor + n*UU;
#pragma unroll
    for(int u=0;u<UU;u++){ s0 += pr[u*2]*fr[u]; s1 += pr[u*2+1]*fr[u]; }
    float i0 = inputs[((b*TT+tt)*NN+n)*2];
    float i1 = inputs[((b*TT+tt)*NN+n)*2+1];
    x4[0]=s0; x4[1]=s1; x4[2]=i0-s0; x4[3]=i1-s1;
  }
  float* xp = X + ((size_t)(b*NN+n)*TX + t)*CC;
#pragma unroll
  for(int o=0;o<CC;o++){
    xp[o] = eb[o] + ew[o*4]*x4[0] + ew[o*4+1]*x4[1] + ew[o*4+2]*x4[2] + ew[o*4+3]*x4[3];
  }
}

// ================= MFMA gated temporal conv =================

__global__ __launch_bounds__(256) void k_gated3(const float* __restrict__ X,
    short* __restrict__ Gbf, short* __restrict__ Glb,
    const float* __restrict__ fw, const float* __restrict__ fb,
    const float* __restrict__ gw, const float* __restrict__ gb,
    const float* __restrict__ stat, int use_stat, int d, int t_out, int lidx) {
  __shared__ __align__(16) short As[64*72];
  __shared__ __align__(16) short Wb[64*72];
  __shared__ float scs[32], shs[32];
  int tid = threadIdx.x;
  if (tid < 32) {
    scs[tid] = use_stat ? stat[tid] : 1.0f;
    shs[tid] = use_stat ? stat[32 + tid] : 0.0f;
  }
  for (int i = tid; i < 2048; i += 256) {
    int o = i >> 6, k = i & 63;
    Wb[o*72 + k]      = (short)f2bf(fw[i]);
    Wb[(32+o)*72 + k] = (short)f2bf(gw[i]);
  }
  __syncthreads();
  int m0 = blockIdx.x * 64;
  {
    int mm = tid & 63;
    int kb = (tid >> 6) * 16;
    int c0 = kb >> 1;
    int m = m0 + mm;
    int bn = m / t_out, t = m - bn * t_out;
    const float* xr = X + (size_t)bn * (TX * CC);
    float4 a0 = *(const float4*)(xr + t * 32 + c0);
    float4 a1 = *(const float4*)(xr + t * 32 + c0 + 4);
    float4 b0 = *(const float4*)(xr + (t + d) * 32 + c0);
    float4 b1 = *(const float4*)(xr + (t + d) * 32 + c0 + 4);
    float va[8] = {a0.x,a0.y,a0.z,a0.w,a1.x,a1.y,a1.z,a1.w};
    float vb[8] = {b0.x,b0.y,b0.z,b0.w,b1.x,b1.y,b1.z,b1.w};
    int iv[8];
#pragma unroll
    for (int j = 0; j < 8; j++) {
      float sc = scs[c0+j], sh = shs[c0+j];
      iv[j] = pk2(va[j]*sc + sh, vb[j]*sc + sh);
    }
    int4 w0 = {iv[0],iv[1],iv[2],iv[3]};
    int4 w1 = {iv[4],iv[5],iv[6],iv[7]};
    *(int4*)(As + mm*72 + kb) = w0;
    *(int4*)(As + mm*72 + kb + 8) = w1;
  }
  __syncthreads();
  int wid = tid>>6, lane = tid&63;
  int lm = lane&15, g = lane>>4, lk8 = g*8;
  f32x4 acc[4] = {};
#pragma unroll
  for (int kk=0; kk<2; kk++){
    bf16x8 af = *(const bf16x8*)(As + (wid*16+lm)*72 + kk*32 + lk8);
#pragma unroll
    for (int fn=0; fn<4; fn++){
      bf16x8 bq = *(const bf16x8*)(Wb + (fn*16+lm)*72 + kk*32 + lk8);
      acc[fn] = __builtin_amdgcn_mfma_f32_16x16x32_bf16(af, bq, acc[fn], 0,0,0);
    }
  }
#pragma unroll
  for (int fn=0; fn<2; fn++){
    int o = fn*16 + lm;
    float fbv = fb[o], gbv = gb[o];
#pragma unroll
    for (int r=0; r<4; r++){
      int m = m0 + wid*16 + g*4 + r;
      int bn = m / t_out, t = m - bn*t_out;
      float f = acc[fn][r] + fbv;
      float gg = acc[fn+2][r] + gbv;
      float th = 2.f/(1.f+__expf(-2.f*f)) - 1.f;
      float sg = 1.f/(1.f+__expf(-gg));
      unsigned short ov = f2bf(th*sg);
      Gbf[(size_t)bn*QS + t*32 + o] = (short)ov;
      if (t == t_out-1) Glb[(size_t)bn*256 + lidx*32 + o] = (short)ov;
    }
  }
}

// 2-stage BN-stat reduction
__global__ __launch_bounds__(64) void k_stat2a(const float* __restrict__ part, int nblk,
    float* __restrict__ part2) {
  int t = threadIdx.x;
  float s = 0.f;
  for (int i = blockIdx.x; i < nblk; i += 64) s += part[(size_t)i*64 + t];
  part2[blockIdx.x*64 + t] = s;
}

__global__ __launch_bounds__(64) void k_stat2b(const float* __restrict__ part2,
    const float* __restrict__ g, const float* __restrict__ b,
    float* __restrict__ statout, float cntinv) {
  int t = threadIdx.x;
  float s = 0.f;
#pragma unroll 8
  for (int i = 0; i < 64; i++) s += part2[i*64 + t];
  __shared__ float red[64];
  red[t] = s;
  __syncthreads();
  if (t < 32){
    float sum = red[t], sq = red[32+t];
    float m = sum*cntinv, var = sq*cntinv - m*m;
    float sc = rsqrtf(var + BN_EPS)*g[t];
    statout[t] = sc;
    statout[32+t] = b[t] - m*sc;
  }
}

// ================= output head =================

__global__ void k_wstack2(const float* __restrict__ skp_w, const float* __restrict__ skp_b,
                          const float* __restrict__ o1w,
                          short* __restrict__ Wstb, short* __restrict__ o1wb,
                          float* __restrict__ bsum) {
  int bid = blockIdx.x;
  int idx = bid*256 + threadIdx.x;
  if (bid < 256){
    int kk = idx >> 8, o = idx & 255;
    Wstb[o*256 + kk] = (short)f2bf(skp_w[(kk>>5)*8192 + o*32 + (kk&31)]);
    if (idx < 256){
      float s=0.f;
      for (int l=0;l<8;l++) s += skp_b[l*256+idx];
      bsum[idx]=s;
    }
  } else {
    int j = idx - 65536;
    o1wb[j] = (short)f2bf(o1w[j]);
  }
}

// C[m][n] = relu(sum_k A[m][k]*B[n][k] + bias[n]) -> bf16 out
__global__ __launch_bounds__(256) void k_mm(const short* __restrict__ A,
    const short* __restrict__ B, const float* __restrict__ bias,
    short* __restrict__ out, int ldout, int K) {
  __shared__ __align__(16) short As[64*72];
  __shared__ __align__(16) short Bs[64*72];
  int m0 = blockIdx.x*64, n0 = blockIdx.y*64;
  int tid = threadIdx.x;
  int row = tid>>2, col = (tid&3)*16;
  const short* ap = A + (size_t)(m0+row)*K + col;
  const short* bp = B + (size_t)(n0+row)*K + col;
  f32x4 ra0 = *(const f32x4*)(ap);
  f32x4 ra1 = *(const f32x4*)(ap+8);
  f32x4 rb0 = *(const f32x4*)(bp);
  f32x4 rb1 = *(const f32x4*)(bp+8);
  int wid = tid>>6, lane = tid&63;
  int wr = wid>>1, wc = wid&1;
  int lm = lane&15, lk = (lane>>4)*8;
  f32x4 acc[2][2] = {};
  short* aw = As + row*72 + col;
  short* bw = Bs + row*72 + col;
  int nk = K>>6;
  for (int kk=0; kk<nk; kk++) {
    __syncthreads();
    *(f32x4*)(aw) = ra0; *(f32x4*)(aw+8) = ra1;
    *(f32x4*)(bw) = rb0; *(f32x4*)(bw+8) = rb1;
    __syncthreads();
    if (kk < nk-1) {
      const short* ap2 = ap + (kk+1)*64;
      const short* bp2 = bp + (kk+1)*64;
      ra0 = *(const f32x4*)(ap2); ra1 = *(const f32x4*)(ap2+8);
      rb0 = *(const f32x4*)(bp2); rb1 = *(const f32x4*)(bp2+8);
    }
#pragma unroll
    for (int ks=0; ks<2; ks++) {
      bf16x8 af0 = *(const bf16x8*)(As + (wr*32 + lm)*72 + ks*32 + lk);
      bf16x8 af1 = *(const bf16x8*)(As + (wr*32 + 16 + lm)*72 + ks*32 + lk);
      bf16x8 bq0 = *(const bf16x8*)(Bs + (wc*32 + lm)*72 + ks*32 + lk);
      bf16x8 bq1 = *(const bf16x8*)(Bs + (wc*32 + 16 + lm)*72 + ks*32 + lk);
      acc[0][0] = __builtin_amdgcn_mfma_f32_16x16x32_bf16(af0, bq0, acc[0][0], 0,0,0);
      acc[0][1] = __builtin_amdgcn_mfma_f32_16x16x32_bf16(af0, bq1, acc[0][1], 0,0,0);
      acc[1][0] = __builtin_amdgcn_mfma_f32_16x16x32_bf16(af1, bq0, acc[1][0], 0,0,0);
      acc[1][1] = __builtin_amdgcn_mfma_f32_16x16x32_bf16(af1, bq1, acc[1][1], 0,0,0);
    }
  }
#pragma unroll
  for (int fm=0; fm<2; fm++) {
    int mb = m0 + wr*32 + fm*16 + (lane>>4)*4;
#pragma unroll
    for (int fn=0; fn<2; fn++) {
      int n = n0 + wc*32 + fn*16 + lm;
      float bv = bias[n];
      f32x4 v4 = acc[fm][fn];
#pragma unroll
      for (int r=0;r<4;r++)
        out[(size_t)(mb+r)*ldout + n] = (short)f2bf(fmaxf(v4[r]+bv, 0.f));
    }
  }
}

// head2 as MFMA skinny GEMM
__global__ __launch_bounds__(256) void k_head2m(const short* __restrict__ Y1b,
    const float* __restrict__ o2w, const float* __restrict__ o2b, float* __restrict__ y) {
  int tid = threadIdx.x;
  int wid = tid>>6, lane = tid&63;
  int lm = lane&15, g = lane>>4, lk8 = g*8;
  int m0 = blockIdx.x*64 + wid*16;
  bf16x8 wf[16];
#pragma unroll
  for (int ks=0; ks<16; ks++){
    f32x4 lo={0,0,0,0}, hi={0,0,0,0};
    if (lm < NPREDC){
      const float* wp = o2w + lm*NENDC + ks*32 + lk8;
      lo = *(const f32x4*)wp; hi = *(const f32x4*)(wp+4);
    }
    wf[ks] = pack8(lo, hi);
  }
  f32x4 acc = {0,0,0,0};
  const short* ar = Y1b + (size_t)(m0+lm)*NENDC;
#pragma unroll
  for (int ks=0; ks<16; ks++){
    bf16x8 af = *(const bf16x8*)(ar + ks*32 + lk8);
    acc = __builtin_amdgcn_mfma_f32_16x16x32_bf16(af, wf[ks], acc, 0,0,0);
  }
  int p = lm;
  if (p < NPREDC){
    float bv = o2b[p];
#pragma unroll
    for (int r=0;r<4;r++){
      int m = m0 + g*4 + r;
      int bb = m/NN, n = m - bb*NN;
      y[(bb*NPREDC+p)*NN + n] = acc[r] + bv;
    }
  }
}

// ================= host =================

extern "C" void kernel_launch(void* const* d_in, const int* in_sizes, int n_in,
                              void* d_out, int out_size, void* d_ws, size_t ws_size,
                              hipStream_t stream) {
  const float* inputs  = (const float*)d_in[0];
  const float* factor  = (const float*)d_in[1];
  const float* map_w   = (const float*)d_in[2];
  const float* map_b   = (const float*)d_in[3];
  const float* a1w     = (const float*)d_in[4];
  const float* a1b     = (const float*)d_in[5];
  const float* a2w     = (const float*)d_in[6];
  const float* a2b     = (const float*)d_in[7];
  const float* a3w     = (const float*)d_in[8];
  const float* a3b     = (const float*)d_in[9];
  const float* enter_w = (const float*)d_in[10];
  const float* enter_b = (const float*)d_in[11];
  const float* filt_w  = (const float*)d_in[12];
  const float* filt_b  = (const float*)d_in[13];
  const float* gate_w  = (const float*)d_in[14];
  const float* gate_b  = (const float*)d_in[15];
  const float* skp_w   = (const float*)d_in[16];
  const float* skp_b   = (const float*)d_in[17];
  const float* gc_w    = (const float*)d_in[18];
  const float* gc_b    = (const float*)d_in[19];
  const float* bn_g    = (const float*)d_in[20];
  const float* bn_b    = (const float*)d_in[21];
  const float* o1w     = (const float*)d_in[22];
  const float* o1b     = (const float*)d_in[23];
  const float* o2w     = (const float*)d_in[24];
  const float* o2b     = (const float*)d_in[25];
  (void)in_sizes; (void)n_in; (void)out_size; (void)ws_size;

  float* ws = (float*)d_ws;
  float* v      = ws + OFF_V;
  float* adj    = ws + OFF_ADJ;
  float* part2  = ws + OFF_ADJ;      // reuse (adj dead after k_tposeS)
  float* asrc   = ws + OFF_ASRC;
  float* adst   = ws + OFF_ADST;
  float* proj   = ws + OFF_PROJ;
  float* statb  = ws + OFF_STAT;
  float* part   = ws + OFF_PART;
  float* bsum   = ws + OFF_BSUM;
  float* X      = ws + OFF_X;
  float* Xn     = ws + OFF_XN;
  short* Gbf    = (short*)(ws + OFF_GBF);
  short* Glb    = (short*)(ws + OFF_GLB);
  short* GT     = (short*)(ws + OFF_GT);
  short* ST     = (short*)(ws + OFF_ST);
  short* SB     = (short*)(ws + OFF_SB);
  short* ST2    = (short*)(ws + OFF_ST2);
  short* Wstb   = (short*)(ws + OFF_WSTB);
  short* o1wb   = (short*)(ws + OFF_O1WB);
  short* skvb   = (short*)(ws + OFF_SKV);
  short* Y1b    = (short*)(ws + OFF_Y1B);

  float* y_out   = (float*)d_out;
  float* sup_out = y_out + BB*NPREDC*NN;

  // adaptive supports
  k_v<<<NN, 32, 0, stream>>>(factor, map_w, map_b, v);
  k_asrc2<<<NN, 64, 0, stream>>>(v, a1w, a1b, asrc, adst);
  {
    dim3 gp(NN, 2);
    k_pair3<<<gp, 256, 0, stream>>>(asrc, adst, a2w, a2b, a3w, a3b, adj);
  }
  k_softmax<<<2*NN, 256, 0, stream>>>(adj, sup_out);
  {
    dim3 gt(8, 8, 2);
    k_tposeS<<<gt, 256, 0, stream>>>(sup_out, ST, SB);
    k_ssq<<<gt, 256, 0, stream>>>(SB, ST, ST2);
  }

  // input split + enter
  k_proj<<<BB*TT, 64, 0, stream>>>(inputs, factor, proj);
  k_enter<<<(BB*NN*TX+255)/256, 256, 0, stream>>>(inputs, factor, proj, enter_w, enter_b, X);

  // head weight prep (independent)
  k_wstack2<<<768, 256, 0, stream>>>(skp_w, skp_b, o1w, Wstb, o1wb, bsum);

  float* Xc = X; float* Xo = Xn;
  int t = TX;
  static const int dil[8]={1,2,1,2,1,2,1,2};
  for (int l=0;l<7;l++){
    int d=dil[l], t_out=t-d;
    const float* st = statb + (l>0 ? (l-1)*64 : 0);
    k_gated3<<<250*t_out,256,0,stream>>>(Xc, Gbf, Glb, filt_w + l*2048, filt_b + l*32,
                                         gate_w + l*2048, gate_b + l*32, st, l>0, d, t_out, l);
    int qmax = t_out*CC;
    int qt64 = (qmax+63)/64;
    dim3 gtp(8, qt64, 32);
    k_tposeGb<<<gtp,256,0,stream>>>(Gbf, GT, qmax);
    int nwg = 4*qt64*32;
    k_fuse<<<nwg,256,0,stream>>>(ST, ST2, GT, Gbf, Xc, Xo,
                                 gc_w + l*5120, gc_b + l*32, st, l>0,
                                 part, d, qt64, qmax);
    k_stat2a<<<64,64,0,stream>>>(part, nwg, part2);
    k_stat2b<<<1,64,0,stream>>>(part2, bn_g + l*32, bn_b + l*32,
                                statb + l*64, 1.f/(16000.f*(float)t_out));
    float* tmp=Xc; Xc=Xo; Xo=tmp;
    t = t_out;
  }
  // layer 8: only gated conv feeds skip
  k_gated3<<<250*1,256,0,stream>>>(Xc, Gbf, Glb, filt_w + 7*2048, filt_b + 7*32,
                                   gate_w + 7*2048, gate_b + 7*32, statb + 6*64, 1, 2, 1, 7);

  // head: skip GEMM -> head1 -> head2
  {
    dim3 gs(BNN/64, NSKIPC/64);
    k_mm<<<gs,256,0,stream>>>(Glb, Wstb, bsum, skvb, NSKIPC, 256);
    dim3 gh(BNN/64, NENDC/64);
    k_mm<<<gh,256,0,stream>>>(skvb, o1wb, o1b, Y1b, NENDC, 256);
    k_head2m<<<BNN/64,256,0,stream>>>(Y1b, o2w, o2b, y_out);
  }
}